// Round 5
// baseline (902.850 us; speedup 1.0000x reference)
//
#include <hip/hip_runtime.h>
#include <math.h>

#define DEVINL __device__ __forceinline__

using bf16x8 = __attribute__((ext_vector_type(8))) short;
using f32x4  = __attribute__((ext_vector_type(4))) float;

DEVINL float gelu_f(float v) { return 0.5f * v * (1.0f + erff(v * 0.7071067811865475f)); }
DEVINL float lrelu_f(float v) { return v > 0.0f ? v : 0.2f * v; }
DEVINL unsigned short f2bf(float f) {
    union { float f; unsigned u; } c; c.f = f;
    unsigned r = c.u + 0x7fffu + ((c.u >> 16) & 1u);
    return (unsigned short)(r >> 16);
}
DEVINL float bf2f(unsigned short s) {
    union { unsigned u; float f; } c; c.u = (unsigned)s << 16;
    return c.f;
}

// ---------------- style: style = gelu(z_g@W_s1+b_s1)@W_s2 + b_s2 ----------------
__global__ void style_k(const float* __restrict__ zg, const float* __restrict__ W1,
                        const float* __restrict__ b1, const float* __restrict__ W2,
                        const float* __restrict__ b2, float* __restrict__ style) {
    __shared__ float s1[128];
    int j = threadIdx.x;
    float a = b1[j];
    for (int k = 0; k < 256; k++) a = fmaf(zg[k], W1[k * 128 + j], a);
    s1[j] = gelu_f(a);
    __syncthreads();
    float o = b2[j];
    for (int k = 0; k < 128; k++) o = fmaf(s1[k], W2[k * 128 + j], o);
    style[j] = o;
}

// ---------------- node-embed layer 1: h1 = gelu(tv@W_ne1 + b_ne1), f32 out ------
__global__ void ne1_k(const float* __restrict__ tv, const float* __restrict__ W,
                      const float* __restrict__ b, float* __restrict__ h1, int Nn) {
    int idx = blockIdx.x * blockDim.x + threadIdx.x;
    if (idx >= Nn * 128) return;
    int n = idx >> 7, c = idx & 127;
    float o = fmaf(tv[n * 3 + 0], W[c],
              fmaf(tv[n * 3 + 1], W[128 + c],
              fmaf(tv[n * 3 + 2], W[256 + c], b[c])));
    h1[idx] = gelu_f(o);
}

// -------- weight prep: f32 W[128][OUT] -> bf16 hi/lo WT[OUT][128] pairs ----------
struct PrepArgs {
    const float* src[8];
    unsigned short* dsth[8];
    unsigned short* dstl[8];
    int off[9];
    int shift[8];  // log2(OUT)
};
__global__ void prep_k(PrepArgs a) {
    int idx = blockIdx.x * 256 + threadIdx.x;
    if (idx >= a.off[8]) return;
    int s = 0;
    while (idx >= a.off[s + 1]) s++;
    int e = idx - a.off[s];
    int sh = a.shift[s];
    int k = e >> sh, j = e & ((1 << sh) - 1);
    float w = a.src[s][e];
    unsigned short hi = f2bf(w);
    unsigned short lo = f2bf(w - bf2f(hi));
    a.dsth[s][j * 128 + k] = hi;
    a.dstl[s][j * 128 + k] = lo;
}

// ---------------- split-MFMA linear: near-f32 accuracy, occupancy-tuned ----------
// 32 rows/block; the (matrix x j0) chunk space is split across the 4 waves so the
// grid is ~1563 blocks (vs 391 at 128 rows/block -> 13% occupancy in R4).
template <int OUT, int EPI, bool DUAL>  // EPI 0:bias 1:bias+style 2:bias+gelu
__global__ __launch_bounds__(256) void mfma_lin_k(
    const float* __restrict__ xin,
    const unsigned short* __restrict__ WH0, const unsigned short* __restrict__ WL0,
    const float* __restrict__ b0,
    const unsigned short* __restrict__ WH1, const unsigned short* __restrict__ WL1,
    const float* __restrict__ b1,
    const float* __restrict__ style,
    float* __restrict__ out0, float* __restrict__ out1, int Nn) {
    int t = threadIdx.x;
    int wave = t >> 6, lane = t & 63;
    int lr = lane & 15, lk = lane >> 4;
    int base = blockIdx.x * 32;
    int r0 = base + lr, r1 = base + 16 + lr;
    int cr0 = min(r0, Nn - 1), cr1 = min(r1, Nn - 1);

    bf16x8 xh[2][4], xlo[2][4];
#pragma unroll
    for (int rr = 0; rr < 2; rr++) {
        const float* px = xin + (size_t)(rr ? cr1 : cr0) * 128;
#pragma unroll
        for (int s = 0; s < 4; s++) {
            const float4* p4 = (const float4*)(px + s * 32 + lk * 8);
            float4 a = p4[0], b = p4[1];
            float v[8] = {a.x, a.y, a.z, a.w, b.x, b.y, b.z, b.w};
            bf16x8 h, l;
#pragma unroll
            for (int i = 0; i < 8; i++) {
                unsigned short hb = f2bf(v[i]);
                h[i] = (short)hb;
                l[i] = (short)f2bf(v[i] - bf2f(hb));
            }
            xh[rr][s] = h;
            xlo[rr][s] = l;
        }
    }

    constexpr int CPM = OUT / 16;                 // chunks per matrix
    constexpr int NCH = (DUAL ? 2 : 1) * CPM;     // total chunks
    for (int c = wave; c < NCH; c += 4) {
        int m = DUAL ? (c >= CPM) : 0;
        int j0 = (c - m * CPM) * 16;
        const unsigned short* WH = m ? WH1 : WH0;
        const unsigned short* WL = m ? WL1 : WL0;
        const float* bias = m ? b1 : b0;
        float* out = m ? out1 : out0;

        const bf16x8* pwh = (const bf16x8*)(WH + (size_t)(j0 + lr) * 128);
        const bf16x8* pwl = (const bf16x8*)(WL + (size_t)(j0 + lr) * 128);
        f32x4 acc0 = {0.f, 0.f, 0.f, 0.f}, acc1 = {0.f, 0.f, 0.f, 0.f};
#pragma unroll
        for (int s = 0; s < 4; s++) {
            bf16x8 wh = pwh[s * 4 + lk];
            bf16x8 wl = pwl[s * 4 + lk];
            acc0 = __builtin_amdgcn_mfma_f32_16x16x32_bf16(wh, xh[0][s], acc0, 0, 0, 0);
            acc0 = __builtin_amdgcn_mfma_f32_16x16x32_bf16(wh, xlo[0][s], acc0, 0, 0, 0);
            acc0 = __builtin_amdgcn_mfma_f32_16x16x32_bf16(wl, xh[0][s], acc0, 0, 0, 0);
            acc1 = __builtin_amdgcn_mfma_f32_16x16x32_bf16(wh, xh[1][s], acc1, 0, 0, 0);
            acc1 = __builtin_amdgcn_mfma_f32_16x16x32_bf16(wh, xlo[1][s], acc1, 0, 0, 0);
            acc1 = __builtin_amdgcn_mfma_f32_16x16x32_bf16(wl, xh[1][s], acc1, 0, 0, 0);
        }
        int j = j0 + lk * 4;
        float o0[4], o1[4];
#pragma unroll
        for (int i = 0; i < 4; i++) {
            float bb = bias[j + i];
            if (EPI == 1) bb += style[j + i];
            float v0 = acc0[i] + bb, v1 = acc1[i] + bb;
            if (EPI == 2) { v0 = gelu_f(v0); v1 = gelu_f(v1); }
            o0[i] = v0; o1[i] = v1;
        }
        if (r0 < Nn) { f32x4 v = {o0[0], o0[1], o0[2], o0[3]}; *(f32x4*)(out + (size_t)r0 * OUT + j) = v; }
        if (r1 < Nn) { f32x4 v = {o1[0], o1[1], o1[2], o1[3]}; *(f32x4*)(out + (size_t)r1 * OUT + j) = v; }
    }
}

// ---------------- CSR build (by destination), self-loops appended ----------------
__global__ void count_k(const int* __restrict__ dst, int* __restrict__ counts, int E, int EP) {
    int e = blockIdx.x * blockDim.x + threadIdx.x;
    if (e >= EP) return;
    int d = (e < E) ? dst[e] : (e - E);
    atomicAdd(&counts[d], 1);
}

__global__ void scan_k(const int* __restrict__ counts, int* __restrict__ rowptr, int Nn, int total) {
    __shared__ int part[1024];
    int tid = threadIdx.x;
    int chunk = (Nn + 1023) >> 10;
    int s = tid * chunk, e = min(s + chunk, Nn);
    int loc = 0;
    for (int i = s; i < e; i++) loc += counts[i];
    part[tid] = loc;
    __syncthreads();
    for (int off = 1; off < 1024; off <<= 1) {
        int v = (tid >= off) ? part[tid - off] : 0;
        __syncthreads();
        part[tid] += v;
        __syncthreads();
    }
    int run = part[tid] - loc;  // exclusive
    for (int i = s; i < e; i++) { rowptr[i] = run; run += counts[i]; }
    if (e == Nn) rowptr[Nn] = total;
}

__global__ void fill_k(const int* __restrict__ src, const int* __restrict__ dst,
                       const int* __restrict__ rowptr, int* __restrict__ fillc,
                       int* __restrict__ col, int E, int EP) {
    int e = blockIdx.x * blockDim.x + threadIdx.x;
    if (e >= EP) return;
    int d = (e < E) ? dst[e] : (e - E);
    int s = (e < E) ? src[e] : (e - E);
    int pos = atomicAdd(&fillc[d], 1);
    col[rowptr[d] + pos] = s;
}

// ---------------- GATv2 gather: 4 edges/iter, 16 lanes x 8ch each ----------------
template <int H>
__global__ __launch_bounds__(256) void gat_gather_k(
    const float* __restrict__ xl, const float* __restrict__ xr,
    const float* __restrict__ att, const float* __restrict__ bo,
    const int* __restrict__ rowptr, const int* __restrict__ col,
    float* __restrict__ y, int Nn) {
    constexpr int NPB = (H == 2) ? 2 : 4;   // nodes per block (4 waves)
    int w = threadIdx.x >> 6;
    int slot = (H == 2) ? (w >> 1) : w;
    int h = (H == 2) ? (w & 1) : 0;
    int lane = threadIdx.x & 63;
    int g = lane >> 4, sub = lane & 15;
    constexpr int HC = H * 128;
    int n = blockIdx.x * NPB + slot;
    bool act = n < Nn;
    int nn = act ? n : 0;

    const float* xrp = xr + (size_t)nn * HC + h * 128 + sub * 8;
    float4 xr0 = *(const float4*)xrp, xr1 = *(const float4*)(xrp + 4);
    const float* ap = att + h * 128 + sub * 8;
    float4 a0 = *(const float4*)ap, a1 = *(const float4*)(ap + 4);

    float den = 0.f;
    float acc[8] = {0.f, 0.f, 0.f, 0.f, 0.f, 0.f, 0.f, 0.f};
    int beg = act ? rowptr[n] : 0, endp = act ? rowptr[n + 1] : 0;

    for (int k0 = beg; k0 < endp; k0 += 4) {
        int k = k0 + g;
        bool ev = k < endp;
        int s = col[ev ? k : beg];
        const float* vp = xl + (size_t)s * HC + h * 128 + sub * 8;
        float4 v0 = *(const float4*)vp, v1 = *(const float4*)(vp + 4);
        float p;
        p = lrelu_f(v0.x + xr0.x) * a0.x;
        p = fmaf(lrelu_f(v0.y + xr0.y), a0.y, p);
        p = fmaf(lrelu_f(v0.z + xr0.z), a0.z, p);
        p = fmaf(lrelu_f(v0.w + xr0.w), a0.w, p);
        p = fmaf(lrelu_f(v1.x + xr1.x), a1.x, p);
        p = fmaf(lrelu_f(v1.y + xr1.y), a1.y, p);
        p = fmaf(lrelu_f(v1.z + xr1.z), a1.z, p);
        p = fmaf(lrelu_f(v1.w + xr1.w), a1.w, p);
        p += __shfl_xor(p, 1, 64);
        p += __shfl_xor(p, 2, 64);
        p += __shfl_xor(p, 4, 64);
        p += __shfl_xor(p, 8, 64);
        float pe = ev ? __expf(p) : 0.f;
        den += pe;
        acc[0] = fmaf(pe, v0.x, acc[0]);
        acc[1] = fmaf(pe, v0.y, acc[1]);
        acc[2] = fmaf(pe, v0.z, acc[2]);
        acc[3] = fmaf(pe, v0.w, acc[3]);
        acc[4] = fmaf(pe, v1.x, acc[4]);
        acc[5] = fmaf(pe, v1.y, acc[5]);
        acc[6] = fmaf(pe, v1.z, acc[6]);
        acc[7] = fmaf(pe, v1.w, acc[7]);
    }
#pragma unroll
    for (int off = 16; off <= 32; off <<= 1) {
        den += __shfl_xor(den, off, 64);
#pragma unroll
        for (int j = 0; j < 8; j++) acc[j] += __shfl_xor(acc[j], off, 64);
    }
    float inv = 1.0f / (den + 1e-16f);

    if constexpr (H == 1) {
        if (act && g == 0) {
            const float* bp = bo + sub * 8;
            f32x4 o0 = {acc[0] * inv + bp[0], acc[1] * inv + bp[1], acc[2] * inv + bp[2], acc[3] * inv + bp[3]};
            f32x4 o1 = {acc[4] * inv + bp[4], acc[5] * inv + bp[5], acc[6] * inv + bp[6], acc[7] * inv + bp[7]};
            *(f32x4*)(y + (size_t)n * 128 + sub * 8) = o0;
            *(f32x4*)(y + (size_t)n * 128 + sub * 8 + 4) = o1;
        }
    } else {
        __shared__ float sh[NPB][2][128];
        if (g == 0) {
#pragma unroll
            for (int j = 0; j < 8; j++) sh[slot][h][sub * 8 + j] = acc[j] * inv;
        }
        __syncthreads();
        int t = threadIdx.x;
        int slot2 = t >> 7, c = t & 127;
        int n2 = blockIdx.x * NPB + slot2;
        if (n2 < Nn)
            y[(size_t)n2 * 128 + c] = (sh[slot2][0][c] + sh[slot2][1][c]) * 0.5f + bo[c];
    }
}

// ---------------- GraphNorm stats: per-channel sum & sumsq -----------------------
__global__ void gn_stats_k(const float* __restrict__ y, float* __restrict__ stats, int Nn) {
    int c = threadIdx.x;  // 128 threads
    int per = (Nn + gridDim.x - 1) / gridDim.x;
    int n0 = blockIdx.x * per, n1 = min(n0 + per, Nn);
    float s = 0.f, s2 = 0.f;
    for (int n = n0; n < n1; n++) {
        float v = y[(size_t)n * 128 + c];
        s += v;
        s2 = fmaf(v, v, s2);
    }
    atomicAdd(&stats[c], s);
    atomicAdd(&stats[128 + c], s2);
}

// ---------------- GraphNorm apply + GELU, f32 out --------------------------------
__global__ void gn_apply_k(const float* __restrict__ y, const float* __restrict__ stats,
                           const float* __restrict__ w, const float* __restrict__ b,
                           const float* __restrict__ ms, float* __restrict__ xo, int Nn) {
    int i4 = blockIdx.x * blockDim.x + threadIdx.x;
    if (i4 >= Nn * 32) return;
    float4 v = reinterpret_cast<const float4*>(y)[i4];
    int c0 = (i4 & 31) * 4;
    float o[4] = {v.x, v.y, v.z, v.w};
    float invN = 1.0f / (float)Nn;
#pragma unroll
    for (int jj = 0; jj < 4; jj++) {
        int c = c0 + jj;
        float mu = stats[c] * invN;
        float ex2 = stats[128 + c] * invN;
        float msv = ms[c];
        float var = ex2 - 2.f * msv * mu * mu + msv * msv * mu * mu;
        float ov = o[jj] - msv * mu;
        float r = rsqrtf(var + 1e-5f);
        o[jj] = gelu_f(fmaf(w[c], ov * r, b[c]));
    }
    float4 res = make_float4(o[0], o[1], o[2], o[3]);
    reinterpret_cast<float4*>(xo)[i4] = res;
}

// ---------------- final head: out = h@W_h2 + b_h2 (OUT=3) ------------------------
__global__ void head2_k(const float* __restrict__ h, const float* __restrict__ W,
                        const float* __restrict__ b, float* __restrict__ out, int Nn) {
    __shared__ float w[192];
    __shared__ float bb[3];
    int t = threadIdx.x;
    if (t < 192) w[t] = W[t];
    if (t < 3) bb[t] = b[t];
    __syncthreads();
    int n = blockIdx.x * blockDim.x + t;
    if (n >= Nn) return;
    float a0 = bb[0], a1 = bb[1], a2 = bb[2];
    const float4* h4 = reinterpret_cast<const float4*>(h + (size_t)n * 64);
    for (int k4 = 0; k4 < 16; k4++) {
        float4 v = h4[k4];
        int k = k4 * 4;
        a0 = fmaf(v.x, w[(k + 0) * 3 + 0], a0); a1 = fmaf(v.x, w[(k + 0) * 3 + 1], a1); a2 = fmaf(v.x, w[(k + 0) * 3 + 2], a2);
        a0 = fmaf(v.y, w[(k + 1) * 3 + 0], a0); a1 = fmaf(v.y, w[(k + 1) * 3 + 1], a1); a2 = fmaf(v.y, w[(k + 1) * 3 + 2], a2);
        a0 = fmaf(v.z, w[(k + 2) * 3 + 0], a0); a1 = fmaf(v.z, w[(k + 2) * 3 + 1], a1); a2 = fmaf(v.z, w[(k + 2) * 3 + 2], a2);
        a0 = fmaf(v.w, w[(k + 3) * 3 + 0], a0); a1 = fmaf(v.w, w[(k + 3) * 3 + 1], a1); a2 = fmaf(v.w, w[(k + 3) * 3 + 2], a2);
    }
    out[n * 3 + 0] = a0;
    out[n * 3 + 1] = a1;
    out[n * 3 + 2] = a2;
}

extern "C" void kernel_launch(void* const* d_in, const int* in_sizes, int n_in,
                              void* d_out, int out_size, void* d_ws, size_t ws_size,
                              hipStream_t stream) {
    const float* zg = (const float*)d_in[0];
    const int* ei = (const int*)d_in[1];
    const float* tv = (const float*)d_in[2];
    const float* W_ne1 = (const float*)d_in[3];
    const float* b_ne1 = (const float*)d_in[4];
    const float* W_ne2 = (const float*)d_in[5];
    const float* b_ne2 = (const float*)d_in[6];
    const float* W_s1 = (const float*)d_in[7];
    const float* b_s1 = (const float*)d_in[8];
    const float* W_s2 = (const float*)d_in[9];
    const float* b_s2 = (const float*)d_in[10];
    const float *Wl[3], *bl[3], *Wr[3], *br[3], *attp[3], *bop[3], *gnw[3], *gnb[3], *gnms[3];
    for (int L = 0; L < 3; L++) {
        int base = 11 + L * 9;
        Wl[L] = (const float*)d_in[base + 0];
        bl[L] = (const float*)d_in[base + 1];
        Wr[L] = (const float*)d_in[base + 2];
        br[L] = (const float*)d_in[base + 3];
        attp[L] = (const float*)d_in[base + 4];
        bop[L] = (const float*)d_in[base + 5];
        gnw[L] = (const float*)d_in[base + 6];
        gnb[L] = (const float*)d_in[base + 7];
        gnms[L] = (const float*)d_in[base + 8];
    }
    const float* W_h1 = (const float*)d_in[38];
    const float* b_h1 = (const float*)d_in[39];
    const float* W_h2 = (const float*)d_in[40];
    const float* b_h2 = (const float*)d_in[41];

    int E = in_sizes[1] / 2;
    int N = in_sizes[2] / 3;
    int EP = E + N;
    const int* srcp = ei;
    const int* dstp = ei + E;

    char* p = (char*)d_ws;
    auto alloc = [&](size_t bytes) -> char* {
        char* r = p;
        p += (bytes + 255) & ~(size_t)255;
        return r;
    };
    float* style = (float*)alloc(512);
    float* h1 = (float*)alloc((size_t)N * 128 * 4);
    float* x = (float*)alloc((size_t)N * 128 * 4);
    float* xle = (float*)alloc((size_t)N * 256 * 4);
    float* xre = (float*)alloc((size_t)N * 256 * 4);
    float* y = (float*)alloc((size_t)N * 128 * 4);
    float* hb = (float*)alloc((size_t)N * 64 * 4);
    float* stats = (float*)alloc(1024);
    int* rowptr = (int*)alloc(((size_t)N + 1) * 4);
    int* counts = (int*)alloc((size_t)N * 4);
    int* fillc = (int*)alloc((size_t)N * 4);
    int* col = (int*)alloc((size_t)EP * 4);
    unsigned short* wth = (unsigned short*)alloc((size_t)188416 * 2);
    unsigned short* wtl = (unsigned short*)alloc((size_t)188416 * 2);

    // weight prep: 8 segments, K=128 all, hi/lo pairs
    PrepArgs pa;
    const float* srcs[8] = {W_ne2, Wl[0], Wr[0], Wl[1], Wr[1], Wl[2], Wr[2], W_h1};
    int outs[8] = {128, 256, 256, 256, 256, 128, 128, 64};
    int off = 0;
    for (int s = 0; s < 8; s++) {
        pa.src[s] = srcs[s];
        pa.dsth[s] = wth + off;
        pa.dstl[s] = wtl + off;
        pa.off[s] = off;
        pa.shift[s] = (outs[s] == 256) ? 8 : (outs[s] == 128 ? 7 : 6);
        off += 128 * outs[s];
    }
    pa.off[8] = off;
    unsigned short *wh_ne2 = pa.dsth[0], *wl_ne2 = pa.dstl[0];
    unsigned short *wh_l[3] = {pa.dsth[1], pa.dsth[3], pa.dsth[5]};
    unsigned short *wl_l[3] = {pa.dstl[1], pa.dstl[3], pa.dstl[5]};
    unsigned short *wh_r[3] = {pa.dsth[2], pa.dsth[4], pa.dsth[6]};
    unsigned short *wl_r[3] = {pa.dstl[2], pa.dstl[4], pa.dstl[6]};
    unsigned short *wh_h1 = pa.dsth[7], *wl_h1 = pa.dstl[7];
    prep_k<<<(off + 255) / 256, 256, 0, stream>>>(pa);

    // style + node embedding
    style_k<<<1, 128, 0, stream>>>(zg, W_s1, b_s1, W_s2, b_s2, style);
    ne1_k<<<(N * 128 + 255) / 256, 256, 0, stream>>>(tv, W_ne1, b_ne1, h1, N);
    mfma_lin_k<128, 1, false><<<(N + 31) / 32, 256, 0, stream>>>(
        h1, wh_ne2, wl_ne2, b_ne2, nullptr, nullptr, nullptr, style, x, nullptr, N);

    // CSR by destination (rebuilt every launch)
    hipMemsetAsync(counts, 0, (size_t)N * 4, stream);
    hipMemsetAsync(fillc, 0, (size_t)N * 4, stream);
    count_k<<<(EP + 255) / 256, 256, 0, stream>>>(dstp, counts, E, EP);
    scan_k<<<1, 1024, 0, stream>>>(counts, rowptr, N, EP);
    fill_k<<<(EP + 255) / 256, 256, 0, stream>>>(srcp, dstp, rowptr, fillc, col, E, EP);

    const int HS[3] = {2, 2, 1};
    for (int L = 0; L < 3; L++) {
        if (HS[L] == 2) {
            mfma_lin_k<256, 0, true><<<(N + 31) / 32, 256, 0, stream>>>(
                x, wh_l[L], wl_l[L], bl[L], wh_r[L], wl_r[L], br[L], nullptr, xle, xre, N);
            gat_gather_k<2><<<(N + 1) / 2, 256, 0, stream>>>(xle, xre, attp[L], bop[L], rowptr, col, y, N);
        } else {
            mfma_lin_k<128, 0, true><<<(N + 31) / 32, 256, 0, stream>>>(
                x, wh_l[L], wl_l[L], bl[L], wh_r[L], wl_r[L], br[L], nullptr, xle, xre, N);
            gat_gather_k<1><<<(N + 3) / 4, 256, 0, stream>>>(xle, xre, attp[L], bop[L], rowptr, col, y, N);
        }
        hipMemsetAsync(stats, 0, 1024, stream);
        gn_stats_k<<<512, 128, 0, stream>>>(y, stats, N);
        gn_apply_k<<<(N * 32 + 255) / 256, 256, 0, stream>>>(y, stats, gnw[L], gnb[L], gnms[L], x, N);
    }

    // head: h = gelu(x@W_h1+b_h1) (split-MFMA, f32 out); out = h@W_h2 + b_h2
    mfma_lin_k<64, 2, false><<<(N + 31) / 32, 256, 0, stream>>>(
        x, wh_h1, wl_h1, b_h1, nullptr, nullptr, nullptr, nullptr, hb, nullptr, N);
    head2_k<<<(N + 255) / 256, 256, 0, stream>>>(hb, W_h2, b_h2, (float*)d_out, N);
}

// Round 7
// 765.257 us; speedup vs baseline: 1.1798x; 1.1798x over previous
//
#include <hip/hip_runtime.h>
#include <math.h>

#define DEVINL __device__ __forceinline__

using bf16x8 = __attribute__((ext_vector_type(8))) short;
using f32x4  = __attribute__((ext_vector_type(4))) float;

DEVINL float gelu_f(float v) { return 0.5f * v * (1.0f + erff(v * 0.7071067811865475f)); }
DEVINL float lrelu_f(float v) { return v > 0.0f ? v : 0.2f * v; }
DEVINL unsigned short f2bf(float f) {
    union { float f; unsigned u; } c; c.f = f;
    unsigned r = c.u + 0x7fffu + ((c.u >> 16) & 1u);
    return (unsigned short)(r >> 16);
}
DEVINL float bf2f(unsigned short s) {
    union { unsigned u; float f; } c; c.u = (unsigned)s << 16;
    return c.f;
}
DEVINL void gl_lds16(const void* g, void* l) {
    __builtin_amdgcn_global_load_lds(
        (const __attribute__((address_space(1))) unsigned*)g,
        (__attribute__((address_space(3))) unsigned*)l, 16, 0, 0);
}

// ---------------- style: style = gelu(z_g@W_s1+b_s1)@W_s2 + b_s2 ----------------
__global__ void style_k(const float* __restrict__ zg, const float* __restrict__ W1,
                        const float* __restrict__ b1, const float* __restrict__ W2,
                        const float* __restrict__ b2, float* __restrict__ style) {
    __shared__ float s1[128];
    int j = threadIdx.x;
    float a = b1[j];
    for (int k = 0; k < 256; k++) a = fmaf(zg[k], W1[k * 128 + j], a);
    s1[j] = gelu_f(a);
    __syncthreads();
    float o = b2[j];
    for (int k = 0; k < 128; k++) o = fmaf(s1[k], W2[k * 128 + j], o);
    style[j] = o;
}

// ---------------- node-embed layer 1: h1 = gelu(tv@W_ne1 + b_ne1), f32 out ------
__global__ void ne1_k(const float* __restrict__ tv, const float* __restrict__ W,
                      const float* __restrict__ b, float* __restrict__ h1, int Nn) {
    int idx = blockIdx.x * blockDim.x + threadIdx.x;
    if (idx >= Nn * 128) return;
    int n = idx >> 7, c = idx & 127;
    float o = fmaf(tv[n * 3 + 0], W[c],
              fmaf(tv[n * 3 + 1], W[128 + c],
              fmaf(tv[n * 3 + 2], W[256 + c], b[c])));
    h1[idx] = gelu_f(o);
}

// -------- weight prep: f32 W[128][OUT] -> staged fragment-order hi/lo chunks -----
// Per 16-col chunk c: 4096 shorts: hi at [s2(4)][lane(64)][8], lo at +2048.
// lane = lk*16+lr holds row j0+lr, k = s2*32+lk*8+i.
struct PrepArgs {
    const float* src[8];
    unsigned short* dst;
    int dstoff[8];  // in shorts
    int off[9];     // source element offsets
    int shift[8];   // log2(OUT)
};
__global__ void prep_k(PrepArgs a) {
    int idx = blockIdx.x * 256 + threadIdx.x;
    if (idx >= a.off[8]) return;
    int s = 0;
    while (idx >= a.off[s + 1]) s++;
    int e = idx - a.off[s];
    int sh = a.shift[s];
    int k = e >> sh, j = e & ((1 << sh) - 1);
    float w = a.src[s][e];
    unsigned short hi = f2bf(w);
    unsigned short lo = f2bf(w - bf2f(hi));
    int c = j >> 4, lr = j & 15;
    int s2 = k >> 5, lk = (k >> 3) & 3, i = k & 7;
    int lane = lk * 16 + lr;
    size_t base = (size_t)a.dstoff[s] + (size_t)c * 4096 + s2 * 512 + lane * 8 + i;
    a.dst[base] = hi;
    a.dst[base + 2048] = lo;
}

// ---------------- split-MFMA linear: LDS double-buffered weight chunks -----------
// Block = 4 waves x 32 rows = 128 rows. Chunk (16 out-cols, hi+lo = 8KB) staged
// via global_load_lds into buf[2]; counted vmcnt(2) keeps the prefetch in flight
// across raw s_barriers (never drain mid-loop). 3 MFMAs/subtile: Wh*xh+Wh*xl+Wl*xh.
template <int OUT, int EPI, bool DUAL>  // EPI 0:bias 1:+style 2:+gelu
__global__ __launch_bounds__(256) void mfma_lin_k(
    const float* __restrict__ xin,
    const unsigned short* __restrict__ WT0, const float* __restrict__ b0,
    const unsigned short* __restrict__ WT1, const float* __restrict__ b1,
    const float* __restrict__ style,
    float* __restrict__ out0, float* __restrict__ out1, int Nn) {
    constexpr int CPM = OUT / 16;
    constexpr int NCH = (DUAL ? 2 : 1) * CPM;
    __shared__ uint4 buf[2][512];  // 2 x 8KB
    int t = threadIdx.x;
    int wave = t >> 6, lane = t & 63;
    int lr = lane & 15, lk = lane >> 4;
    int base = blockIdx.x * 128 + wave * 32;
    int r0 = base + lr, r1 = base + 16 + lr;
    int cr0 = min(r0, Nn - 1), cr1 = min(r1, Nn - 1);

    bf16x8 xh[2][4], xlo[2][4];
#pragma unroll
    for (int rr = 0; rr < 2; rr++) {
        const float* px = xin + (size_t)(rr ? cr1 : cr0) * 128;
#pragma unroll
        for (int s = 0; s < 4; s++) {
            const float4* p4 = (const float4*)(px + s * 32 + lk * 8);
            float4 a = p4[0], b = p4[1];
            float v[8] = {a.x, a.y, a.z, a.w, b.x, b.y, b.z, b.w};
            bf16x8 h, l;
#pragma unroll
            for (int i = 0; i < 8; i++) {
                unsigned short hb = f2bf(v[i]);
                h[i] = (short)hb;
                l[i] = (short)f2bf(v[i] - bf2f(hb));
            }
            xh[rr][s] = h;
            xlo[rr][s] = l;
        }
    }

    auto stage = [&](int c, int bsel) {
        const unsigned short* Wt = (DUAL && c >= CPM) ? WT1 : WT0;
        int cc = (DUAL && c >= CPM) ? c - CPM : c;
        const char* g = (const char*)(Wt + (size_t)cc * 4096);
        char* l = (char*)&buf[bsel][0];
        gl_lds16(g + t * 16, l + wave * 1024);
        gl_lds16(g + 4096 + t * 16, l + 4096 + wave * 1024);
    };

    stage(0, 0);
    for (int c = 0; c < NCH; ++c) {
        int cur = c & 1;
        bool pre = (c + 1 < NCH);
        if (pre) stage(c + 1, cur ^ 1);
        if (pre) asm volatile("s_waitcnt vmcnt(2)" ::: "memory");
        else     asm volatile("s_waitcnt vmcnt(0)" ::: "memory");
        __builtin_amdgcn_s_barrier();

        int m = (DUAL && c >= CPM) ? 1 : 0;
        int j0 = (c - m * CPM) * 16;
        const float* bias = m ? b1 : b0;
        float* out = m ? out1 : out0;
        const bf16x8* W = (const bf16x8*)&buf[cur][0];

        f32x4 acc0 = {0.f, 0.f, 0.f, 0.f}, acc1 = {0.f, 0.f, 0.f, 0.f};
#pragma unroll
        for (int s = 0; s < 4; ++s) {
            bf16x8 wh = W[s * 64 + lane];
            bf16x8 wl = W[256 + s * 64 + lane];
            acc0 = __builtin_amdgcn_mfma_f32_16x16x32_bf16(wh, xh[0][s], acc0, 0, 0, 0);
            acc0 = __builtin_amdgcn_mfma_f32_16x16x32_bf16(wh, xlo[0][s], acc0, 0, 0, 0);
            acc0 = __builtin_amdgcn_mfma_f32_16x16x32_bf16(wl, xh[0][s], acc0, 0, 0, 0);
            acc1 = __builtin_amdgcn_mfma_f32_16x16x32_bf16(wh, xh[1][s], acc1, 0, 0, 0);
            acc1 = __builtin_amdgcn_mfma_f32_16x16x32_bf16(wh, xlo[1][s], acc1, 0, 0, 0);
            acc1 = __builtin_amdgcn_mfma_f32_16x16x32_bf16(wl, xh[1][s], acc1, 0, 0, 0);
        }
        int j = j0 + lk * 4;
        float o0[4], o1[4];
#pragma unroll
        for (int i = 0; i < 4; i++) {
            float bb = bias[j + i];
            if (EPI == 1) bb += style[j + i];
            float v0 = acc0[i] + bb, v1 = acc1[i] + bb;
            if (EPI == 2) { v0 = gelu_f(v0); v1 = gelu_f(v1); }
            o0[i] = v0; o1[i] = v1;
        }
        if (r0 < Nn) { f32x4 v = {o0[0], o0[1], o0[2], o0[3]}; *(f32x4*)(out + (size_t)r0 * OUT + j) = v; }
        if (r1 < Nn) { f32x4 v = {o1[0], o1[1], o1[2], o1[3]}; *(f32x4*)(out + (size_t)r1 * OUT + j) = v; }
        __builtin_amdgcn_s_barrier();
    }
}

// ---------------- CSR build (by destination), self-loops appended ----------------
__global__ void count_k(const int* __restrict__ dst, int* __restrict__ counts, int E, int EP) {
    int e = blockIdx.x * blockDim.x + threadIdx.x;
    if (e >= EP) return;
    int d = (e < E) ? dst[e] : (e - E);
    atomicAdd(&counts[d], 1);
}

__global__ void scan_k(const int* __restrict__ counts, int* __restrict__ rowptr, int Nn, int total) {
    __shared__ int part[1024];
    int tid = threadIdx.x;
    int chunk = (Nn + 1023) >> 10;
    int s = tid * chunk, e = min(s + chunk, Nn);
    int loc = 0;
    for (int i = s; i < e; i++) loc += counts[i];
    part[tid] = loc;
    __syncthreads();
    for (int off = 1; off < 1024; off <<= 1) {
        int v = (tid >= off) ? part[tid - off] : 0;
        __syncthreads();
        part[tid] += v;
        __syncthreads();
    }
    int run = part[tid] - loc;  // exclusive
    for (int i = s; i < e; i++) { rowptr[i] = run; run += counts[i]; }
    if (e == Nn) rowptr[Nn] = total;
}

__global__ void fill_k(const int* __restrict__ src, const int* __restrict__ dst,
                       const int* __restrict__ rowptr, int* __restrict__ fillc,
                       int* __restrict__ col, int E, int EP) {
    int e = blockIdx.x * blockDim.x + threadIdx.x;
    if (e >= EP) return;
    int d = (e < E) ? dst[e] : (e - E);
    int s = (e < E) ? src[e] : (e - E);
    int pos = atomicAdd(&fillc[d], 1);
    col[rowptr[d] + pos] = s;
}

// ---------------- GATv2 gather: 4 edges/iter, 16 lanes x 8ch each, f32 -----------
template <int H>
__global__ __launch_bounds__(256) void gat_gather_k(
    const float* __restrict__ xl, const float* __restrict__ xr,
    const float* __restrict__ att, const float* __restrict__ bo,
    const int* __restrict__ rowptr, const int* __restrict__ col,
    float* __restrict__ y, int Nn) {
    constexpr int NPB = (H == 2) ? 2 : 4;   // nodes per block (4 waves)
    int w = threadIdx.x >> 6;
    int slot = (H == 2) ? (w >> 1) : w;
    int h = (H == 2) ? (w & 1) : 0;
    int lane = threadIdx.x & 63;
    int g = lane >> 4, sub = lane & 15;
    constexpr int HC = H * 128;
    int n = blockIdx.x * NPB + slot;
    bool act = n < Nn;
    int nn = act ? n : 0;

    const float* xrp = xr + (size_t)nn * HC + h * 128 + sub * 8;
    float4 xr0 = *(const float4*)xrp, xr1 = *(const float4*)(xrp + 4);
    const float* ap = att + h * 128 + sub * 8;
    float4 a0 = *(const float4*)ap, a1 = *(const float4*)(ap + 4);

    float den = 0.f;
    float acc[8] = {0.f, 0.f, 0.f, 0.f, 0.f, 0.f, 0.f, 0.f};
    int beg = act ? rowptr[n] : 0, endp = act ? rowptr[n + 1] : 0;

    for (int k0 = beg; k0 < endp; k0 += 4) {
        int k = k0 + g;
        bool ev = k < endp;
        int s = col[ev ? k : beg];
        const float* vp = xl + (size_t)s * HC + h * 128 + sub * 8;
        float4 v0 = *(const float4*)vp, v1 = *(const float4*)(vp + 4);
        float p;
        p = lrelu_f(v0.x + xr0.x) * a0.x;
        p = fmaf(lrelu_f(v0.y + xr0.y), a0.y, p);
        p = fmaf(lrelu_f(v0.z + xr0.z), a0.z, p);
        p = fmaf(lrelu_f(v0.w + xr0.w), a0.w, p);
        p = fmaf(lrelu_f(v1.x + xr1.x), a1.x, p);
        p = fmaf(lrelu_f(v1.y + xr1.y), a1.y, p);
        p = fmaf(lrelu_f(v1.z + xr1.z), a1.z, p);
        p = fmaf(lrelu_f(v1.w + xr1.w), a1.w, p);
        p += __shfl_xor(p, 1, 64);
        p += __shfl_xor(p, 2, 64);
        p += __shfl_xor(p, 4, 64);
        p += __shfl_xor(p, 8, 64);
        float pe = ev ? __expf(p) : 0.f;
        den += pe;
        acc[0] = fmaf(pe, v0.x, acc[0]);
        acc[1] = fmaf(pe, v0.y, acc[1]);
        acc[2] = fmaf(pe, v0.z, acc[2]);
        acc[3] = fmaf(pe, v0.w, acc[3]);
        acc[4] = fmaf(pe, v1.x, acc[4]);
        acc[5] = fmaf(pe, v1.y, acc[5]);
        acc[6] = fmaf(pe, v1.z, acc[6]);
        acc[7] = fmaf(pe, v1.w, acc[7]);
    }
#pragma unroll
    for (int off = 16; off <= 32; off <<= 1) {
        den += __shfl_xor(den, off, 64);
#pragma unroll
        for (int j = 0; j < 8; j++) acc[j] += __shfl_xor(acc[j], off, 64);
    }
    float inv = 1.0f / (den + 1e-16f);

    if constexpr (H == 1) {
        if (act && g == 0) {
            const float* bp = bo + sub * 8;
            f32x4 o0 = {acc[0] * inv + bp[0], acc[1] * inv + bp[1], acc[2] * inv + bp[2], acc[3] * inv + bp[3]};
            f32x4 o1 = {acc[4] * inv + bp[4], acc[5] * inv + bp[5], acc[6] * inv + bp[6], acc[7] * inv + bp[7]};
            *(f32x4*)(y + (size_t)n * 128 + sub * 8) = o0;
            *(f32x4*)(y + (size_t)n * 128 + sub * 8 + 4) = o1;
        }
    } else {
        __shared__ float sh[NPB][2][128];
        if (g == 0) {
#pragma unroll
            for (int j = 0; j < 8; j++) sh[slot][h][sub * 8 + j] = acc[j] * inv;
        }
        __syncthreads();
        int t = threadIdx.x;
        int slot2 = t >> 7, c = t & 127;
        int n2 = blockIdx.x * NPB + slot2;
        if (n2 < Nn)
            y[(size_t)n2 * 128 + c] = (sh[slot2][0][c] + sh[slot2][1][c]) * 0.5f + bo[c];
    }
}

// ---------------- GraphNorm stats: per-channel sum & sumsq -----------------------
__global__ void gn_stats_k(const float* __restrict__ y, float* __restrict__ stats, int Nn) {
    int c = threadIdx.x;  // 128 threads
    int per = (Nn + gridDim.x - 1) / gridDim.x;
    int n0 = blockIdx.x * per, n1 = min(n0 + per, Nn);
    float s = 0.f, s2 = 0.f;
    for (int n = n0; n < n1; n++) {
        float v = y[(size_t)n * 128 + c];
        s += v;
        s2 = fmaf(v, v, s2);
    }
    atomicAdd(&stats[c], s);
    atomicAdd(&stats[128 + c], s2);
}

// ---------------- GraphNorm apply + GELU, f32 out --------------------------------
__global__ void gn_apply_k(const float* __restrict__ y, const float* __restrict__ stats,
                           const float* __restrict__ w, const float* __restrict__ b,
                           const float* __restrict__ ms, float* __restrict__ xo, int Nn) {
    int i4 = blockIdx.x * blockDim.x + threadIdx.x;
    if (i4 >= Nn * 32) return;
    float4 v = reinterpret_cast<const float4*>(y)[i4];
    int c0 = (i4 & 31) * 4;
    float o[4] = {v.x, v.y, v.z, v.w};
    float invN = 1.0f / (float)Nn;
#pragma unroll
    for (int jj = 0; jj < 4; jj++) {
        int c = c0 + jj;
        float mu = stats[c] * invN;
        float ex2 = stats[128 + c] * invN;
        float msv = ms[c];
        float var = ex2 - 2.f * msv * mu * mu + msv * msv * mu * mu;
        float ov = o[jj] - msv * mu;
        float r = rsqrtf(var + 1e-5f);
        o[jj] = gelu_f(fmaf(w[c], ov * r, b[c]));
    }
    float4 res = make_float4(o[0], o[1], o[2], o[3]);
    reinterpret_cast<float4*>(xo)[i4] = res;
}

// ---------------- final head: out = h@W_h2 + b_h2 (OUT=3) ------------------------
__global__ void head2_k(const float* __restrict__ h, const float* __restrict__ W,
                        const float* __restrict__ b, float* __restrict__ out, int Nn) {
    __shared__ float w[192];
    __shared__ float bb[3];
    int t = threadIdx.x;
    if (t < 192) w[t] = W[t];
    if (t < 3) bb[t] = b[t];
    __syncthreads();
    int n = blockIdx.x * blockDim.x + t;
    if (n >= Nn) return;
    float a0 = bb[0], a1 = bb[1], a2 = bb[2];
    const float4* h4 = reinterpret_cast<const float4*>(h + (size_t)n * 64);
    for (int k4 = 0; k4 < 16; k4++) {
        float4 v = h4[k4];
        int k = k4 * 4;
        a0 = fmaf(v.x, w[(k + 0) * 3 + 0], a0); a1 = fmaf(v.x, w[(k + 0) * 3 + 1], a1); a2 = fmaf(v.x, w[(k + 0) * 3 + 2], a2);
        a0 = fmaf(v.y, w[(k + 1) * 3 + 0], a0); a1 = fmaf(v.y, w[(k + 1) * 3 + 1], a1); a2 = fmaf(v.y, w[(k + 1) * 3 + 2], a2);
        a0 = fmaf(v.z, w[(k + 2) * 3 + 0], a0); a1 = fmaf(v.z, w[(k + 2) * 3 + 1], a1); a2 = fmaf(v.z, w[(k + 2) * 3 + 2], a2);
        a0 = fmaf(v.w, w[(k + 3) * 3 + 0], a0); a1 = fmaf(v.w, w[(k + 3) * 3 + 1], a1); a2 = fmaf(v.w, w[(k + 3) * 3 + 2], a2);
    }
    out[n * 3 + 0] = a0;
    out[n * 3 + 1] = a1;
    out[n * 3 + 2] = a2;
}

extern "C" void kernel_launch(void* const* d_in, const int* in_sizes, int n_in,
                              void* d_out, int out_size, void* d_ws, size_t ws_size,
                              hipStream_t stream) {
    const float* zg = (const float*)d_in[0];
    const int* ei = (const int*)d_in[1];
    const float* tv = (const float*)d_in[2];
    const float* W_ne1 = (const float*)d_in[3];
    const float* b_ne1 = (const float*)d_in[4];
    const float* W_ne2 = (const float*)d_in[5];
    const float* b_ne2 = (const float*)d_in[6];
    const float* W_s1 = (const float*)d_in[7];
    const float* b_s1 = (const float*)d_in[8];
    const float* W_s2 = (const float*)d_in[9];
    const float* b_s2 = (const float*)d_in[10];
    const float *Wl[3], *bl[3], *Wr[3], *br[3], *attp[3], *bop[3], *gnw[3], *gnb[3], *gnms[3];
    for (int L = 0; L < 3; L++) {
        int base = 11 + L * 9;
        Wl[L] = (const float*)d_in[base + 0];
        bl[L] = (const float*)d_in[base + 1];
        Wr[L] = (const float*)d_in[base + 2];
        br[L] = (const float*)d_in[base + 3];
        attp[L] = (const float*)d_in[base + 4];
        bop[L] = (const float*)d_in[base + 5];
        gnw[L] = (const float*)d_in[base + 6];
        gnb[L] = (const float*)d_in[base + 7];
        gnms[L] = (const float*)d_in[base + 8];
    }
    const float* W_h1 = (const float*)d_in[38];
    const float* b_h1 = (const float*)d_in[39];
    const float* W_h2 = (const float*)d_in[40];
    const float* b_h2 = (const float*)d_in[41];

    int E = in_sizes[1] / 2;
    int N = in_sizes[2] / 3;
    int EP = E + N;
    const int* srcp = ei;
    const int* dstp = ei + E;

    char* p = (char*)d_ws;
    auto alloc = [&](size_t bytes) -> char* {
        char* r = p;
        p += (bytes + 255) & ~(size_t)255;
        return r;
    };
    float* style = (float*)alloc(512);
    float* h1 = (float*)alloc((size_t)N * 128 * 4);
    float* x = (float*)alloc((size_t)N * 128 * 4);
    float* xle = (float*)alloc((size_t)N * 256 * 4);
    float* xre = (float*)alloc((size_t)N * 256 * 4);
    float* y = (float*)alloc((size_t)N * 128 * 4);
    float* hb = (float*)alloc((size_t)N * 64 * 4);
    float* stats = (float*)alloc(1024);
    int* rowptr = (int*)alloc(((size_t)N + 1) * 4);
    int* counts = (int*)alloc((size_t)N * 4);
    int* fillc = (int*)alloc((size_t)N * 4);
    int* col = (int*)alloc((size_t)EP * 4);
    unsigned short* wt = (unsigned short*)alloc((size_t)376832 * 2);

    // weight prep: 8 segments, staged fragment-order hi/lo layout
    PrepArgs pa;
    const float* srcs[8] = {W_ne2, Wl[0], Wr[0], Wl[1], Wr[1], Wl[2], Wr[2], W_h1};
    int outs[8] = {128, 256, 256, 256, 256, 128, 128, 64};
    int off = 0;
    pa.dst = wt;
    for (int s = 0; s < 8; s++) {
        pa.src[s] = srcs[s];
        pa.off[s] = off;
        pa.dstoff[s] = 2 * off;
        pa.shift[s] = (outs[s] == 256) ? 8 : (outs[s] == 128 ? 7 : 6);
        off += 128 * outs[s];
    }
    pa.off[8] = off;
    const unsigned short* ws_ne2 = wt + pa.dstoff[0];
    const unsigned short* ws_l[3] = {wt + pa.dstoff[1], wt + pa.dstoff[3], wt + pa.dstoff[5]};
    const unsigned short* ws_r[3] = {wt + pa.dstoff[2], wt + pa.dstoff[4], wt + pa.dstoff[6]};
    const unsigned short* ws_h1 = wt + pa.dstoff[7];
    prep_k<<<(off + 255) / 256, 256, 0, stream>>>(pa);

    // style + node embedding
    style_k<<<1, 128, 0, stream>>>(zg, W_s1, b_s1, W_s2, b_s2, style);
    ne1_k<<<(N * 128 + 255) / 256, 256, 0, stream>>>(tv, W_ne1, b_ne1, h1, N);
    mfma_lin_k<128, 1, false><<<(N + 127) / 128, 256, 0, stream>>>(
        h1, ws_ne2, b_ne2, nullptr, nullptr, style, x, nullptr, N);

    // CSR by destination (rebuilt every launch)
    hipMemsetAsync(counts, 0, (size_t)N * 4, stream);
    hipMemsetAsync(fillc, 0, (size_t)N * 4, stream);
    count_k<<<(EP + 255) / 256, 256, 0, stream>>>(dstp, counts, E, EP);
    scan_k<<<1, 1024, 0, stream>>>(counts, rowptr, N, EP);
    fill_k<<<(EP + 255) / 256, 256, 0, stream>>>(srcp, dstp, rowptr, fillc, col, E, EP);

    const int HS[3] = {2, 2, 1};
    for (int L = 0; L < 3; L++) {
        if (HS[L] == 2) {
            mfma_lin_k<256, 0, true><<<(N + 127) / 128, 256, 0, stream>>>(
                x, ws_l[L], bl[L], ws_r[L], br[L], nullptr, xle, xre, N);
            gat_gather_k<2><<<(N + 1) / 2, 256, 0, stream>>>(xle, xre, attp[L], bop[L], rowptr, col, y, N);
        } else {
            mfma_lin_k<128, 0, true><<<(N + 127) / 128, 256, 0, stream>>>(
                x, ws_l[L], bl[L], ws_r[L], br[L], nullptr, xle, xre, N);
            gat_gather_k<1><<<(N + 3) / 4, 256, 0, stream>>>(xle, xre, attp[L], bop[L], rowptr, col, y, N);
        }
        hipMemsetAsync(stats, 0, 1024, stream);
        gn_stats_k<<<512, 128, 0, stream>>>(y, stats, N);
        gn_apply_k<<<(N * 32 + 255) / 256, 256, 0, stream>>>(y, stats, gnw[L], gnb[L], gnms[L], x, N);
    }

    // head: h = gelu(x@W_h1+b_h1) (split-MFMA, f32 out); out = h@W_h2 + b_h2
    mfma_lin_k<64, 2, false><<<(N + 127) / 128, 256, 0, stream>>>(
        x, ws_h1, b_h1, nullptr, nullptr, nullptr, hb, nullptr, N);
    head2_k<<<(N + 255) / 256, 256, 0, stream>>>(hb, W_h2, b_h2, (float*)d_out, N);
}

// Round 8
// 704.343 us; speedup vs baseline: 1.2818x; 1.0865x over previous
//
#include <hip/hip_runtime.h>
#include <math.h>

#define DEVINL __device__ __forceinline__

using bf16x8 = __attribute__((ext_vector_type(8))) short;
using f32x4  = __attribute__((ext_vector_type(4))) float;

DEVINL float gelu_f(float v) { return 0.5f * v * (1.0f + erff(v * 0.7071067811865475f)); }
DEVINL float lrelu_f(float v) { return v > 0.0f ? v : 0.2f * v; }
DEVINL unsigned short f2bf(float f) {
    union { float f; unsigned u; } c; c.f = f;
    unsigned r = c.u + 0x7fffu + ((c.u >> 16) & 1u);
    return (unsigned short)(r >> 16);
}
DEVINL float bf2f(unsigned short s) {
    union { unsigned u; float f; } c; c.u = (unsigned)s << 16;
    return c.f;
}
DEVINL void gl_lds16(const void* g, void* l) {
    __builtin_amdgcn_global_load_lds(
        (const __attribute__((address_space(1))) unsigned*)g,
        (__attribute__((address_space(3))) unsigned*)l, 16, 0, 0);
}

// ---------------- style: style = gelu(z_g@W_s1+b_s1)@W_s2 + b_s2 ----------------
__global__ void style_k(const float* __restrict__ zg, const float* __restrict__ W1,
                        const float* __restrict__ b1, const float* __restrict__ W2,
                        const float* __restrict__ b2, float* __restrict__ style) {
    __shared__ float s1[128];
    int j = threadIdx.x;
    float a = b1[j];
    for (int k = 0; k < 256; k++) a = fmaf(zg[k], W1[k * 128 + j], a);
    s1[j] = gelu_f(a);
    __syncthreads();
    float o = b2[j];
    for (int k = 0; k < 128; k++) o = fmaf(s1[k], W2[k * 128 + j], o);
    style[j] = o;
}

// ---------------- node-embed layer 1: h1 = gelu(tv@W_ne1 + b_ne1), f32 out ------
__global__ void ne1_k(const float* __restrict__ tv, const float* __restrict__ W,
                      const float* __restrict__ b, float* __restrict__ h1, int Nn) {
    int idx = blockIdx.x * blockDim.x + threadIdx.x;
    if (idx >= Nn * 128) return;
    int n = idx >> 7, c = idx & 127;
    float o = fmaf(tv[n * 3 + 0], W[c],
              fmaf(tv[n * 3 + 1], W[128 + c],
              fmaf(tv[n * 3 + 2], W[256 + c], b[c])));
    h1[idx] = gelu_f(o);
}

// -------- weight prep: f32 W[128][OUT] -> staged fragment-order hi/lo chunks -----
struct PrepArgs {
    const float* src[8];
    unsigned short* dst;
    int dstoff[8];  // in shorts
    int off[9];     // source element offsets
    int shift[8];   // log2(OUT)
};
__global__ void prep_k(PrepArgs a) {
    int idx = blockIdx.x * 256 + threadIdx.x;
    if (idx >= a.off[8]) return;
    int s = 0;
    while (idx >= a.off[s + 1]) s++;
    int e = idx - a.off[s];
    int sh = a.shift[s];
    int k = e >> sh, j = e & ((1 << sh) - 1);
    float w = a.src[s][e];
    unsigned short hi = f2bf(w);
    unsigned short lo = f2bf(w - bf2f(hi));
    int c = j >> 4, lr = j & 15;
    int s2 = k >> 5, lk = (k >> 3) & 3, i = k & 7;
    int lane = lk * 16 + lr;
    size_t base = (size_t)a.dstoff[s] + (size_t)c * 4096 + s2 * 512 + lane * 8 + i;
    a.dst[base] = hi;
    a.dst[base + 2048] = lo;
}

// ---------------- split-MFMA linear: LDS double-buffered weight chunks -----------
template <int OUT, int EPI, bool DUAL>  // EPI 0:bias 1:+style 2:+gelu
__global__ __launch_bounds__(256) void mfma_lin_k(
    const float* __restrict__ xin,
    const unsigned short* __restrict__ WT0, const float* __restrict__ b0,
    const unsigned short* __restrict__ WT1, const float* __restrict__ b1,
    const float* __restrict__ style,
    float* __restrict__ out0, float* __restrict__ out1, int Nn) {
    constexpr int CPM = OUT / 16;
    constexpr int NCH = (DUAL ? 2 : 1) * CPM;
    __shared__ uint4 buf[2][512];  // 2 x 8KB
    int t = threadIdx.x;
    int wave = t >> 6, lane = t & 63;
    int lr = lane & 15, lk = lane >> 4;
    int base = blockIdx.x * 128 + wave * 32;
    int r0 = base + lr, r1 = base + 16 + lr;
    int cr0 = min(r0, Nn - 1), cr1 = min(r1, Nn - 1);

    bf16x8 xh[2][4], xlo[2][4];
#pragma unroll
    for (int rr = 0; rr < 2; rr++) {
        const float* px = xin + (size_t)(rr ? cr1 : cr0) * 128;
#pragma unroll
        for (int s = 0; s < 4; s++) {
            const float4* p4 = (const float4*)(px + s * 32 + lk * 8);
            float4 a = p4[0], b = p4[1];
            float v[8] = {a.x, a.y, a.z, a.w, b.x, b.y, b.z, b.w};
            bf16x8 h, l;
#pragma unroll
            for (int i = 0; i < 8; i++) {
                unsigned short hb = f2bf(v[i]);
                h[i] = (short)hb;
                l[i] = (short)f2bf(v[i] - bf2f(hb));
            }
            xh[rr][s] = h;
            xlo[rr][s] = l;
        }
    }

    auto stage = [&](int c, int bsel) {
        const unsigned short* Wt = (DUAL && c >= CPM) ? WT1 : WT0;
        int cc = (DUAL && c >= CPM) ? c - CPM : c;
        const char* g = (const char*)(Wt + (size_t)cc * 4096);
        char* l = (char*)&buf[bsel][0];
        gl_lds16(g + t * 16, l + wave * 1024);
        gl_lds16(g + 4096 + t * 16, l + 4096 + wave * 1024);
    };

    stage(0, 0);
    for (int c = 0; c < NCH; ++c) {
        int cur = c & 1;
        bool pre = (c + 1 < NCH);
        if (pre) stage(c + 1, cur ^ 1);
        if (pre) asm volatile("s_waitcnt vmcnt(2)" ::: "memory");
        else     asm volatile("s_waitcnt vmcnt(0)" ::: "memory");
        __builtin_amdgcn_s_barrier();

        int m = (DUAL && c >= CPM) ? 1 : 0;
        int j0 = (c - m * CPM) * 16;
        const float* bias = m ? b1 : b0;
        float* out = m ? out1 : out0;
        const bf16x8* W = (const bf16x8*)&buf[cur][0];

        f32x4 acc0 = {0.f, 0.f, 0.f, 0.f}, acc1 = {0.f, 0.f, 0.f, 0.f};
#pragma unroll
        for (int s = 0; s < 4; ++s) {
            bf16x8 wh = W[s * 64 + lane];
            bf16x8 wl = W[256 + s * 64 + lane];
            acc0 = __builtin_amdgcn_mfma_f32_16x16x32_bf16(wh, xh[0][s], acc0, 0, 0, 0);
            acc0 = __builtin_amdgcn_mfma_f32_16x16x32_bf16(wh, xlo[0][s], acc0, 0, 0, 0);
            acc0 = __builtin_amdgcn_mfma_f32_16x16x32_bf16(wl, xh[0][s], acc0, 0, 0, 0);
            acc1 = __builtin_amdgcn_mfma_f32_16x16x32_bf16(wh, xh[1][s], acc1, 0, 0, 0);
            acc1 = __builtin_amdgcn_mfma_f32_16x16x32_bf16(wh, xlo[1][s], acc1, 0, 0, 0);
            acc1 = __builtin_amdgcn_mfma_f32_16x16x32_bf16(wl, xh[1][s], acc1, 0, 0, 0);
        }
        int j = j0 + lk * 4;
        float o0[4], o1[4];
#pragma unroll
        for (int i = 0; i < 4; i++) {
            float bb = bias[j + i];
            if (EPI == 1) bb += style[j + i];
            float v0 = acc0[i] + bb, v1 = acc1[i] + bb;
            if (EPI == 2) { v0 = gelu_f(v0); v1 = gelu_f(v1); }
            o0[i] = v0; o1[i] = v1;
        }
        if (r0 < Nn) { f32x4 v = {o0[0], o0[1], o0[2], o0[3]}; *(f32x4*)(out + (size_t)r0 * OUT + j) = v; }
        if (r1 < Nn) { f32x4 v = {o1[0], o1[1], o1[2], o1[3]}; *(f32x4*)(out + (size_t)r1 * OUT + j) = v; }
        __builtin_amdgcn_s_barrier();
    }
}

// ---------------- CSR build (by destination), self-loops appended ----------------
__global__ void count_k(const int* __restrict__ dst, int* __restrict__ counts, int E, int EP) {
    int e = blockIdx.x * blockDim.x + threadIdx.x;
    if (e >= EP) return;
    int d = (e < E) ? dst[e] : (e - E);
    atomicAdd(&counts[d], 1);
}

// hierarchical scan: tile sums -> tile offsets -> per-tile block scan
__global__ void tile_sum_k(const int* __restrict__ counts, int* __restrict__ tsum, int Nn) {
    int i = blockIdx.x * 256 + threadIdx.x;
    int v = (i < Nn) ? counts[i] : 0;
    int lane = threadIdx.x & 63, wave = threadIdx.x >> 6;
#pragma unroll
    for (int off = 1; off < 64; off <<= 1) v += __shfl_xor(v, off, 64);
    __shared__ int red[4];
    if (lane == 0) red[wave] = v;
    __syncthreads();
    if (threadIdx.x == 0) tsum[blockIdx.x] = red[0] + red[1] + red[2] + red[3];
}

__global__ void tile_scan_k(const int* __restrict__ tsum, int* __restrict__ toff,
                            int ntiles, int* __restrict__ rowptr, int Nn, int total) {
    __shared__ int s[256];
    int t = threadIdx.x;
    int v = (t < ntiles) ? tsum[t] : 0;
    s[t] = v;
    __syncthreads();
    for (int off = 1; off < 256; off <<= 1) {
        int a = (t >= off) ? s[t - off] : 0;
        __syncthreads();
        s[t] += a;
        __syncthreads();
    }
    if (t < ntiles) toff[t] = s[t] - v;  // exclusive
    if (t == 0) rowptr[Nn] = total;
}

__global__ void tile_write_k(const int* __restrict__ counts, const int* __restrict__ toff,
                             int* __restrict__ rowptr, int Nn) {
    int i = blockIdx.x * 256 + threadIdx.x;
    int t = threadIdx.x;
    int v = (i < Nn) ? counts[i] : 0;
    __shared__ int s[256];
    s[t] = v;
    __syncthreads();
    for (int off = 1; off < 256; off <<= 1) {
        int a = (t >= off) ? s[t - off] : 0;
        __syncthreads();
        s[t] += a;
        __syncthreads();
    }
    if (i < Nn) rowptr[i] = toff[blockIdx.x] + s[t] - v;
}

__global__ void fill_k(const int* __restrict__ src, const int* __restrict__ dst,
                       const int* __restrict__ rowptr, int* __restrict__ fillc,
                       int* __restrict__ col, int E, int EP) {
    int e = blockIdx.x * blockDim.x + threadIdx.x;
    if (e >= EP) return;
    int d = (e < E) ? dst[e] : (e - E);
    int s = (e < E) ? src[e] : (e - E);
    int pos = atomicAdd(&fillc[d], 1);
    col[rowptr[d] + pos] = s;
}

// ---------------- GATv2 gather: 4 edges/iter, 16 lanes x 8ch each, f32 -----------
template <int H>
__global__ __launch_bounds__(256) void gat_gather_k(
    const float* __restrict__ xl, const float* __restrict__ xr,
    const float* __restrict__ att, const float* __restrict__ bo,
    const int* __restrict__ rowptr, const int* __restrict__ col,
    float* __restrict__ y, int Nn) {
    constexpr int NPB = (H == 2) ? 2 : 4;   // nodes per block (4 waves)
    int w = threadIdx.x >> 6;
    int slot = (H == 2) ? (w >> 1) : w;
    int h = (H == 2) ? (w & 1) : 0;
    int lane = threadIdx.x & 63;
    int g = lane >> 4, sub = lane & 15;
    constexpr int HC = H * 128;
    int n = blockIdx.x * NPB + slot;
    bool act = n < Nn;
    int nn = act ? n : 0;

    const float* xrp = xr + (size_t)nn * HC + h * 128 + sub * 8;
    float4 xr0 = *(const float4*)xrp, xr1 = *(const float4*)(xrp + 4);
    const float* ap = att + h * 128 + sub * 8;
    float4 a0 = *(const float4*)ap, a1 = *(const float4*)(ap + 4);

    float den = 0.f;
    float acc[8] = {0.f, 0.f, 0.f, 0.f, 0.f, 0.f, 0.f, 0.f};
    int beg = act ? rowptr[n] : 0, endp = act ? rowptr[n + 1] : 0;

    for (int k0 = beg; k0 < endp; k0 += 4) {
        int k = k0 + g;
        bool ev = k < endp;
        int s = col[ev ? k : beg];
        const float* vp = xl + (size_t)s * HC + h * 128 + sub * 8;
        float4 v0 = *(const float4*)vp, v1 = *(const float4*)(vp + 4);
        float p;
        p = lrelu_f(v0.x + xr0.x) * a0.x;
        p = fmaf(lrelu_f(v0.y + xr0.y), a0.y, p);
        p = fmaf(lrelu_f(v0.z + xr0.z), a0.z, p);
        p = fmaf(lrelu_f(v0.w + xr0.w), a0.w, p);
        p = fmaf(lrelu_f(v1.x + xr1.x), a1.x, p);
        p = fmaf(lrelu_f(v1.y + xr1.y), a1.y, p);
        p = fmaf(lrelu_f(v1.z + xr1.z), a1.z, p);
        p = fmaf(lrelu_f(v1.w + xr1.w), a1.w, p);
        p += __shfl_xor(p, 1, 64);
        p += __shfl_xor(p, 2, 64);
        p += __shfl_xor(p, 4, 64);
        p += __shfl_xor(p, 8, 64);
        float pe = ev ? __expf(p) : 0.f;
        den += pe;
        acc[0] = fmaf(pe, v0.x, acc[0]);
        acc[1] = fmaf(pe, v0.y, acc[1]);
        acc[2] = fmaf(pe, v0.z, acc[2]);
        acc[3] = fmaf(pe, v0.w, acc[3]);
        acc[4] = fmaf(pe, v1.x, acc[4]);
        acc[5] = fmaf(pe, v1.y, acc[5]);
        acc[6] = fmaf(pe, v1.z, acc[6]);
        acc[7] = fmaf(pe, v1.w, acc[7]);
    }
#pragma unroll
    for (int off = 16; off <= 32; off <<= 1) {
        den += __shfl_xor(den, off, 64);
#pragma unroll
        for (int j = 0; j < 8; j++) acc[j] += __shfl_xor(acc[j], off, 64);
    }
    float inv = 1.0f / (den + 1e-16f);

    if constexpr (H == 1) {
        if (act && g == 0) {
            const float* bp = bo + sub * 8;
            f32x4 o0 = {acc[0] * inv + bp[0], acc[1] * inv + bp[1], acc[2] * inv + bp[2], acc[3] * inv + bp[3]};
            f32x4 o1 = {acc[4] * inv + bp[4], acc[5] * inv + bp[5], acc[6] * inv + bp[6], acc[7] * inv + bp[7]};
            *(f32x4*)(y + (size_t)n * 128 + sub * 8) = o0;
            *(f32x4*)(y + (size_t)n * 128 + sub * 8 + 4) = o1;
        }
    } else {
        __shared__ float sh[NPB][2][128];
        if (g == 0) {
#pragma unroll
            for (int j = 0; j < 8; j++) sh[slot][h][sub * 8 + j] = acc[j] * inv;
        }
        __syncthreads();
        int t = threadIdx.x;
        int slot2 = t >> 7, c = t & 127;
        int n2 = blockIdx.x * NPB + slot2;
        if (n2 < Nn)
            y[(size_t)n2 * 128 + c] = (sh[slot2][0][c] + sh[slot2][1][c]) * 0.5f + bo[c];
    }
}

// ---------------- GraphNorm stats: per-channel sum & sumsq -----------------------
__global__ void gn_stats_k(const float* __restrict__ y, float* __restrict__ stats, int Nn) {
    int c = threadIdx.x;  // 128 threads
    int per = (Nn + gridDim.x - 1) / gridDim.x;
    int n0 = blockIdx.x * per, n1 = min(n0 + per, Nn);
    float s = 0.f, s2 = 0.f;
    for (int n = n0; n < n1; n++) {
        float v = y[(size_t)n * 128 + c];
        s += v;
        s2 = fmaf(v, v, s2);
    }
    atomicAdd(&stats[c], s);
    atomicAdd(&stats[128 + c], s2);
}

// ---------------- GraphNorm apply + GELU, f32 out --------------------------------
__global__ void gn_apply_k(const float* __restrict__ y, const float* __restrict__ stats,
                           const float* __restrict__ w, const float* __restrict__ b,
                           const float* __restrict__ ms, float* __restrict__ xo, int Nn) {
    int i4 = blockIdx.x * blockDim.x + threadIdx.x;
    if (i4 >= Nn * 32) return;
    float4 v = reinterpret_cast<const float4*>(y)[i4];
    int c0 = (i4 & 31) * 4;
    float o[4] = {v.x, v.y, v.z, v.w};
    float invN = 1.0f / (float)Nn;
#pragma unroll
    for (int jj = 0; jj < 4; jj++) {
        int c = c0 + jj;
        float mu = stats[c] * invN;
        float ex2 = stats[128 + c] * invN;
        float msv = ms[c];
        float var = ex2 - 2.f * msv * mu * mu + msv * msv * mu * mu;
        float ov = o[jj] - msv * mu;
        float r = rsqrtf(var + 1e-5f);
        o[jj] = gelu_f(fmaf(w[c], ov * r, b[c]));
    }
    float4 res = make_float4(o[0], o[1], o[2], o[3]);
    reinterpret_cast<float4*>(xo)[i4] = res;
}

// ---------------- final head: out = h@W_h2 + b_h2 (OUT=3) ------------------------
__global__ void head2_k(const float* __restrict__ h, const float* __restrict__ W,
                        const float* __restrict__ b, float* __restrict__ out, int Nn) {
    __shared__ float w[192];
    __shared__ float bb[3];
    int t = threadIdx.x;
    if (t < 192) w[t] = W[t];
    if (t < 3) bb[t] = b[t];
    __syncthreads();
    int n = blockIdx.x * blockDim.x + t;
    if (n >= Nn) return;
    float a0 = bb[0], a1 = bb[1], a2 = bb[2];
    const float4* h4 = reinterpret_cast<const float4*>(h + (size_t)n * 64);
    for (int k4 = 0; k4 < 16; k4++) {
        float4 v = h4[k4];
        int k = k4 * 4;
        a0 = fmaf(v.x, w[(k + 0) * 3 + 0], a0); a1 = fmaf(v.x, w[(k + 0) * 3 + 1], a1); a2 = fmaf(v.x, w[(k + 0) * 3 + 2], a2);
        a0 = fmaf(v.y, w[(k + 1) * 3 + 0], a0); a1 = fmaf(v.y, w[(k + 1) * 3 + 1], a1); a2 = fmaf(v.y, w[(k + 1) * 3 + 2], a2);
        a0 = fmaf(v.z, w[(k + 2) * 3 + 0], a0); a1 = fmaf(v.z, w[(k + 2) * 3 + 1], a1); a2 = fmaf(v.z, w[(k + 2) * 3 + 2], a2);
        a0 = fmaf(v.w, w[(k + 3) * 3 + 0], a0); a1 = fmaf(v.w, w[(k + 3) * 3 + 1], a1); a2 = fmaf(v.w, w[(k + 3) * 3 + 2], a2);
    }
    out[n * 3 + 0] = a0;
    out[n * 3 + 1] = a1;
    out[n * 3 + 2] = a2;
}

extern "C" void kernel_launch(void* const* d_in, const int* in_sizes, int n_in,
                              void* d_out, int out_size, void* d_ws, size_t ws_size,
                              hipStream_t stream) {
    const float* zg = (const float*)d_in[0];
    const int* ei = (const int*)d_in[1];
    const float* tv = (const float*)d_in[2];
    const float* W_ne1 = (const float*)d_in[3];
    const float* b_ne1 = (const float*)d_in[4];
    const float* W_ne2 = (const float*)d_in[5];
    const float* b_ne2 = (const float*)d_in[6];
    const float* W_s1 = (const float*)d_in[7];
    const float* b_s1 = (const float*)d_in[8];
    const float* W_s2 = (const float*)d_in[9];
    const float* b_s2 = (const float*)d_in[10];
    const float *Wl[3], *bl[3], *Wr[3], *br[3], *attp[3], *bop[3], *gnw[3], *gnb[3], *gnms[3];
    for (int L = 0; L < 3; L++) {
        int base = 11 + L * 9;
        Wl[L] = (const float*)d_in[base + 0];
        bl[L] = (const float*)d_in[base + 1];
        Wr[L] = (const float*)d_in[base + 2];
        br[L] = (const float*)d_in[base + 3];
        attp[L] = (const float*)d_in[base + 4];
        bop[L] = (const float*)d_in[base + 5];
        gnw[L] = (const float*)d_in[base + 6];
        gnb[L] = (const float*)d_in[base + 7];
        gnms[L] = (const float*)d_in[base + 8];
    }
    const float* W_h1 = (const float*)d_in[38];
    const float* b_h1 = (const float*)d_in[39];
    const float* W_h2 = (const float*)d_in[40];
    const float* b_h2 = (const float*)d_in[41];

    int E = in_sizes[1] / 2;
    int N = in_sizes[2] / 3;
    int EP = E + N;
    int NT = (N + 255) / 256;
    const int* srcp = ei;
    const int* dstp = ei + E;

    char* p = (char*)d_ws;
    auto alloc = [&](size_t bytes) -> char* {
        char* r = p;
        p += (bytes + 255) & ~(size_t)255;
        return r;
    };
    float* style = (float*)alloc(512);
    float* h1 = (float*)alloc((size_t)N * 128 * 4);
    float* x = (float*)alloc((size_t)N * 128 * 4);
    float* xle = (float*)alloc((size_t)N * 256 * 4);
    float* xre = (float*)alloc((size_t)N * 256 * 4);
    float* y = (float*)alloc((size_t)N * 128 * 4);
    float* hb = (float*)alloc((size_t)N * 64 * 4);
    float* stats = (float*)alloc(1024);
    int* rowptr = (int*)alloc(((size_t)N + 1) * 4);
    int* counts = (int*)alloc((size_t)N * 4);
    int* fillc = (int*)alloc((size_t)N * 4);
    int* col = (int*)alloc((size_t)EP * 4);
    int* tsum = (int*)alloc((size_t)NT * 4);
    int* toff = (int*)alloc((size_t)NT * 4);
    unsigned short* wt = (unsigned short*)alloc((size_t)376832 * 2);

    // weight prep: 8 segments, staged fragment-order hi/lo layout
    PrepArgs pa;
    const float* srcs[8] = {W_ne2, Wl[0], Wr[0], Wl[1], Wr[1], Wl[2], Wr[2], W_h1};
    int outs[8] = {128, 256, 256, 256, 256, 128, 128, 64};
    int off = 0;
    pa.dst = wt;
    for (int s = 0; s < 8; s++) {
        pa.src[s] = srcs[s];
        pa.off[s] = off;
        pa.dstoff[s] = 2 * off;
        pa.shift[s] = (outs[s] == 256) ? 8 : (outs[s] == 128 ? 7 : 6);
        off += 128 * outs[s];
    }
    pa.off[8] = off;
    const unsigned short* ws_ne2 = wt + pa.dstoff[0];
    const unsigned short* ws_l[3] = {wt + pa.dstoff[1], wt + pa.dstoff[3], wt + pa.dstoff[5]};
    const unsigned short* ws_r[3] = {wt + pa.dstoff[2], wt + pa.dstoff[4], wt + pa.dstoff[6]};
    const unsigned short* ws_h1 = wt + pa.dstoff[7];
    prep_k<<<(off + 255) / 256, 256, 0, stream>>>(pa);

    // style + node embedding
    style_k<<<1, 128, 0, stream>>>(zg, W_s1, b_s1, W_s2, b_s2, style);
    ne1_k<<<(N * 128 + 255) / 256, 256, 0, stream>>>(tv, W_ne1, b_ne1, h1, N);
    mfma_lin_k<128, 1, false><<<(N + 127) / 128, 256, 0, stream>>>(
        h1, ws_ne2, b_ne2, nullptr, nullptr, style, x, nullptr, N);

    // CSR by destination (rebuilt every launch); hierarchical scan
    hipMemsetAsync(counts, 0, (size_t)N * 4, stream);
    hipMemsetAsync(fillc, 0, (size_t)N * 4, stream);
    count_k<<<(EP + 255) / 256, 256, 0, stream>>>(dstp, counts, E, EP);
    tile_sum_k<<<NT, 256, 0, stream>>>(counts, tsum, N);
    tile_scan_k<<<1, 256, 0, stream>>>(tsum, toff, NT, rowptr, N, EP);
    tile_write_k<<<NT, 256, 0, stream>>>(counts, toff, rowptr, N);
    fill_k<<<(EP + 255) / 256, 256, 0, stream>>>(srcp, dstp, rowptr, fillc, col, E, EP);

    const int HS[3] = {2, 2, 1};
    for (int L = 0; L < 3; L++) {
        if (HS[L] == 2) {
            mfma_lin_k<256, 0, true><<<(N + 127) / 128, 256, 0, stream>>>(
                x, ws_l[L], bl[L], ws_r[L], br[L], nullptr, xle, xre, N);
            gat_gather_k<2><<<(N + 1) / 2, 256, 0, stream>>>(xle, xre, attp[L], bop[L], rowptr, col, y, N);
        } else {
            mfma_lin_k<128, 0, true><<<(N + 127) / 128, 256, 0, stream>>>(
                x, ws_l[L], bl[L], ws_r[L], br[L], nullptr, xle, xre, N);
            gat_gather_k<1><<<(N + 3) / 4, 256, 0, stream>>>(xle, xre, attp[L], bop[L], rowptr, col, y, N);
        }
        hipMemsetAsync(stats, 0, 1024, stream);
        gn_stats_k<<<512, 128, 0, stream>>>(y, stats, N);
        gn_apply_k<<<(N * 32 + 255) / 256, 256, 0, stream>>>(y, stats, gnw[L], gnb[L], gnms[L], x, N);
    }

    // head: h = gelu(x@W_h1+b_h1) (split-MFMA, f32 out); out = h@W_h2 + b_h2
    mfma_lin_k<64, 2, false><<<(N + 127) / 128, 256, 0, stream>>>(
        x, ws_h1, b_h1, nullptr, nullptr, nullptr, hb, nullptr, N);
    head2_k<<<(N + 255) / 256, 256, 0, stream>>>(hb, W_h2, b_h2, (float*)d_out, N);
}

// Round 9
// 677.305 us; speedup vs baseline: 1.3330x; 1.0399x over previous
//
#include <hip/hip_runtime.h>
#include <hip/hip_fp16.h>
#include <math.h>

#define DEVINL __device__ __forceinline__

using bf16x8 = __attribute__((ext_vector_type(8))) short;
using f32x4  = __attribute__((ext_vector_type(4))) float;
using u16x4  = __attribute__((ext_vector_type(4))) unsigned short;

DEVINL float gelu_f(float v) { return 0.5f * v * (1.0f + erff(v * 0.7071067811865475f)); }
DEVINL float lrelu_f(float v) { return v > 0.0f ? v : 0.2f * v; }
DEVINL unsigned short f2bf(float f) {
    union { float f; unsigned u; } c; c.f = f;
    unsigned r = c.u + 0x7fffu + ((c.u >> 16) & 1u);
    return (unsigned short)(r >> 16);
}
DEVINL float bf2f(unsigned short s) {
    union { unsigned u; float f; } c; c.u = (unsigned)s << 16;
    return c.f;
}
DEVINL unsigned short f2h(float f) {
    __half h = __float2half_rn(f);
    return *(unsigned short*)&h;
}
DEVINL void gl_lds16(const void* g, void* l) {
    __builtin_amdgcn_global_load_lds(
        (const __attribute__((address_space(1))) unsigned*)g,
        (__attribute__((address_space(3))) unsigned*)l, 16, 0, 0);
}
DEVINL void unp8h(const unsigned short* p, float* v) {
    uint4 u = *(const uint4*)p;
    __half2 h0 = *(__half2*)&u.x, h1 = *(__half2*)&u.y;
    __half2 h2 = *(__half2*)&u.z, h3 = *(__half2*)&u.w;
    float2 f0 = __half22float2(h0), f1 = __half22float2(h1);
    float2 f2 = __half22float2(h2), f3 = __half22float2(h3);
    v[0] = f0.x; v[1] = f0.y; v[2] = f1.x; v[3] = f1.y;
    v[4] = f2.x; v[5] = f2.y; v[6] = f3.x; v[7] = f3.y;
}

// ---------------- style: style = gelu(z_g@W_s1+b_s1)@W_s2 + b_s2 ----------------
__global__ void style_k(const float* __restrict__ zg, const float* __restrict__ W1,
                        const float* __restrict__ b1, const float* __restrict__ W2,
                        const float* __restrict__ b2, float* __restrict__ style) {
    __shared__ float s1[128];
    int j = threadIdx.x;
    float a = b1[j];
    for (int k = 0; k < 256; k++) a = fmaf(zg[k], W1[k * 128 + j], a);
    s1[j] = gelu_f(a);
    __syncthreads();
    float o = b2[j];
    for (int k = 0; k < 128; k++) o = fmaf(s1[k], W2[k * 128 + j], o);
    style[j] = o;
}

// ---------------- node-embed layer 1: h1 = gelu(tv@W_ne1 + b_ne1), f32 out ------
__global__ void ne1_k(const float* __restrict__ tv, const float* __restrict__ W,
                      const float* __restrict__ b, float* __restrict__ h1, int Nn) {
    int idx = blockIdx.x * blockDim.x + threadIdx.x;
    if (idx >= Nn * 128) return;
    int n = idx >> 7, c = idx & 127;
    float o = fmaf(tv[n * 3 + 0], W[c],
              fmaf(tv[n * 3 + 1], W[128 + c],
              fmaf(tv[n * 3 + 2], W[256 + c], b[c])));
    h1[idx] = gelu_f(o);
}

// -------- weight prep: f32 W[128][OUT] -> staged fragment-order hi/lo chunks -----
struct PrepArgs {
    const float* src[8];
    unsigned short* dst;
    int dstoff[8];  // in shorts
    int off[9];     // source element offsets
    int shift[8];   // log2(OUT)
};
__global__ void prep_k(PrepArgs a) {
    int idx = blockIdx.x * 256 + threadIdx.x;
    if (idx >= a.off[8]) return;
    int s = 0;
    while (idx >= a.off[s + 1]) s++;
    int e = idx - a.off[s];
    int sh = a.shift[s];
    int k = e >> sh, j = e & ((1 << sh) - 1);
    float w = a.src[s][e];
    unsigned short hi = f2bf(w);
    unsigned short lo = f2bf(w - bf2f(hi));
    int c = j >> 4, lr = j & 15;
    int s2 = k >> 5, lk = (k >> 3) & 3, i = k & 7;
    int lane = lk * 16 + lr;
    size_t base = (size_t)a.dstoff[s] + (size_t)c * 4096 + s2 * 512 + lane * 8 + i;
    a.dst[base] = hi;
    a.dst[base + 2048] = lo;
}

// ---------------- split-MFMA linear: LDS double-buffered weight chunks -----------
template <int OUT, int EPI, bool DUAL, typename OutT>  // EPI 0:bias 1:+style 2:+gelu
__global__ __launch_bounds__(256) void mfma_lin_k(
    const float* __restrict__ xin,
    const unsigned short* __restrict__ WT0, const float* __restrict__ b0,
    const unsigned short* __restrict__ WT1, const float* __restrict__ b1,
    const float* __restrict__ style,
    OutT* __restrict__ out0, OutT* __restrict__ out1, int Nn) {
    constexpr int CPM = OUT / 16;
    constexpr int NCH = (DUAL ? 2 : 1) * CPM;
    __shared__ uint4 buf[2][512];  // 2 x 8KB
    int t = threadIdx.x;
    int wave = t >> 6, lane = t & 63;
    int lr = lane & 15, lk = lane >> 4;
    int base = blockIdx.x * 128 + wave * 32;
    int r0 = base + lr, r1 = base + 16 + lr;
    int cr0 = min(r0, Nn - 1), cr1 = min(r1, Nn - 1);

    bf16x8 xh[2][4], xlo[2][4];
#pragma unroll
    for (int rr = 0; rr < 2; rr++) {
        const float* px = xin + (size_t)(rr ? cr1 : cr0) * 128;
#pragma unroll
        for (int s = 0; s < 4; s++) {
            const float4* p4 = (const float4*)(px + s * 32 + lk * 8);
            float4 a = p4[0], b = p4[1];
            float v[8] = {a.x, a.y, a.z, a.w, b.x, b.y, b.z, b.w};
            bf16x8 h, l;
#pragma unroll
            for (int i = 0; i < 8; i++) {
                unsigned short hb = f2bf(v[i]);
                h[i] = (short)hb;
                l[i] = (short)f2bf(v[i] - bf2f(hb));
            }
            xh[rr][s] = h;
            xlo[rr][s] = l;
        }
    }

    auto stage = [&](int c, int bsel) {
        const unsigned short* Wt = (DUAL && c >= CPM) ? WT1 : WT0;
        int cc = (DUAL && c >= CPM) ? c - CPM : c;
        const char* g = (const char*)(Wt + (size_t)cc * 4096);
        char* l = (char*)&buf[bsel][0];
        gl_lds16(g + t * 16, l + wave * 1024);
        gl_lds16(g + 4096 + t * 16, l + 4096 + wave * 1024);
    };

    stage(0, 0);
    for (int c = 0; c < NCH; ++c) {
        int cur = c & 1;
        bool pre = (c + 1 < NCH);
        if (pre) stage(c + 1, cur ^ 1);
        if (pre) asm volatile("s_waitcnt vmcnt(2)" ::: "memory");
        else     asm volatile("s_waitcnt vmcnt(0)" ::: "memory");
        __builtin_amdgcn_s_barrier();

        int m = (DUAL && c >= CPM) ? 1 : 0;
        int j0 = (c - m * CPM) * 16;
        const float* bias = m ? b1 : b0;
        OutT* out = m ? out1 : out0;
        const bf16x8* W = (const bf16x8*)&buf[cur][0];

        f32x4 acc0 = {0.f, 0.f, 0.f, 0.f}, acc1 = {0.f, 0.f, 0.f, 0.f};
#pragma unroll
        for (int s = 0; s < 4; ++s) {
            bf16x8 wh = W[s * 64 + lane];
            bf16x8 wl = W[256 + s * 64 + lane];
            acc0 = __builtin_amdgcn_mfma_f32_16x16x32_bf16(wh, xh[0][s], acc0, 0, 0, 0);
            acc0 = __builtin_amdgcn_mfma_f32_16x16x32_bf16(wh, xlo[0][s], acc0, 0, 0, 0);
            acc0 = __builtin_amdgcn_mfma_f32_16x16x32_bf16(wl, xh[0][s], acc0, 0, 0, 0);
            acc1 = __builtin_amdgcn_mfma_f32_16x16x32_bf16(wh, xh[1][s], acc1, 0, 0, 0);
            acc1 = __builtin_amdgcn_mfma_f32_16x16x32_bf16(wh, xlo[1][s], acc1, 0, 0, 0);
            acc1 = __builtin_amdgcn_mfma_f32_16x16x32_bf16(wl, xh[1][s], acc1, 0, 0, 0);
        }
        int j = j0 + lk * 4;
        float o0[4], o1[4];
#pragma unroll
        for (int i = 0; i < 4; i++) {
            float bb = bias[j + i];
            if (EPI == 1) bb += style[j + i];
            float v0 = acc0[i] + bb, v1 = acc1[i] + bb;
            if (EPI == 2) { v0 = gelu_f(v0); v1 = gelu_f(v1); }
            o0[i] = v0; o1[i] = v1;
        }
        if constexpr (sizeof(OutT) == 2) {
            u16x4 s0 = {f2h(o0[0]), f2h(o0[1]), f2h(o0[2]), f2h(o0[3])};
            u16x4 s1v = {f2h(o1[0]), f2h(o1[1]), f2h(o1[2]), f2h(o1[3])};
            if (r0 < Nn) *(u16x4*)((unsigned short*)out + (size_t)r0 * OUT + j) = s0;
            if (r1 < Nn) *(u16x4*)((unsigned short*)out + (size_t)r1 * OUT + j) = s1v;
        } else {
            if (r0 < Nn) { f32x4 v = {o0[0], o0[1], o0[2], o0[3]}; *(f32x4*)((float*)out + (size_t)r0 * OUT + j) = v; }
            if (r1 < Nn) { f32x4 v = {o1[0], o1[1], o1[2], o1[3]}; *(f32x4*)((float*)out + (size_t)r1 * OUT + j) = v; }
        }
        __builtin_amdgcn_s_barrier();
    }
}

// ---------------- CSR build (by destination), self-loops appended ----------------
__global__ void count_k(const int* __restrict__ dst, int* __restrict__ counts, int E, int EP) {
    int e = blockIdx.x * blockDim.x + threadIdx.x;
    if (e >= EP) return;
    int d = (e < E) ? dst[e] : (e - E);
    atomicAdd(&counts[d], 1);
}

// hierarchical scan: tile sums -> tile offsets -> per-tile block scan
__global__ void tile_sum_k(const int* __restrict__ counts, int* __restrict__ tsum, int Nn) {
    int i = blockIdx.x * 256 + threadIdx.x;
    int v = (i < Nn) ? counts[i] : 0;
    int lane = threadIdx.x & 63, wave = threadIdx.x >> 6;
#pragma unroll
    for (int off = 1; off < 64; off <<= 1) v += __shfl_xor(v, off, 64);
    __shared__ int red[4];
    if (lane == 0) red[wave] = v;
    __syncthreads();
    if (threadIdx.x == 0) tsum[blockIdx.x] = red[0] + red[1] + red[2] + red[3];
}

__global__ void tile_scan_k(const int* __restrict__ tsum, int* __restrict__ toff,
                            int ntiles, int* __restrict__ rowptr, int Nn, int total) {
    __shared__ int s[256];
    int t = threadIdx.x;
    int v = (t < ntiles) ? tsum[t] : 0;
    s[t] = v;
    __syncthreads();
    for (int off = 1; off < 256; off <<= 1) {
        int a = (t >= off) ? s[t - off] : 0;
        __syncthreads();
        s[t] += a;
        __syncthreads();
    }
    if (t < ntiles) toff[t] = s[t] - v;  // exclusive
    if (t == 0) rowptr[Nn] = total;
}

__global__ void tile_write_k(const int* __restrict__ counts, const int* __restrict__ toff,
                             int* __restrict__ rowptr, int Nn) {
    int i = blockIdx.x * 256 + threadIdx.x;
    int t = threadIdx.x;
    int v = (i < Nn) ? counts[i] : 0;
    __shared__ int s[256];
    s[t] = v;
    __syncthreads();
    for (int off = 1; off < 256; off <<= 1) {
        int a = (t >= off) ? s[t - off] : 0;
        __syncthreads();
        s[t] += a;
        __syncthreads();
    }
    if (i < Nn) rowptr[i] = toff[blockIdx.x] + s[t] - v;
}

__global__ void fill_k(const int* __restrict__ src, const int* __restrict__ dst,
                       const int* __restrict__ rowptr, int* __restrict__ fillc,
                       int* __restrict__ col, int E, int EP) {
    int e = blockIdx.x * blockDim.x + threadIdx.x;
    if (e >= EP) return;
    int d = (e < E) ? dst[e] : (e - E);
    int s = (e < E) ? src[e] : (e - E);
    int pos = atomicAdd(&fillc[d], 1);
    col[rowptr[d] + pos] = s;
}

// ---------------- GATv2 gather: 4 edges/iter, 16 lanes x 8ch, fp16 operands ------
template <int H>
__global__ __launch_bounds__(256) void gat_gather_k(
    const unsigned short* __restrict__ xl, const unsigned short* __restrict__ xr,
    const float* __restrict__ att, const float* __restrict__ bo,
    const int* __restrict__ rowptr, const int* __restrict__ col,
    float* __restrict__ y, int Nn) {
    constexpr int NPB = (H == 2) ? 2 : 4;   // nodes per block (4 waves)
    int w = threadIdx.x >> 6;
    int slot = (H == 2) ? (w >> 1) : w;
    int h = (H == 2) ? (w & 1) : 0;
    int lane = threadIdx.x & 63;
    int g = lane >> 4, sub = lane & 15;
    constexpr int HC = H * 128;
    int n = blockIdx.x * NPB + slot;
    bool act = n < Nn;
    int nn = act ? n : 0;

    float xrv[8], av[8];
    unp8h(xr + (size_t)nn * HC + h * 128 + sub * 8, xrv);
    const float* ap = att + h * 128 + sub * 8;
#pragma unroll
    for (int i = 0; i < 8; i++) av[i] = ap[i];

    float den = 0.f;
    float acc[8] = {0.f, 0.f, 0.f, 0.f, 0.f, 0.f, 0.f, 0.f};
    int beg = act ? rowptr[n] : 0, endp = act ? rowptr[n + 1] : 0;

    for (int k0 = beg; k0 < endp; k0 += 4) {
        int k = k0 + g;
        bool ev = k < endp;
        int s = col[ev ? k : beg];
        float v[8];
        unp8h(xl + (size_t)s * HC + h * 128 + sub * 8, v);
        float p = lrelu_f(v[0] + xrv[0]) * av[0];
#pragma unroll
        for (int i = 1; i < 8; i++) p = fmaf(lrelu_f(v[i] + xrv[i]), av[i], p);
        p += __shfl_xor(p, 1, 64);
        p += __shfl_xor(p, 2, 64);
        p += __shfl_xor(p, 4, 64);
        p += __shfl_xor(p, 8, 64);
        float pe = ev ? __expf(p) : 0.f;
        den += pe;
#pragma unroll
        for (int i = 0; i < 8; i++) acc[i] = fmaf(pe, v[i], acc[i]);
    }
#pragma unroll
    for (int off = 16; off <= 32; off <<= 1) {
        den += __shfl_xor(den, off, 64);
#pragma unroll
        for (int j = 0; j < 8; j++) acc[j] += __shfl_xor(acc[j], off, 64);
    }
    float inv = 1.0f / (den + 1e-16f);

    if constexpr (H == 1) {
        if (act && g == 0) {
            const float* bp = bo + sub * 8;
            f32x4 o0 = {acc[0] * inv + bp[0], acc[1] * inv + bp[1], acc[2] * inv + bp[2], acc[3] * inv + bp[3]};
            f32x4 o1 = {acc[4] * inv + bp[4], acc[5] * inv + bp[5], acc[6] * inv + bp[6], acc[7] * inv + bp[7]};
            *(f32x4*)(y + (size_t)n * 128 + sub * 8) = o0;
            *(f32x4*)(y + (size_t)n * 128 + sub * 8 + 4) = o1;
        }
    } else {
        __shared__ float sh[NPB][2][128];
        if (g == 0) {
#pragma unroll
            for (int j = 0; j < 8; j++) sh[slot][h][sub * 8 + j] = acc[j] * inv;
        }
        __syncthreads();
        int t = threadIdx.x;
        int slot2 = t >> 7, c = t & 127;
        int n2 = blockIdx.x * NPB + slot2;
        if (n2 < Nn)
            y[(size_t)n2 * 128 + c] = (sh[slot2][0][c] + sh[slot2][1][c]) * 0.5f + bo[c];
    }
}

// ---------------- GraphNorm stats: per-channel sum & sumsq -----------------------
__global__ void gn_stats_k(const float* __restrict__ y, float* __restrict__ stats, int Nn) {
    int c = threadIdx.x;  // 128 threads
    int per = (Nn + gridDim.x - 1) / gridDim.x;
    int n0 = blockIdx.x * per, n1 = min(n0 + per, Nn);
    float s = 0.f, s2 = 0.f;
    for (int n = n0; n < n1; n++) {
        float v = y[(size_t)n * 128 + c];
        s += v;
        s2 = fmaf(v, v, s2);
    }
    atomicAdd(&stats[c], s);
    atomicAdd(&stats[128 + c], s2);
}

// ---------------- GraphNorm apply + GELU, f32 out --------------------------------
__global__ void gn_apply_k(const float* __restrict__ y, const float* __restrict__ stats,
                           const float* __restrict__ w, const float* __restrict__ b,
                           const float* __restrict__ ms, float* __restrict__ xo, int Nn) {
    int i4 = blockIdx.x * blockDim.x + threadIdx.x;
    if (i4 >= Nn * 32) return;
    float4 v = reinterpret_cast<const float4*>(y)[i4];
    int c0 = (i4 & 31) * 4;
    float o[4] = {v.x, v.y, v.z, v.w};
    float invN = 1.0f / (float)Nn;
#pragma unroll
    for (int jj = 0; jj < 4; jj++) {
        int c = c0 + jj;
        float mu = stats[c] * invN;
        float ex2 = stats[128 + c] * invN;
        float msv = ms[c];
        float var = ex2 - 2.f * msv * mu * mu + msv * msv * mu * mu;
        float ov = o[jj] - msv * mu;
        float r = rsqrtf(var + 1e-5f);
        o[jj] = gelu_f(fmaf(w[c], ov * r, b[c]));
    }
    float4 res = make_float4(o[0], o[1], o[2], o[3]);
    reinterpret_cast<float4*>(xo)[i4] = res;
}

// ---------------- final head: out = h@W_h2 + b_h2 (OUT=3) ------------------------
__global__ void head2_k(const float* __restrict__ h, const float* __restrict__ W,
                        const float* __restrict__ b, float* __restrict__ out, int Nn) {
    __shared__ float w[192];
    __shared__ float bb[3];
    int t = threadIdx.x;
    if (t < 192) w[t] = W[t];
    if (t < 3) bb[t] = b[t];
    __syncthreads();
    int n = blockIdx.x * blockDim.x + t;
    if (n >= Nn) return;
    float a0 = bb[0], a1 = bb[1], a2 = bb[2];
    const float4* h4 = reinterpret_cast<const float4*>(h + (size_t)n * 64);
    for (int k4 = 0; k4 < 16; k4++) {
        float4 v = h4[k4];
        int k = k4 * 4;
        a0 = fmaf(v.x, w[(k + 0) * 3 + 0], a0); a1 = fmaf(v.x, w[(k + 0) * 3 + 1], a1); a2 = fmaf(v.x, w[(k + 0) * 3 + 2], a2);
        a0 = fmaf(v.y, w[(k + 1) * 3 + 0], a0); a1 = fmaf(v.y, w[(k + 1) * 3 + 1], a1); a2 = fmaf(v.y, w[(k + 1) * 3 + 2], a2);
        a0 = fmaf(v.z, w[(k + 2) * 3 + 0], a0); a1 = fmaf(v.z, w[(k + 2) * 3 + 1], a1); a2 = fmaf(v.z, w[(k + 2) * 3 + 2], a2);
        a0 = fmaf(v.w, w[(k + 3) * 3 + 0], a0); a1 = fmaf(v.w, w[(k + 3) * 3 + 1], a1); a2 = fmaf(v.w, w[(k + 3) * 3 + 2], a2);
    }
    out[n * 3 + 0] = a0;
    out[n * 3 + 1] = a1;
    out[n * 3 + 2] = a2;
}

extern "C" void kernel_launch(void* const* d_in, const int* in_sizes, int n_in,
                              void* d_out, int out_size, void* d_ws, size_t ws_size,
                              hipStream_t stream) {
    const float* zg = (const float*)d_in[0];
    const int* ei = (const int*)d_in[1];
    const float* tv = (const float*)d_in[2];
    const float* W_ne1 = (const float*)d_in[3];
    const float* b_ne1 = (const float*)d_in[4];
    const float* W_ne2 = (const float*)d_in[5];
    const float* b_ne2 = (const float*)d_in[6];
    const float* W_s1 = (const float*)d_in[7];
    const float* b_s1 = (const float*)d_in[8];
    const float* W_s2 = (const float*)d_in[9];
    const float* b_s2 = (const float*)d_in[10];
    const float *Wl[3], *bl[3], *Wr[3], *br[3], *attp[3], *bop[3], *gnw[3], *gnb[3], *gnms[3];
    for (int L = 0; L < 3; L++) {
        int base = 11 + L * 9;
        Wl[L] = (const float*)d_in[base + 0];
        bl[L] = (const float*)d_in[base + 1];
        Wr[L] = (const float*)d_in[base + 2];
        br[L] = (const float*)d_in[base + 3];
        attp[L] = (const float*)d_in[base + 4];
        bop[L] = (const float*)d_in[base + 5];
        gnw[L] = (const float*)d_in[base + 6];
        gnb[L] = (const float*)d_in[base + 7];
        gnms[L] = (const float*)d_in[base + 8];
    }
    const float* W_h1 = (const float*)d_in[38];
    const float* b_h1 = (const float*)d_in[39];
    const float* W_h2 = (const float*)d_in[40];
    const float* b_h2 = (const float*)d_in[41];

    int E = in_sizes[1] / 2;
    int N = in_sizes[2] / 3;
    int EP = E + N;
    int NT = (N + 255) / 256;
    const int* srcp = ei;
    const int* dstp = ei + E;

    char* p = (char*)d_ws;
    auto alloc = [&](size_t bytes) -> char* {
        char* r = p;
        p += (bytes + 255) & ~(size_t)255;
        return r;
    };
    float* style = (float*)alloc(512);
    float* h1 = (float*)alloc((size_t)N * 128 * 4);
    float* x = (float*)alloc((size_t)N * 128 * 4);
    unsigned short* xle = (unsigned short*)alloc((size_t)N * 256 * 2);
    unsigned short* xre = (unsigned short*)alloc((size_t)N * 256 * 2);
    float* y = (float*)alloc((size_t)N * 128 * 4);
    float* hb = (float*)alloc((size_t)N * 64 * 4);
    float* stats = (float*)alloc(1024);
    int* rowptr = (int*)alloc(((size_t)N + 1) * 4);
    int* counts = (int*)alloc((size_t)N * 4);
    int* fillc = (int*)alloc((size_t)N * 4);
    int* col = (int*)alloc((size_t)EP * 4);
    int* tsum = (int*)alloc((size_t)NT * 4);
    int* toff = (int*)alloc((size_t)NT * 4);
    unsigned short* wt = (unsigned short*)alloc((size_t)376832 * 2);

    // weight prep: 8 segments, staged fragment-order hi/lo layout
    PrepArgs pa;
    const float* srcs[8] = {W_ne2, Wl[0], Wr[0], Wl[1], Wr[1], Wl[2], Wr[2], W_h1};
    int outs[8] = {128, 256, 256, 256, 256, 128, 128, 64};
    int off = 0;
    pa.dst = wt;
    for (int s = 0; s < 8; s++) {
        pa.src[s] = srcs[s];
        pa.off[s] = off;
        pa.dstoff[s] = 2 * off;
        pa.shift[s] = (outs[s] == 256) ? 8 : (outs[s] == 128 ? 7 : 6);
        off += 128 * outs[s];
    }
    pa.off[8] = off;
    const unsigned short* ws_ne2 = wt + pa.dstoff[0];
    const unsigned short* ws_l[3] = {wt + pa.dstoff[1], wt + pa.dstoff[3], wt + pa.dstoff[5]};
    const unsigned short* ws_r[3] = {wt + pa.dstoff[2], wt + pa.dstoff[4], wt + pa.dstoff[6]};
    const unsigned short* ws_h1 = wt + pa.dstoff[7];
    prep_k<<<(off + 255) / 256, 256, 0, stream>>>(pa);

    // style + node embedding
    style_k<<<1, 128, 0, stream>>>(zg, W_s1, b_s1, W_s2, b_s2, style);
    ne1_k<<<(N * 128 + 255) / 256, 256, 0, stream>>>(tv, W_ne1, b_ne1, h1, N);
    mfma_lin_k<128, 1, false, float><<<(N + 127) / 128, 256, 0, stream>>>(
        h1, ws_ne2, b_ne2, nullptr, nullptr, style, x, nullptr, N);

    // CSR by destination (rebuilt every launch); hierarchical scan
    hipMemsetAsync(counts, 0, (size_t)N * 4, stream);
    hipMemsetAsync(fillc, 0, (size_t)N * 4, stream);
    count_k<<<(EP + 255) / 256, 256, 0, stream>>>(dstp, counts, E, EP);
    tile_sum_k<<<NT, 256, 0, stream>>>(counts, tsum, N);
    tile_scan_k<<<1, 256, 0, stream>>>(tsum, toff, NT, rowptr, N, EP);
    tile_write_k<<<NT, 256, 0, stream>>>(counts, toff, rowptr, N);
    fill_k<<<(EP + 255) / 256, 256, 0, stream>>>(srcp, dstp, rowptr, fillc, col, E, EP);

    const int HS[3] = {2, 2, 1};
    for (int L = 0; L < 3; L++) {
        if (HS[L] == 2) {
            mfma_lin_k<256, 0, true, unsigned short><<<(N + 127) / 128, 256, 0, stream>>>(
                x, ws_l[L], bl[L], ws_r[L], br[L], nullptr, xle, xre, N);
            gat_gather_k<2><<<(N + 1) / 2, 256, 0, stream>>>(xle, xre, attp[L], bop[L], rowptr, col, y, N);
        } else {
            mfma_lin_k<128, 0, true, unsigned short><<<(N + 127) / 128, 256, 0, stream>>>(
                x, ws_l[L], bl[L], ws_r[L], br[L], nullptr, xle, xre, N);
            gat_gather_k<1><<<(N + 3) / 4, 256, 0, stream>>>(xle, xre, attp[L], bop[L], rowptr, col, y, N);
        }
        hipMemsetAsync(stats, 0, 1024, stream);
        gn_stats_k<<<512, 128, 0, stream>>>(y, stats, N);
        gn_apply_k<<<(N * 32 + 255) / 256, 256, 0, stream>>>(y, stats, gnw[L], gnb[L], gnms[L], x, N);
    }

    // head: h = gelu(x@W_h1+b_h1) (split-MFMA, f32 out); out = h@W_h2 + b_h2
    mfma_lin_k<64, 2, false, float><<<(N + 127) / 128, 256, 0, stream>>>(
        x, ws_h1, b_h1, nullptr, nullptr, nullptr, hb, nullptr, N);
    head2_k<<<(N + 255) / 256, 256, 0, stream>>>(hb, W_h2, b_h2, (float*)d_out, N);
}

// Round 10
// 666.956 us; speedup vs baseline: 1.3537x; 1.0155x over previous
//
#include <hip/hip_runtime.h>
#include <hip/hip_fp16.h>
#include <math.h>

#define DEVINL __device__ __forceinline__

using bf16x8 = __attribute__((ext_vector_type(8))) short;
using f32x4  = __attribute__((ext_vector_type(4))) float;
using u16x4  = __attribute__((ext_vector_type(4))) unsigned short;
using f16x2  = __attribute__((ext_vector_type(2))) _Float16;

DEVINL float gelu_f(float v) { return 0.5f * v * (1.0f + erff(v * 0.7071067811865475f)); }
DEVINL float lrelu_f(float v) { return v > 0.0f ? v : 0.2f * v; }
DEVINL unsigned short f2bf(float f) {
    union { float f; unsigned u; } c; c.f = f;
    unsigned r = c.u + 0x7fffu + ((c.u >> 16) & 1u);
    return (unsigned short)(r >> 16);
}
DEVINL float bf2f(unsigned short s) {
    union { unsigned u; float f; } c; c.u = (unsigned)s << 16;
    return c.f;
}
DEVINL unsigned short f2h(float f) {
    __half h = __float2half_rn(f);
    return *(unsigned short*)&h;
}
DEVINL f16x2 b2h2(unsigned u) {
    union { unsigned u; f16x2 h; } c; c.u = u; return c.h;
}
DEVINL void gl_lds16(const void* g, void* l) {
    __builtin_amdgcn_global_load_lds(
        (const __attribute__((address_space(1))) unsigned*)g,
        (__attribute__((address_space(3))) unsigned*)l, 16, 0, 0);
}

// ---------------- style: style = gelu(z_g@W_s1+b_s1)@W_s2 + b_s2 ----------------
__global__ void style_k(const float* __restrict__ zg, const float* __restrict__ W1,
                        const float* __restrict__ b1, const float* __restrict__ W2,
                        const float* __restrict__ b2, float* __restrict__ style) {
    __shared__ float s1[128];
    int j = threadIdx.x;
    float a = b1[j];
    for (int k = 0; k < 256; k++) a = fmaf(zg[k], W1[k * 128 + j], a);
    s1[j] = gelu_f(a);
    __syncthreads();
    float o = b2[j];
    for (int k = 0; k < 128; k++) o = fmaf(s1[k], W2[k * 128 + j], o);
    style[j] = o;
}

// ------ node-embed layer 1 (+ fused counts zeroing for the CSR build) ------------
__global__ void ne1_k(const float* __restrict__ tv, const float* __restrict__ W,
                      const float* __restrict__ b, float* __restrict__ h1,
                      int* __restrict__ counts, int Nn) {
    int idx = blockIdx.x * blockDim.x + threadIdx.x;
    if (idx < Nn) counts[idx] = 0;
    if (idx >= Nn * 128) return;
    int n = idx >> 7, c = idx & 127;
    float o = fmaf(tv[n * 3 + 0], W[c],
              fmaf(tv[n * 3 + 1], W[128 + c],
              fmaf(tv[n * 3 + 2], W[256 + c], b[c])));
    h1[idx] = gelu_f(o);
}

// -------- weight prep: f32 W[128][OUT] -> staged fragment-order hi/lo chunks -----
struct PrepArgs {
    const float* src[8];
    unsigned short* dst;
    int dstoff[8];  // in shorts
    int off[9];     // source element offsets
    int shift[8];   // log2(OUT)
};
__global__ void prep_k(PrepArgs a) {
    int idx = blockIdx.x * 256 + threadIdx.x;
    if (idx >= a.off[8]) return;
    int s = 0;
    while (idx >= a.off[s + 1]) s++;
    int e = idx - a.off[s];
    int sh = a.shift[s];
    int k = e >> sh, j = e & ((1 << sh) - 1);
    float w = a.src[s][e];
    unsigned short hi = f2bf(w);
    unsigned short lo = f2bf(w - bf2f(hi));
    int c = j >> 4, lr = j & 15;
    int s2 = k >> 5, lk = (k >> 3) & 3, i = k & 7;
    int lane = lk * 16 + lr;
    size_t base = (size_t)a.dstoff[s] + (size_t)c * 4096 + s2 * 512 + lane * 8 + i;
    a.dst[base] = hi;
    a.dst[base + 2048] = lo;
}

// ---------------- split-MFMA linear: LDS double-buffered weight chunks -----------
template <int OUT, int EPI, bool DUAL, typename OutT>  // EPI 0:bias 1:+style 2:+gelu
__global__ __launch_bounds__(256) void mfma_lin_k(
    const float* __restrict__ xin,
    const unsigned short* __restrict__ WT0, const float* __restrict__ b0,
    const unsigned short* __restrict__ WT1, const float* __restrict__ b1,
    const float* __restrict__ style,
    OutT* __restrict__ out0, OutT* __restrict__ out1, int Nn) {
    constexpr int CPM = OUT / 16;
    constexpr int NCH = (DUAL ? 2 : 1) * CPM;
    __shared__ uint4 buf[2][512];  // 2 x 8KB
    int t = threadIdx.x;
    int wave = t >> 6, lane = t & 63;
    int lr = lane & 15, lk = lane >> 4;
    int base = blockIdx.x * 128 + wave * 32;
    int r0 = base + lr, r1 = base + 16 + lr;
    int cr0 = min(r0, Nn - 1), cr1 = min(r1, Nn - 1);

    bf16x8 xh[2][4], xlo[2][4];
#pragma unroll
    for (int rr = 0; rr < 2; rr++) {
        const float* px = xin + (size_t)(rr ? cr1 : cr0) * 128;
#pragma unroll
        for (int s = 0; s < 4; s++) {
            const float4* p4 = (const float4*)(px + s * 32 + lk * 8);
            float4 a = p4[0], b = p4[1];
            float v[8] = {a.x, a.y, a.z, a.w, b.x, b.y, b.z, b.w};
            bf16x8 h, l;
#pragma unroll
            for (int i = 0; i < 8; i++) {
                unsigned short hb = f2bf(v[i]);
                h[i] = (short)hb;
                l[i] = (short)f2bf(v[i] - bf2f(hb));
            }
            xh[rr][s] = h;
            xlo[rr][s] = l;
        }
    }

    auto stage = [&](int c, int bsel) {
        const unsigned short* Wt = (DUAL && c >= CPM) ? WT1 : WT0;
        int cc = (DUAL && c >= CPM) ? c - CPM : c;
        const char* g = (const char*)(Wt + (size_t)cc * 4096);
        char* l = (char*)&buf[bsel][0];
        gl_lds16(g + t * 16, l + wave * 1024);
        gl_lds16(g + 4096 + t * 16, l + 4096 + wave * 1024);
    };

    stage(0, 0);
    for (int c = 0; c < NCH; ++c) {
        int cur = c & 1;
        bool pre = (c + 1 < NCH);
        if (pre) stage(c + 1, cur ^ 1);
        if (pre) asm volatile("s_waitcnt vmcnt(2)" ::: "memory");
        else     asm volatile("s_waitcnt vmcnt(0)" ::: "memory");
        __builtin_amdgcn_s_barrier();

        int m = (DUAL && c >= CPM) ? 1 : 0;
        int j0 = (c - m * CPM) * 16;
        const float* bias = m ? b1 : b0;
        OutT* out = m ? out1 : out0;
        const bf16x8* W = (const bf16x8*)&buf[cur][0];

        f32x4 acc0 = {0.f, 0.f, 0.f, 0.f}, acc1 = {0.f, 0.f, 0.f, 0.f};
#pragma unroll
        for (int s = 0; s < 4; ++s) {
            bf16x8 wh = W[s * 64 + lane];
            bf16x8 wl = W[256 + s * 64 + lane];
            acc0 = __builtin_amdgcn_mfma_f32_16x16x32_bf16(wh, xh[0][s], acc0, 0, 0, 0);
            acc0 = __builtin_amdgcn_mfma_f32_16x16x32_bf16(wh, xlo[0][s], acc0, 0, 0, 0);
            acc0 = __builtin_amdgcn_mfma_f32_16x16x32_bf16(wl, xh[0][s], acc0, 0, 0, 0);
            acc1 = __builtin_amdgcn_mfma_f32_16x16x32_bf16(wh, xh[1][s], acc1, 0, 0, 0);
            acc1 = __builtin_amdgcn_mfma_f32_16x16x32_bf16(wh, xlo[1][s], acc1, 0, 0, 0);
            acc1 = __builtin_amdgcn_mfma_f32_16x16x32_bf16(wl, xh[1][s], acc1, 0, 0, 0);
        }
        int j = j0 + lk * 4;
        float o0[4], o1[4];
#pragma unroll
        for (int i = 0; i < 4; i++) {
            float bb = bias[j + i];
            if (EPI == 1) bb += style[j + i];
            float v0 = acc0[i] + bb, v1 = acc1[i] + bb;
            if (EPI == 2) { v0 = gelu_f(v0); v1 = gelu_f(v1); }
            o0[i] = v0; o1[i] = v1;
        }
        if constexpr (sizeof(OutT) == 2) {
            u16x4 s0 = {f2h(o0[0]), f2h(o0[1]), f2h(o0[2]), f2h(o0[3])};
            u16x4 s1v = {f2h(o1[0]), f2h(o1[1]), f2h(o1[2]), f2h(o1[3])};
            if (r0 < Nn) *(u16x4*)((unsigned short*)out + (size_t)r0 * OUT + j) = s0;
            if (r1 < Nn) *(u16x4*)((unsigned short*)out + (size_t)r1 * OUT + j) = s1v;
        } else {
            if (r0 < Nn) { f32x4 v = {o0[0], o0[1], o0[2], o0[3]}; *(f32x4*)((float*)out + (size_t)r0 * OUT + j) = v; }
            if (r1 < Nn) { f32x4 v = {o1[0], o1[1], o1[2], o1[3]}; *(f32x4*)((float*)out + (size_t)r1 * OUT + j) = v; }
        }
        __builtin_amdgcn_s_barrier();
    }
}

// ---------------- CSR build (by destination), self-loops appended ----------------
__global__ void count_k(const int* __restrict__ dst, int* __restrict__ counts, int E, int EP) {
    int e = blockIdx.x * blockDim.x + threadIdx.x;
    if (e >= EP) return;
    int d = (e < E) ? dst[e] : (e - E);
    atomicAdd(&counts[d], 1);
}

// hierarchical scan: tile sums -> tile offsets -> per-tile block scan
__global__ void tile_sum_k(const int* __restrict__ counts, int* __restrict__ tsum, int Nn) {
    int i = blockIdx.x * 256 + threadIdx.x;
    int v = (i < Nn) ? counts[i] : 0;
    int lane = threadIdx.x & 63, wave = threadIdx.x >> 6;
#pragma unroll
    for (int off = 1; off < 64; off <<= 1) v += __shfl_xor(v, off, 64);
    __shared__ int red[4];
    if (lane == 0) red[wave] = v;
    __syncthreads();
    if (threadIdx.x == 0) tsum[blockIdx.x] = red[0] + red[1] + red[2] + red[3];
}

__global__ void tile_scan_k(const int* __restrict__ tsum, int* __restrict__ toff,
                            int ntiles, int* __restrict__ rowptr, int Nn, int total) {
    __shared__ int s[256];
    int t = threadIdx.x;
    int v = (t < ntiles) ? tsum[t] : 0;
    s[t] = v;
    __syncthreads();
    for (int off = 1; off < 256; off <<= 1) {
        int a = (t >= off) ? s[t - off] : 0;
        __syncthreads();
        s[t] += a;
        __syncthreads();
    }
    if (t < ntiles) toff[t] = s[t] - v;  // exclusive
    if (t == 0) rowptr[Nn] = total;
}

__global__ void tile_write_k(const int* __restrict__ counts, const int* __restrict__ toff,
                             int* __restrict__ rowptr, int* __restrict__ fillc, int Nn) {
    int i = blockIdx.x * 256 + threadIdx.x;
    int t = threadIdx.x;
    int v = (i < Nn) ? counts[i] : 0;
    if (i < Nn) fillc[i] = 0;
    __shared__ int s[256];
    s[t] = v;
    __syncthreads();
    for (int off = 1; off < 256; off <<= 1) {
        int a = (t >= off) ? s[t - off] : 0;
        __syncthreads();
        s[t] += a;
        __syncthreads();
    }
    if (i < Nn) rowptr[i] = toff[blockIdx.x] + s[t] - v;
}

__global__ void fill_k(const int* __restrict__ src, const int* __restrict__ dst,
                       const int* __restrict__ rowptr, int* __restrict__ fillc,
                       int* __restrict__ col, int E, int EP) {
    int e = blockIdx.x * blockDim.x + threadIdx.x;
    if (e >= EP) return;
    int d = (e < E) ? dst[e] : (e - E);
    int s = (e < E) ? src[e] : (e - E);
    int pos = atomicAdd(&fillc[d], 1);
    col[rowptr[d] + pos] = s;
}

// ------ GATv2 gather: packed-f16 math, 4 edges/iter, 16 lanes x 8ch --------------
// lrelu(t)=max(t,0.2t) in v_pk ops; logit via fdot2 (f32 acc); acc fma from f16
// (fma_mix-foldable). Block 0 zeroes stats for the following gn_stats.
template <int H>
__global__ __launch_bounds__(256) void gat_gather_k(
    const unsigned short* __restrict__ xl, const unsigned short* __restrict__ xr,
    const float* __restrict__ att, const float* __restrict__ bo,
    const int* __restrict__ rowptr, const int* __restrict__ col,
    float* __restrict__ y, float* __restrict__ stats, int Nn) {
    if (blockIdx.x == 0 && threadIdx.x < 256) stats[threadIdx.x] = 0.f;
    constexpr int NPB = (H == 2) ? 2 : 4;   // nodes per block (4 waves)
    int w = threadIdx.x >> 6;
    int slot = (H == 2) ? (w >> 1) : w;
    int h = (H == 2) ? (w & 1) : 0;
    int lane = threadIdx.x & 63;
    int g = lane >> 4, sub = lane & 15;
    constexpr int HC = H * 128;
    int n = blockIdx.x * NPB + slot;
    bool act = n < Nn;
    int nn = act ? n : 0;

    uint4 uxr = *(const uint4*)(xr + (size_t)nn * HC + h * 128 + sub * 8);
    f16x2 xrv[4] = {b2h2(uxr.x), b2h2(uxr.y), b2h2(uxr.z), b2h2(uxr.w)};
    const float* ap = att + h * 128 + sub * 8;
    f16x2 a2[4];
#pragma unroll
    for (int i = 0; i < 4; i++) {
        f16x2 t; t.x = (_Float16)ap[2 * i]; t.y = (_Float16)ap[2 * i + 1];
        a2[i] = t;
    }
    f16x2 c02; c02.x = (_Float16)0.2f; c02.y = (_Float16)0.2f;

    float den = 0.f;
    float acc[8] = {0.f, 0.f, 0.f, 0.f, 0.f, 0.f, 0.f, 0.f};
    int beg = act ? rowptr[n] : 0, endp = act ? rowptr[n + 1] : 0;

    for (int k0 = beg; k0 < endp; k0 += 4) {
        int k = k0 + g;
        bool ev = k < endp;
        int s = col[ev ? k : beg];
        uint4 u = *(const uint4*)(xl + (size_t)s * HC + h * 128 + sub * 8);
        f16x2 v2[4] = {b2h2(u.x), b2h2(u.y), b2h2(u.z), b2h2(u.w)};
        float p = 0.f;
#pragma unroll
        for (int i = 0; i < 4; i++) {
            f16x2 t = v2[i] + xrv[i];
            f16x2 e = __builtin_elementwise_max(t, t * c02);
#if __has_builtin(__builtin_amdgcn_fdot2)
            p = __builtin_amdgcn_fdot2(e, a2[i], p, false);
#else
            p = fmaf((float)e.x, (float)a2[i].x, p);
            p = fmaf((float)e.y, (float)a2[i].y, p);
#endif
        }
        p += __shfl_xor(p, 1, 64);
        p += __shfl_xor(p, 2, 64);
        p += __shfl_xor(p, 4, 64);
        p += __shfl_xor(p, 8, 64);
        float pe = ev ? __expf(p) : 0.f;
        den += pe;
#pragma unroll
        for (int i = 0; i < 4; i++) {
            acc[2 * i]     = fmaf(pe, (float)v2[i].x, acc[2 * i]);
            acc[2 * i + 1] = fmaf(pe, (float)v2[i].y, acc[2 * i + 1]);
        }
    }
#pragma unroll
    for (int off = 16; off <= 32; off <<= 1) {
        den += __shfl_xor(den, off, 64);
#pragma unroll
        for (int j = 0; j < 8; j++) acc[j] += __shfl_xor(acc[j], off, 64);
    }
    float inv = 1.0f / (den + 1e-16f);

    if constexpr (H == 1) {
        if (act && g == 0) {
            const float* bp = bo + sub * 8;
            f32x4 o0 = {acc[0] * inv + bp[0], acc[1] * inv + bp[1], acc[2] * inv + bp[2], acc[3] * inv + bp[3]};
            f32x4 o1 = {acc[4] * inv + bp[4], acc[5] * inv + bp[5], acc[6] * inv + bp[6], acc[7] * inv + bp[7]};
            *(f32x4*)(y + (size_t)n * 128 + sub * 8) = o0;
            *(f32x4*)(y + (size_t)n * 128 + sub * 8 + 4) = o1;
        }
    } else {
        __shared__ float sh[NPB][2][128];
        if (g == 0) {
#pragma unroll
            for (int j = 0; j < 8; j++) sh[slot][h][sub * 8 + j] = acc[j] * inv;
        }
        __syncthreads();
        int t = threadIdx.x;
        int slot2 = t >> 7, c = t & 127;
        int n2 = blockIdx.x * NPB + slot2;
        if (n2 < Nn)
            y[(size_t)n2 * 128 + c] = (sh[slot2][0][c] + sh[slot2][1][c]) * 0.5f + bo[c];
    }
}

// ---------------- GraphNorm stats: per-channel sum & sumsq -----------------------
__global__ void gn_stats_k(const float* __restrict__ y, float* __restrict__ stats, int Nn) {
    int c = threadIdx.x;  // 128 threads
    int per = (Nn + gridDim.x - 1) / gridDim.x;
    int n0 = blockIdx.x * per, n1 = min(n0 + per, Nn);
    float s = 0.f, s2 = 0.f;
    for (int n = n0; n < n1; n++) {
        float v = y[(size_t)n * 128 + c];
        s += v;
        s2 = fmaf(v, v, s2);
    }
    atomicAdd(&stats[c], s);
    atomicAdd(&stats[128 + c], s2);
}

// ---------------- GraphNorm apply + GELU, f32 out --------------------------------
__global__ void gn_apply_k(const float* __restrict__ y, const float* __restrict__ stats,
                           const float* __restrict__ w, const float* __restrict__ b,
                           const float* __restrict__ ms, float* __restrict__ xo, int Nn) {
    int i4 = blockIdx.x * blockDim.x + threadIdx.x;
    if (i4 >= Nn * 32) return;
    float4 v = reinterpret_cast<const float4*>(y)[i4];
    int c0 = (i4 & 31) * 4;
    float o[4] = {v.x, v.y, v.z, v.w};
    float invN = 1.0f / (float)Nn;
#pragma unroll
    for (int jj = 0; jj < 4; jj++) {
        int c = c0 + jj;
        float mu = stats[c] * invN;
        float ex2 = stats[128 + c] * invN;
        float msv = ms[c];
        float var = ex2 - 2.f * msv * mu * mu + msv * msv * mu * mu;
        float ov = o[jj] - msv * mu;
        float r = rsqrtf(var + 1e-5f);
        o[jj] = gelu_f(fmaf(w[c], ov * r, b[c]));
    }
    float4 res = make_float4(o[0], o[1], o[2], o[3]);
    reinterpret_cast<float4*>(xo)[i4] = res;
}

// ---------------- final head: out = h@W_h2 + b_h2 (OUT=3) ------------------------
__global__ void head2_k(const float* __restrict__ h, const float* __restrict__ W,
                        const float* __restrict__ b, float* __restrict__ out, int Nn) {
    __shared__ float w[192];
    __shared__ float bb[3];
    int t = threadIdx.x;
    if (t < 192) w[t] = W[t];
    if (t < 3) bb[t] = b[t];
    __syncthreads();
    int n = blockIdx.x * blockDim.x + t;
    if (n >= Nn) return;
    float a0 = bb[0], a1 = bb[1], a2 = bb[2];
    const float4* h4 = reinterpret_cast<const float4*>(h + (size_t)n * 64);
    for (int k4 = 0; k4 < 16; k4++) {
        float4 v = h4[k4];
        int k = k4 * 4;
        a0 = fmaf(v.x, w[(k + 0) * 3 + 0], a0); a1 = fmaf(v.x, w[(k + 0) * 3 + 1], a1); a2 = fmaf(v.x, w[(k + 0) * 3 + 2], a2);
        a0 = fmaf(v.y, w[(k + 1) * 3 + 0], a0); a1 = fmaf(v.y, w[(k + 1) * 3 + 1], a1); a2 = fmaf(v.y, w[(k + 1) * 3 + 2], a2);
        a0 = fmaf(v.z, w[(k + 2) * 3 + 0], a0); a1 = fmaf(v.z, w[(k + 2) * 3 + 1], a1); a2 = fmaf(v.z, w[(k + 2) * 3 + 2], a2);
        a0 = fmaf(v.w, w[(k + 3) * 3 + 0], a0); a1 = fmaf(v.w, w[(k + 3) * 3 + 1], a1); a2 = fmaf(v.w, w[(k + 3) * 3 + 2], a2);
    }
    out[n * 3 + 0] = a0;
    out[n * 3 + 1] = a1;
    out[n * 3 + 2] = a2;
}

extern "C" void kernel_launch(void* const* d_in, const int* in_sizes, int n_in,
                              void* d_out, int out_size, void* d_ws, size_t ws_size,
                              hipStream_t stream) {
    const float* zg = (const float*)d_in[0];
    const int* ei = (const int*)d_in[1];
    const float* tv = (const float*)d_in[2];
    const float* W_ne1 = (const float*)d_in[3];
    const float* b_ne1 = (const float*)d_in[4];
    const float* W_ne2 = (const float*)d_in[5];
    const float* b_ne2 = (const float*)d_in[6];
    const float* W_s1 = (const float*)d_in[7];
    const float* b_s1 = (const float*)d_in[8];
    const float* W_s2 = (const float*)d_in[9];
    const float* b_s2 = (const float*)d_in[10];
    const float *Wl[3], *bl[3], *Wr[3], *br[3], *attp[3], *bop[3], *gnw[3], *gnb[3], *gnms[3];
    for (int L = 0; L < 3; L++) {
        int base = 11 + L * 9;
        Wl[L] = (const float*)d_in[base + 0];
        bl[L] = (const float*)d_in[base + 1];
        Wr[L] = (const float*)d_in[base + 2];
        br[L] = (const float*)d_in[base + 3];
        attp[L] = (const float*)d_in[base + 4];
        bop[L] = (const float*)d_in[base + 5];
        gnw[L] = (const float*)d_in[base + 6];
        gnb[L] = (const float*)d_in[base + 7];
        gnms[L] = (const float*)d_in[base + 8];
    }
    const float* W_h1 = (const float*)d_in[38];
    const float* b_h1 = (const float*)d_in[39];
    const float* W_h2 = (const float*)d_in[40];
    const float* b_h2 = (const float*)d_in[41];

    int E = in_sizes[1] / 2;
    int N = in_sizes[2] / 3;
    int EP = E + N;
    int NT = (N + 255) / 256;
    const int* srcp = ei;
    const int* dstp = ei + E;

    char* p = (char*)d_ws;
    auto alloc = [&](size_t bytes) -> char* {
        char* r = p;
        p += (bytes + 255) & ~(size_t)255;
        return r;
    };
    float* style = (float*)alloc(512);
    float* h1 = (float*)alloc((size_t)N * 128 * 4);
    float* x = (float*)alloc((size_t)N * 128 * 4);
    unsigned short* xle = (unsigned short*)alloc((size_t)N * 256 * 2);
    unsigned short* xre = (unsigned short*)alloc((size_t)N * 256 * 2);
    float* y = (float*)alloc((size_t)N * 128 * 4);
    float* hb = (float*)alloc((size_t)N * 64 * 4);
    float* stats = (float*)alloc(1024);
    int* rowptr = (int*)alloc(((size_t)N + 1) * 4);
    int* counts = (int*)alloc((size_t)N * 4);
    int* fillc = (int*)alloc((size_t)N * 4);
    int* col = (int*)alloc((size_t)EP * 4);
    int* tsum = (int*)alloc((size_t)NT * 4);
    int* toff = (int*)alloc((size_t)NT * 4);
    unsigned short* wt = (unsigned short*)alloc((size_t)376832 * 2);

    // weight prep: 8 segments, staged fragment-order hi/lo layout
    PrepArgs pa;
    const float* srcs[8] = {W_ne2, Wl[0], Wr[0], Wl[1], Wr[1], Wl[2], Wr[2], W_h1};
    int outs[8] = {128, 256, 256, 256, 256, 128, 128, 64};
    int off = 0;
    pa.dst = wt;
    for (int s = 0; s < 8; s++) {
        pa.src[s] = srcs[s];
        pa.off[s] = off;
        pa.dstoff[s] = 2 * off;
        pa.shift[s] = (outs[s] == 256) ? 8 : (outs[s] == 128 ? 7 : 6);
        off += 128 * outs[s];
    }
    pa.off[8] = off;
    const unsigned short* ws_ne2 = wt + pa.dstoff[0];
    const unsigned short* ws_l[3] = {wt + pa.dstoff[1], wt + pa.dstoff[3], wt + pa.dstoff[5]};
    const unsigned short* ws_r[3] = {wt + pa.dstoff[2], wt + pa.dstoff[4], wt + pa.dstoff[6]};
    const unsigned short* ws_h1 = wt + pa.dstoff[7];
    prep_k<<<(off + 255) / 256, 256, 0, stream>>>(pa);

    // style + node embedding (ne1 also zeroes counts)
    style_k<<<1, 128, 0, stream>>>(zg, W_s1, b_s1, W_s2, b_s2, style);
    ne1_k<<<(N * 128 + 255) / 256, 256, 0, stream>>>(tv, W_ne1, b_ne1, h1, counts, N);
    mfma_lin_k<128, 1, false, float><<<(N + 127) / 128, 256, 0, stream>>>(
        h1, ws_ne2, b_ne2, nullptr, nullptr, style, x, nullptr, N);

    // CSR by destination (rebuilt every launch); hierarchical scan
    count_k<<<(EP + 255) / 256, 256, 0, stream>>>(dstp, counts, E, EP);
    tile_sum_k<<<NT, 256, 0, stream>>>(counts, tsum, N);
    tile_scan_k<<<1, 256, 0, stream>>>(tsum, toff, NT, rowptr, N, EP);
    tile_write_k<<<NT, 256, 0, stream>>>(counts, toff, rowptr, fillc, N);
    fill_k<<<(EP + 255) / 256, 256, 0, stream>>>(srcp, dstp, rowptr, fillc, col, E, EP);

    const int HS[3] = {2, 2, 1};
    for (int L = 0; L < 3; L++) {
        if (HS[L] == 2) {
            mfma_lin_k<256, 0, true, unsigned short><<<(N + 127) / 128, 256, 0, stream>>>(
                x, ws_l[L], bl[L], ws_r[L], br[L], nullptr, xle, xre, N);
            gat_gather_k<2><<<(N + 1) / 2, 256, 0, stream>>>(xle, xre, attp[L], bop[L], rowptr, col, y, stats, N);
        } else {
            mfma_lin_k<128, 0, true, unsigned short><<<(N + 127) / 128, 256, 0, stream>>>(
                x, ws_l[L], bl[L], ws_r[L], br[L], nullptr, xle, xre, N);
            gat_gather_k<1><<<(N + 3) / 4, 256, 0, stream>>>(xle, xre, attp[L], bop[L], rowptr, col, y, stats, N);
        }
        gn_stats_k<<<512, 128, 0, stream>>>(y, stats, N);
        gn_apply_k<<<(N * 32 + 255) / 256, 256, 0, stream>>>(y, stats, gnw[L], gnb[L], gnms[L], x, N);
    }

    // head: h = gelu(x@W_h1+b_h1) (split-MFMA, f32 out); out = h@W_h2 + b_h2
    mfma_lin_k<64, 2, false, float><<<(N + 127) / 128, 256, 0, stream>>>(
        x, ws_h1, b_h1, nullptr, nullptr, nullptr, hb, nullptr, N);
    head2_k<<<(N + 255) / 256, 256, 0, stream>>>(hb, W_h2, b_h2, (float*)d_out, N);
}

// Round 12
// 607.180 us; speedup vs baseline: 1.4870x; 1.0984x over previous
//
#include <hip/hip_runtime.h>
#include <hip/hip_fp16.h>
#include <math.h>

#define DEVINL __device__ __forceinline__

using bf16x8 = __attribute__((ext_vector_type(8))) short;
using f32x4  = __attribute__((ext_vector_type(4))) float;
using u16x4  = __attribute__((ext_vector_type(4))) unsigned short;
using f16x2  = __attribute__((ext_vector_type(2))) _Float16;

DEVINL float gelu_f(float v) { return 0.5f * v * (1.0f + erff(v * 0.7071067811865475f)); }
DEVINL unsigned short f2bf(float f) {
    union { float f; unsigned u; } c; c.f = f;
    unsigned r = c.u + 0x7fffu + ((c.u >> 16) & 1u);
    return (unsigned short)(r >> 16);
}
DEVINL float bf2f(unsigned short s) {
    union { unsigned u; float f; } c; c.u = (unsigned)s << 16;
    return c.f;
}
DEVINL unsigned short f2h(float f) {
    __half h = __float2half_rn(f);
    return *(unsigned short*)&h;
}
DEVINL f16x2 b2h2(unsigned u) {
    union { unsigned u; f16x2 h; } c; c.u = u; return c.h;
}
DEVINL void gl_lds16(const void* g, void* l) {
    __builtin_amdgcn_global_load_lds(
        (const __attribute__((address_space(1))) unsigned*)g,
        (__attribute__((address_space(3))) unsigned*)l, 16, 0, 0);
}

// ---------------- style: style = gelu(z_g@W_s1+b_s1)@W_s2 + b_s2 ----------------
__global__ void style_k(const float* __restrict__ zg, const float* __restrict__ W1,
                        const float* __restrict__ b1, const float* __restrict__ W2,
                        const float* __restrict__ b2, float* __restrict__ style) {
    __shared__ float s1[128];
    int j = threadIdx.x;
    float a = b1[j];
    for (int k = 0; k < 256; k++) a = fmaf(zg[k], W1[k * 128 + j], a);
    s1[j] = gelu_f(a);
    __syncthreads();
    float o = b2[j];
    for (int k = 0; k < 128; k++) o = fmaf(s1[k], W2[k * 128 + j], o);
    style[j] = o;
}

// ------ node-embed layer 1 (+ fused counts zeroing for the CSR build) ------------
__global__ void ne1_k(const float* __restrict__ tv, const float* __restrict__ W,
                      const float* __restrict__ b, float* __restrict__ h1,
                      int* __restrict__ counts, int Nn) {
    int idx = blockIdx.x * blockDim.x + threadIdx.x;
    if (idx < Nn) counts[idx] = 0;
    if (idx >= Nn * 128) return;
    int n = idx >> 7, c = idx & 127;
    float o = fmaf(tv[n * 3 + 0], W[c],
              fmaf(tv[n * 3 + 1], W[128 + c],
              fmaf(tv[n * 3 + 2], W[256 + c], b[c])));
    h1[idx] = gelu_f(o);
}

// -------- weight prep: f32 W[128][OUT] -> staged fragment-order hi/lo chunks -----
struct PrepArgs {
    const float* src[8];
    unsigned short* dst;
    int dstoff[8];  // in shorts
    int off[9];     // source element offsets
    int shift[8];   // log2(OUT)
};
__global__ void prep_k(PrepArgs a) {
    int idx = blockIdx.x * 256 + threadIdx.x;
    if (idx >= a.off[8]) return;
    int s = 0;
    while (idx >= a.off[s + 1]) s++;
    int e = idx - a.off[s];
    int sh = a.shift[s];
    int k = e >> sh, j = e & ((1 << sh) - 1);
    float w = a.src[s][e];
    unsigned short hi = f2bf(w);
    unsigned short lo = f2bf(w - bf2f(hi));
    int c = j >> 4, lr = j & 15;
    int s2 = k >> 5, lk = (k >> 3) & 3, i = k & 7;
    int lane = lk * 16 + lr;
    size_t base = (size_t)a.dstoff[s] + (size_t)c * 4096 + s2 * 512 + lane * 8 + i;
    a.dst[base] = hi;
    a.dst[base + 2048] = lo;
}

// ---------------- split-MFMA linear: LDS double-buffered weight chunks -----------
// PRE=0: raw f32 input rows. PRE=2: input y + per-channel affine norm (A,B) + gelu
// fused into the fragment-load phase (replaces the standalone gn_apply kernel).
template <int OUT, int EPI, bool DUAL, typename OutT, int PRE>
__global__ __launch_bounds__(256) void mfma_lin_k(
    const float* __restrict__ xin,
    const unsigned short* __restrict__ WT0, const float* __restrict__ b0,
    const unsigned short* __restrict__ WT1, const float* __restrict__ b1,
    const float* __restrict__ style, const float* __restrict__ AB,
    OutT* __restrict__ out0, OutT* __restrict__ out1, int Nn) {
    constexpr int CPM = OUT / 16;
    constexpr int NCH = (DUAL ? 2 : 1) * CPM;
    __shared__ uint4 buf[2][512];  // 2 x 8KB
    int t = threadIdx.x;
    int wave = t >> 6, lane = t & 63;
    int lr = lane & 15, lk = lane >> 4;
    int base = blockIdx.x * 128 + wave * 32;
    int r0 = base + lr, r1 = base + 16 + lr;
    int cr0 = min(r0, Nn - 1), cr1 = min(r1, Nn - 1);
    const float* px0 = xin + (size_t)cr0 * 128;
    const float* px1 = xin + (size_t)cr1 * 128;

    bf16x8 xh[2][4], xlo[2][4];
#pragma unroll
    for (int s = 0; s < 4; s++) {
        int cb = s * 32 + lk * 8;
        float A_[8], B_[8];
        if constexpr (PRE == 2) {
            *(f32x4*)&A_[0] = *(const f32x4*)(AB + cb);
            *(f32x4*)&A_[4] = *(const f32x4*)(AB + cb + 4);
            *(f32x4*)&B_[0] = *(const f32x4*)(AB + 128 + cb);
            *(f32x4*)&B_[4] = *(const f32x4*)(AB + 128 + cb + 4);
        }
#pragma unroll
        for (int rr = 0; rr < 2; rr++) {
            const float4* p4 = (const float4*)((rr ? px1 : px0) + cb);
            float4 a = p4[0], b = p4[1];
            float v[8] = {a.x, a.y, a.z, a.w, b.x, b.y, b.z, b.w};
            if constexpr (PRE == 2) {
#pragma unroll
                for (int i = 0; i < 8; i++) v[i] = gelu_f(fmaf(A_[i], v[i], B_[i]));
            }
            bf16x8 h, l;
#pragma unroll
            for (int i = 0; i < 8; i++) {
                unsigned short hb = f2bf(v[i]);
                h[i] = (short)hb;
                l[i] = (short)f2bf(v[i] - bf2f(hb));
            }
            xh[rr][s] = h;
            xlo[rr][s] = l;
        }
    }

    auto stage = [&](int c, int bsel) {
        const unsigned short* Wt = (DUAL && c >= CPM) ? WT1 : WT0;
        int cc = (DUAL && c >= CPM) ? c - CPM : c;
        const char* g = (const char*)(Wt + (size_t)cc * 4096);
        char* l = (char*)&buf[bsel][0];
        gl_lds16(g + t * 16, l + wave * 1024);
        gl_lds16(g + 4096 + t * 16, l + 4096 + wave * 1024);
    };

    stage(0, 0);
    for (int c = 0; c < NCH; ++c) {
        int cur = c & 1;
        bool pre = (c + 1 < NCH);
        if (pre) stage(c + 1, cur ^ 1);
        if (pre) asm volatile("s_waitcnt vmcnt(2)" ::: "memory");
        else     asm volatile("s_waitcnt vmcnt(0)" ::: "memory");
        __builtin_amdgcn_s_barrier();

        int m = (DUAL && c >= CPM) ? 1 : 0;
        int j0 = (c - m * CPM) * 16;
        const float* bias = m ? b1 : b0;
        OutT* out = m ? out1 : out0;
        const bf16x8* W = (const bf16x8*)&buf[cur][0];

        f32x4 acc0 = {0.f, 0.f, 0.f, 0.f}, acc1 = {0.f, 0.f, 0.f, 0.f};
#pragma unroll
        for (int s = 0; s < 4; ++s) {
            bf16x8 wh = W[s * 64 + lane];
            bf16x8 wl = W[256 + s * 64 + lane];
            acc0 = __builtin_amdgcn_mfma_f32_16x16x32_bf16(wh, xh[0][s], acc0, 0, 0, 0);
            acc0 = __builtin_amdgcn_mfma_f32_16x16x32_bf16(wh, xlo[0][s], acc0, 0, 0, 0);
            acc0 = __builtin_amdgcn_mfma_f32_16x16x32_bf16(wl, xh[0][s], acc0, 0, 0, 0);
            acc1 = __builtin_amdgcn_mfma_f32_16x16x32_bf16(wh, xh[1][s], acc1, 0, 0, 0);
            acc1 = __builtin_amdgcn_mfma_f32_16x16x32_bf16(wh, xlo[1][s], acc1, 0, 0, 0);
            acc1 = __builtin_amdgcn_mfma_f32_16x16x32_bf16(wl, xh[1][s], acc1, 0, 0, 0);
        }
        int j = j0 + lk * 4;
        float o0[4], o1[4];
#pragma unroll
        for (int i = 0; i < 4; i++) {
            float bb = bias[j + i];
            if (EPI == 1) bb += style[j + i];
            float v0 = acc0[i] + bb, v1 = acc1[i] + bb;
            if (EPI == 2) { v0 = gelu_f(v0); v1 = gelu_f(v1); }
            o0[i] = v0; o1[i] = v1;
        }
        if constexpr (sizeof(OutT) == 2) {
            u16x4 s0 = {f2h(o0[0]), f2h(o0[1]), f2h(o0[2]), f2h(o0[3])};
            u16x4 s1v = {f2h(o1[0]), f2h(o1[1]), f2h(o1[2]), f2h(o1[3])};
            if (r0 < Nn) *(u16x4*)((unsigned short*)out + (size_t)r0 * OUT + j) = s0;
            if (r1 < Nn) *(u16x4*)((unsigned short*)out + (size_t)r1 * OUT + j) = s1v;
        } else {
            if (r0 < Nn) { f32x4 v = {o0[0], o0[1], o0[2], o0[3]}; *(f32x4*)((float*)out + (size_t)r0 * OUT + j) = v; }
            if (r1 < Nn) { f32x4 v = {o1[0], o1[1], o1[2], o1[3]}; *(f32x4*)((float*)out + (size_t)r1 * OUT + j) = v; }
        }
        __builtin_amdgcn_s_barrier();
    }
}

// ---------------- CSR build (by destination), self-loops appended ----------------
__global__ void count_k(const int* __restrict__ dst, int* __restrict__ counts, int E, int EP) {
    int e = blockIdx.x * blockDim.x + threadIdx.x;
    if (e >= EP) return;
    int d = (e < E) ? dst[e] : (e - E);
    atomicAdd(&counts[d], 1);
}

// hierarchical scan: tile sums -> tile offsets -> per-tile block scan
__global__ void tile_sum_k(const int* __restrict__ counts, int* __restrict__ tsum, int Nn) {
    int i = blockIdx.x * 256 + threadIdx.x;
    int v = (i < Nn) ? counts[i] : 0;
    int lane = threadIdx.x & 63, wave = threadIdx.x >> 6;
#pragma unroll
    for (int off = 1; off < 64; off <<= 1) v += __shfl_xor(v, off, 64);
    __shared__ int red[4];
    if (lane == 0) red[wave] = v;
    __syncthreads();
    if (threadIdx.x == 0) tsum[blockIdx.x] = red[0] + red[1] + red[2] + red[3];
}

__global__ void tile_scan_k(const int* __restrict__ tsum, int* __restrict__ toff,
                            int ntiles, int* __restrict__ rowptr, int Nn, int total) {
    __shared__ int s[256];
    int t = threadIdx.x;
    int v = (t < ntiles) ? tsum[t] : 0;
    s[t] = v;
    __syncthreads();
    for (int off = 1; off < 256; off <<= 1) {
        int a = (t >= off) ? s[t - off] : 0;
        __syncthreads();
        s[t] += a;
        __syncthreads();
    }
    if (t < ntiles) toff[t] = s[t] - v;  // exclusive
    if (t == 0) rowptr[Nn] = total;
}

__global__ void tile_write_k(const int* __restrict__ counts, const int* __restrict__ toff,
                             int* __restrict__ rowptr, int* __restrict__ fillc, int Nn) {
    int i = blockIdx.x * 256 + threadIdx.x;
    int t = threadIdx.x;
    int v = (i < Nn) ? counts[i] : 0;
    if (i < Nn) fillc[i] = 0;
    __shared__ int s[256];
    s[t] = v;
    __syncthreads();
    for (int off = 1; off < 256; off <<= 1) {
        int a = (t >= off) ? s[t - off] : 0;
        __syncthreads();
        s[t] += a;
        __syncthreads();
    }
    if (i < Nn) rowptr[i] = toff[blockIdx.x] + s[t] - v;
}

__global__ void fill_k(const int* __restrict__ src, const int* __restrict__ dst,
                       const int* __restrict__ rowptr, int* __restrict__ fillc,
                       int* __restrict__ col, int E, int EP) {
    int e = blockIdx.x * blockDim.x + threadIdx.x;
    if (e >= EP) return;
    int d = (e < E) ? dst[e] : (e - E);
    int s = (e < E) ? src[e] : (e - E);
    int pos = atomicAdd(&fillc[d], 1);
    col[rowptr[d] + pos] = s;
}

// ------ GATv2 gather: packed-f16 math, 4 edges/iter, 16 lanes x 8ch --------------
template <int H>
__global__ __launch_bounds__(256) void gat_gather_k(
    const unsigned short* __restrict__ xl, const unsigned short* __restrict__ xr,
    const float* __restrict__ att, const float* __restrict__ bo,
    const int* __restrict__ rowptr, const int* __restrict__ col,
    float* __restrict__ y, float* __restrict__ stats, int Nn) {
    if (blockIdx.x == 0 && threadIdx.x < 256) stats[threadIdx.x] = 0.f;
    constexpr int NPB = (H == 2) ? 2 : 4;   // nodes per block (4 waves)
    int w = threadIdx.x >> 6;
    int slot = (H == 2) ? (w >> 1) : w;
    int h = (H == 2) ? (w & 1) : 0;
    int lane = threadIdx.x & 63;
    int g = lane >> 4, sub = lane & 15;
    constexpr int HC = H * 128;
    int n = blockIdx.x * NPB + slot;
    bool act = n < Nn;
    int nn = act ? n : 0;

    uint4 uxr = *(const uint4*)(xr + (size_t)nn * HC + h * 128 + sub * 8);
    f16x2 xrv[4] = {b2h2(uxr.x), b2h2(uxr.y), b2h2(uxr.z), b2h2(uxr.w)};
    const float* ap = att + h * 128 + sub * 8;
    f16x2 a2[4];
#pragma unroll
    for (int i = 0; i < 4; i++) {
        f16x2 t; t.x = (_Float16)ap[2 * i]; t.y = (_Float16)ap[2 * i + 1];
        a2[i] = t;
    }
    f16x2 c02; c02.x = (_Float16)0.2f; c02.y = (_Float16)0.2f;

    float den = 0.f;
    float acc[8] = {0.f, 0.f, 0.f, 0.f, 0.f, 0.f, 0.f, 0.f};
    int beg = act ? rowptr[n] : 0, endp = act ? rowptr[n + 1] : 0;

    for (int k0 = beg; k0 < endp; k0 += 4) {
        int k = k0 + g;
        bool ev = k < endp;
        int s = col[ev ? k : beg];
        uint4 u = *(const uint4*)(xl + (size_t)s * HC + h * 128 + sub * 8);
        f16x2 v2[4] = {b2h2(u.x), b2h2(u.y), b2h2(u.z), b2h2(u.w)};
        float p = 0.f;
#pragma unroll
        for (int i = 0; i < 4; i++) {
            f16x2 t = v2[i] + xrv[i];
            f16x2 e = __builtin_elementwise_max(t, t * c02);
#if __has_builtin(__builtin_amdgcn_fdot2)
            p = __builtin_amdgcn_fdot2(e, a2[i], p, false);
#else
            p = fmaf((float)e.x, (float)a2[i].x, p);
            p = fmaf((float)e.y, (float)a2[i].y, p);
#endif
        }
        p += __shfl_xor(p, 1, 64);
        p += __shfl_xor(p, 2, 64);
        p += __shfl_xor(p, 4, 64);
        p += __shfl_xor(p, 8, 64);
        float pe = ev ? __expf(p) : 0.f;
        den += pe;
#pragma unroll
        for (int i = 0; i < 4; i++) {
            acc[2 * i]     = fmaf(pe, (float)v2[i].x, acc[2 * i]);
            acc[2 * i + 1] = fmaf(pe, (float)v2[i].y, acc[2 * i + 1]);
        }
    }
#pragma unroll
    for (int off = 16; off <= 32; off <<= 1) {
        den += __shfl_xor(den, off, 64);
#pragma unroll
        for (int j = 0; j < 8; j++) acc[j] += __shfl_xor(acc[j], off, 64);
    }
    float inv = 1.0f / (den + 1e-16f);

    if constexpr (H == 1) {
        if (act && g == 0) {
            const float* bp = bo + sub * 8;
            f32x4 o0 = {acc[0] * inv + bp[0], acc[1] * inv + bp[1], acc[2] * inv + bp[2], acc[3] * inv + bp[3]};
            f32x4 o1 = {acc[4] * inv + bp[4], acc[5] * inv + bp[5], acc[6] * inv + bp[6], acc[7] * inv + bp[7]};
            *(f32x4*)(y + (size_t)n * 128 + sub * 8) = o0;
            *(f32x4*)(y + (size_t)n * 128 + sub * 8 + 4) = o1;
        }
    } else {
        __shared__ float sh[NPB][2][128];
        if (g == 0) {
#pragma unroll
            for (int j = 0; j < 8; j++) sh[slot][h][sub * 8 + j] = acc[j] * inv;
        }
        __syncthreads();
        int t = threadIdx.x;
        int slot2 = t >> 7, c = t & 127;
        int n2 = blockIdx.x * NPB + slot2;
        if (n2 < Nn)
            y[(size_t)n2 * 128 + c] = (sh[slot2][0][c] + sh[slot2][1][c]) * 0.5f + bo[c];
    }
}

// ---------------- GraphNorm stats: per-channel sum & sumsq -----------------------
__global__ void gn_stats_k(const float* __restrict__ y, float* __restrict__ stats, int Nn) {
    int c = threadIdx.x;  // 128 threads
    int per = (Nn + gridDim.x - 1) / gridDim.x;
    int n0 = blockIdx.x * per, n1 = min(n0 + per, Nn);
    float s = 0.f, s2 = 0.f;
    for (int n = n0; n < n1; n++) {
        float v = y[(size_t)n * 128 + c];
        s += v;
        s2 = fmaf(v, v, s2);
    }
    atomicAdd(&stats[c], s);
    atomicAdd(&stats[128 + c], s2);
}

// ------- GraphNorm finalize: stats -> per-channel affine (A, B) ------------------
// apply is out = gelu(A*y + B), fused into the consumer mfma_lin (PRE=2).
__global__ void gn_final_k(const float* __restrict__ stats, const float* __restrict__ w,
                           const float* __restrict__ b, const float* __restrict__ ms,
                           float* __restrict__ AB, float invN) {
    int c = threadIdx.x;
    float mu = stats[c] * invN;
    float ex2 = stats[128 + c] * invN;
    float msv = ms[c];
    float var = ex2 - 2.f * msv * mu * mu + msv * msv * mu * mu;
    float r = rsqrtf(var + 1e-5f);
    float A = w[c] * r;
    AB[c] = A;
    AB[128 + c] = b[c] - A * msv * mu;
}

// ---------------- final head: out = h@W_h2 + b_h2 (OUT=3) ------------------------
__global__ void head2_k(const float* __restrict__ h, const float* __restrict__ W,
                        const float* __restrict__ b, float* __restrict__ out, int Nn) {
    __shared__ float w[192];
    __shared__ float bb[3];
    int t = threadIdx.x;
    if (t < 192) w[t] = W[t];
    if (t < 3) bb[t] = b[t];
    __syncthreads();
    int n = blockIdx.x * blockDim.x + t;
    if (n >= Nn) return;
    float a0 = bb[0], a1 = bb[1], a2 = bb[2];
    const float4* h4 = reinterpret_cast<const float4*>(h + (size_t)n * 64);
    for (int k4 = 0; k4 < 16; k4++) {
        float4 v = h4[k4];
        int k = k4 * 4;
        a0 = fmaf(v.x, w[(k + 0) * 3 + 0], a0); a1 = fmaf(v.x, w[(k + 0) * 3 + 1], a1); a2 = fmaf(v.x, w[(k + 0) * 3 + 2], a2);
        a0 = fmaf(v.y, w[(k + 1) * 3 + 0], a0); a1 = fmaf(v.y, w[(k + 1) * 3 + 1], a1); a2 = fmaf(v.y, w[(k + 1) * 3 + 2], a2);
        a0 = fmaf(v.z, w[(k + 2) * 3 + 0], a0); a1 = fmaf(v.z, w[(k + 2) * 3 + 1], a1); a2 = fmaf(v.z, w[(k + 2) * 3 + 2], a2);
        a0 = fmaf(v.w, w[(k + 3) * 3 + 0], a0); a1 = fmaf(v.w, w[(k + 3) * 3 + 1], a1); a2 = fmaf(v.w, w[(k + 3) * 3 + 2], a2);
    }
    out[n * 3 + 0] = a0;
    out[n * 3 + 1] = a1;
    out[n * 3 + 2] = a2;
}

extern "C" void kernel_launch(void* const* d_in, const int* in_sizes, int n_in,
                              void* d_out, int out_size, void* d_ws, size_t ws_size,
                              hipStream_t stream) {
    const float* zg = (const float*)d_in[0];
    const int* ei = (const int*)d_in[1];
    const float* tv = (const float*)d_in[2];
    const float* W_ne1 = (const float*)d_in[3];
    const float* b_ne1 = (const float*)d_in[4];
    const float* W_ne2 = (const float*)d_in[5];
    const float* b_ne2 = (const float*)d_in[6];
    const float* W_s1 = (const float*)d_in[7];
    const float* b_s1 = (const float*)d_in[8];
    const float* W_s2 = (const float*)d_in[9];
    const float* b_s2 = (const float*)d_in[10];
    const float *Wl[3], *bl[3], *Wr[3], *br[3], *attp[3], *bop[3], *gnw[3], *gnb[3], *gnms[3];
    for (int L = 0; L < 3; L++) {
        int base = 11 + L * 9;
        Wl[L] = (const float*)d_in[base + 0];
        bl[L] = (const float*)d_in[base + 1];
        Wr[L] = (const float*)d_in[base + 2];
        br[L] = (const float*)d_in[base + 3];
        attp[L] = (const float*)d_in[base + 4];
        bop[L] = (const float*)d_in[base + 5];
        gnw[L] = (const float*)d_in[base + 6];
        gnb[L] = (const float*)d_in[base + 7];
        gnms[L] = (const float*)d_in[base + 8];
    }
    const float* W_h1 = (const float*)d_in[38];
    const float* b_h1 = (const float*)d_in[39];
    const float* W_h2 = (const float*)d_in[40];
    const float* b_h2 = (const float*)d_in[41];

    int E = in_sizes[1] / 2;
    int N = in_sizes[2] / 3;
    int EP = E + N;
    int NT = (N + 255) / 256;
    const int* srcp = ei;
    const int* dstp = ei + E;

    char* p = (char*)d_ws;
    auto alloc = [&](size_t bytes) -> char* {
        char* r = p;
        p += (bytes + 255) & ~(size_t)255;
        return r;
    };
    float* style = (float*)alloc(512);
    float* h1 = (float*)alloc((size_t)N * 128 * 4);
    float* x = (float*)alloc((size_t)N * 128 * 4);
    unsigned short* xle = (unsigned short*)alloc((size_t)N * 256 * 2);
    unsigned short* xre = (unsigned short*)alloc((size_t)N * 256 * 2);
    float* y = (float*)alloc((size_t)N * 128 * 4);
    float* hb = (float*)alloc((size_t)N * 64 * 4);
    float* stats = (float*)alloc(1024);
    float* AB = (float*)alloc(1024);
    int* rowptr = (int*)alloc(((size_t)N + 1) * 4);
    int* counts = (int*)alloc((size_t)N * 4);
    int* fillc = (int*)alloc((size_t)N * 4);
    int* col = (int*)alloc((size_t)EP * 4);
    int* tsum = (int*)alloc((size_t)NT * 4);
    int* toff = (int*)alloc((size_t)NT * 4);
    unsigned short* wt = (unsigned short*)alloc((size_t)376832 * 2);

    // weight prep: 8 segments, staged fragment-order hi/lo layout
    PrepArgs pa;
    const float* srcs[8] = {W_ne2, Wl[0], Wr[0], Wl[1], Wr[1], Wl[2], Wr[2], W_h1};
    int outs[8] = {128, 256, 256, 256, 256, 128, 128, 64};
    int off = 0;
    pa.dst = wt;
    for (int s = 0; s < 8; s++) {
        pa.src[s] = srcs[s];
        pa.off[s] = off;
        pa.dstoff[s] = 2 * off;
        pa.shift[s] = (outs[s] == 256) ? 8 : (outs[s] == 128 ? 7 : 6);
        off += 128 * outs[s];
    }
    pa.off[8] = off;
    const unsigned short* ws_ne2 = wt + pa.dstoff[0];
    const unsigned short* ws_l[3] = {wt + pa.dstoff[1], wt + pa.dstoff[3], wt + pa.dstoff[5]};
    const unsigned short* ws_r[3] = {wt + pa.dstoff[2], wt + pa.dstoff[4], wt + pa.dstoff[6]};
    const unsigned short* ws_h1 = wt + pa.dstoff[7];
    prep_k<<<(off + 255) / 256, 256, 0, stream>>>(pa);

    float invN = 1.0f / (float)N;

    // style + node embedding (ne1 also zeroes counts)
    style_k<<<1, 128, 0, stream>>>(zg, W_s1, b_s1, W_s2, b_s2, style);
    ne1_k<<<(N * 128 + 255) / 256, 256, 0, stream>>>(tv, W_ne1, b_ne1, h1, counts, N);
    mfma_lin_k<128, 1, false, float, 0><<<(N + 127) / 128, 256, 0, stream>>>(
        h1, ws_ne2, b_ne2, nullptr, nullptr, style, nullptr, x, nullptr, N);

    // CSR by destination (rebuilt every launch); hierarchical scan
    count_k<<<(EP + 255) / 256, 256, 0, stream>>>(dstp, counts, E, EP);
    tile_sum_k<<<NT, 256, 0, stream>>>(counts, tsum, N);
    tile_scan_k<<<1, 256, 0, stream>>>(tsum, toff, NT, rowptr, N, EP);
    tile_write_k<<<NT, 256, 0, stream>>>(counts, toff, rowptr, fillc, N);
    fill_k<<<(EP + 255) / 256, 256, 0, stream>>>(srcp, dstp, rowptr, fillc, col, E, EP);

    // ---- layer 1 (H=2): input x (raw) ----
    mfma_lin_k<256, 0, true, unsigned short, 0><<<(N + 127) / 128, 256, 0, stream>>>(
        x, ws_l[0], bl[0], ws_r[0], br[0], nullptr, nullptr, xle, xre, N);
    gat_gather_k<2><<<(N + 1) / 2, 256, 0, stream>>>(xle, xre, attp[0], bop[0], rowptr, col, y, stats, N);
    gn_stats_k<<<512, 128, 0, stream>>>(y, stats, N);
    gn_final_k<<<1, 128, 0, stream>>>(stats, gnw[0], gnb[0], gnms[0], AB, invN);

    // ---- layer 2 (H=2): input y + fused norm ----
    mfma_lin_k<256, 0, true, unsigned short, 2><<<(N + 127) / 128, 256, 0, stream>>>(
        y, ws_l[1], bl[1], ws_r[1], br[1], nullptr, AB, xle, xre, N);
    gat_gather_k<2><<<(N + 1) / 2, 256, 0, stream>>>(xle, xre, attp[1], bop[1], rowptr, col, y, stats, N);
    gn_stats_k<<<512, 128, 0, stream>>>(y, stats, N);
    gn_final_k<<<1, 128, 0, stream>>>(stats, gnw[1], gnb[1], gnms[1], AB, invN);

    // ---- layer 3 (H=1): input y + fused norm ----
    mfma_lin_k<128, 0, true, unsigned short, 2><<<(N + 127) / 128, 256, 0, stream>>>(
        y, ws_l[2], bl[2], ws_r[2], br[2], nullptr, AB, xle, xre, N);
    gat_gather_k<1><<<(N + 3) / 4, 256, 0, stream>>>(xle, xre, attp[2], bop[2], rowptr, col, y, stats, N);
    gn_stats_k<<<512, 128, 0, stream>>>(y, stats, N);
    gn_final_k<<<1, 128, 0, stream>>>(stats, gnw[2], gnb[2], gnms[2], AB, invN);

    // head: h = gelu(gn3(y)@W_h1 + b_h1) with fused norm; out = h@W_h2 + b_h2
    mfma_lin_k<64, 2, false, float, 2><<<(N + 127) / 128, 256, 0, stream>>>(
        y, ws_h1, b_h1, nullptr, nullptr, nullptr, AB, hb, nullptr, N);
    head2_k<<<(N + 255) / 256, 256, 0, stream>>>(hb, W_h2, b_h2, (float*)d_out, N);
}

// Round 13
// 607.086 us; speedup vs baseline: 1.4872x; 1.0002x over previous
//
#include <hip/hip_runtime.h>
#include <hip/hip_fp16.h>
#include <math.h>

#define DEVINL __device__ __forceinline__

using bf16x8 = __attribute__((ext_vector_type(8))) short;
using f32x4  = __attribute__((ext_vector_type(4))) float;
using u16x4  = __attribute__((ext_vector_type(4))) unsigned short;
using f16x2  = __attribute__((ext_vector_type(2))) _Float16;

DEVINL float gelu_f(float v) { return 0.5f * v * (1.0f + erff(v * 0.7071067811865475f)); }
DEVINL unsigned short f2bf(float f) {
    union { float f; unsigned u; } c; c.f = f;
    unsigned r = c.u + 0x7fffu + ((c.u >> 16) & 1u);
    return (unsigned short)(r >> 16);
}
DEVINL float bf2f(unsigned short s) {
    union { unsigned u; float f; } c; c.u = (unsigned)s << 16;
    return c.f;
}
DEVINL unsigned short f2h(float f) {
    __half h = __float2half_rn(f);
    return *(unsigned short*)&h;
}
DEVINL f16x2 b2h2(unsigned u) {
    union { unsigned u; f16x2 h; } c; c.u = u; return c.h;
}
DEVINL void gl_lds16(const void* g, void* l) {
    __builtin_amdgcn_global_load_lds(
        (const __attribute__((address_space(1))) unsigned*)g,
        (__attribute__((address_space(3))) unsigned*)l, 16, 0, 0);
}

// ---------------- style: style = gelu(z_g@W_s1+b_s1)@W_s2 + b_s2 ----------------
__global__ void style_k(const float* __restrict__ zg, const float* __restrict__ W1,
                        const float* __restrict__ b1, const float* __restrict__ W2,
                        const float* __restrict__ b2, float* __restrict__ style) {
    __shared__ float s1[128];
    int j = threadIdx.x;
    float a = b1[j];
    for (int k = 0; k < 256; k++) a = fmaf(zg[k], W1[k * 128 + j], a);
    s1[j] = gelu_f(a);
    __syncthreads();
    float o = b2[j];
    for (int k = 0; k < 128; k++) o = fmaf(s1[k], W2[k * 128 + j], o);
    style[j] = o;
}

// ------ node-embed layer 1 (+ fused counts zeroing for the CSR build) ------------
__global__ void ne1_k(const float* __restrict__ tv, const float* __restrict__ W,
                      const float* __restrict__ b, float* __restrict__ h1,
                      int* __restrict__ counts, int Nn) {
    int idx = blockIdx.x * blockDim.x + threadIdx.x;
    if (idx < Nn) counts[idx] = 0;
    if (idx >= Nn * 128) return;
    int n = idx >> 7, c = idx & 127;
    float o = fmaf(tv[n * 3 + 0], W[c],
              fmaf(tv[n * 3 + 1], W[128 + c],
              fmaf(tv[n * 3 + 2], W[256 + c], b[c])));
    h1[idx] = gelu_f(o);
}

// -------- weight prep: f32 W[128][OUT] -> staged fragment-order hi/lo chunks -----
struct PrepArgs {
    const float* src[8];
    unsigned short* dst;
    int dstoff[8];  // in shorts
    int off[9];     // source element offsets
    int shift[8];   // log2(OUT)
};
__global__ void prep_k(PrepArgs a) {
    int idx = blockIdx.x * 256 + threadIdx.x;
    if (idx >= a.off[8]) return;
    int s = 0;
    while (idx >= a.off[s + 1]) s++;
    int e = idx - a.off[s];
    int sh = a.shift[s];
    int k = e >> sh, j = e & ((1 << sh) - 1);
    float w = a.src[s][e];
    unsigned short hi = f2bf(w);
    unsigned short lo = f2bf(w - bf2f(hi));
    int c = j >> 4, lr = j & 15;
    int s2 = k >> 5, lk = (k >> 3) & 3, i = k & 7;
    int lane = lk * 16 + lr;
    size_t base = (size_t)a.dstoff[s] + (size_t)c * 4096 + s2 * 512 + lane * 8 + i;
    a.dst[base] = hi;
    a.dst[base + 2048] = lo;
}

// ---------------- split-MFMA linear: LDS double-buffered weight chunks -----------
// PRE=0: raw f32 input rows. PRE=2: per-channel affine norm (A,B) + gelu fused.
// SPLIT: column-chunk space split across blockIdx.y (occupancy).
template <int OUT, int EPI, bool DUAL, typename OutT, int PRE, int SPLIT>
__global__ __launch_bounds__(256) void mfma_lin_k(
    const float* __restrict__ xin,
    const unsigned short* __restrict__ WT0, const float* __restrict__ b0,
    const unsigned short* __restrict__ WT1, const float* __restrict__ b1,
    const float* __restrict__ style, const float* __restrict__ AB,
    OutT* __restrict__ out0, OutT* __restrict__ out1, int Nn) {
    constexpr int CPM = OUT / 16;
    constexpr int NCH = (DUAL ? 2 : 1) * CPM;
    constexpr int CPB = NCH / SPLIT;   // chunks per block
    __shared__ uint4 buf[2][512];  // 2 x 8KB
    int t = threadIdx.x;
    int wave = t >> 6, lane = t & 63;
    int lr = lane & 15, lk = lane >> 4;
    int base = blockIdx.x * 128 + wave * 32;
    int c0 = blockIdx.y * CPB;
    int r0 = base + lr, r1 = base + 16 + lr;
    int cr0 = min(r0, Nn - 1), cr1 = min(r1, Nn - 1);
    const float* px0 = xin + (size_t)cr0 * 128;
    const float* px1 = xin + (size_t)cr1 * 128;

    bf16x8 xh[2][4], xlo[2][4];
#pragma unroll
    for (int s = 0; s < 4; s++) {
        int cb = s * 32 + lk * 8;
        float A_[8], B_[8];
        if constexpr (PRE == 2) {
            *(f32x4*)&A_[0] = *(const f32x4*)(AB + cb);
            *(f32x4*)&A_[4] = *(const f32x4*)(AB + cb + 4);
            *(f32x4*)&B_[0] = *(const f32x4*)(AB + 128 + cb);
            *(f32x4*)&B_[4] = *(const f32x4*)(AB + 128 + cb + 4);
        }
#pragma unroll
        for (int rr = 0; rr < 2; rr++) {
            const float4* p4 = (const float4*)((rr ? px1 : px0) + cb);
            float4 a = p4[0], b = p4[1];
            float v[8] = {a.x, a.y, a.z, a.w, b.x, b.y, b.z, b.w};
            if constexpr (PRE == 2) {
#pragma unroll
                for (int i = 0; i < 8; i++) v[i] = gelu_f(fmaf(A_[i], v[i], B_[i]));
            }
            bf16x8 h, l;
#pragma unroll
            for (int i = 0; i < 8; i++) {
                unsigned short hb = f2bf(v[i]);
                h[i] = (short)hb;
                l[i] = (short)f2bf(v[i] - bf2f(hb));
            }
            xh[rr][s] = h;
            xlo[rr][s] = l;
        }
    }

    auto stage = [&](int c, int bsel) {
        const unsigned short* Wt = (DUAL && c >= CPM) ? WT1 : WT0;
        int cc = (DUAL && c >= CPM) ? c - CPM : c;
        const char* g = (const char*)(Wt + (size_t)cc * 4096);
        char* l = (char*)&buf[bsel][0];
        gl_lds16(g + t * 16, l + wave * 1024);
        gl_lds16(g + 4096 + t * 16, l + 4096 + wave * 1024);
    };

    stage(c0, 0);
    for (int ci = 0; ci < CPB; ++ci) {
        int c = c0 + ci;
        int cur = ci & 1;
        bool pre = (ci + 1 < CPB);
        if (pre) stage(c + 1, cur ^ 1);
        if (pre) asm volatile("s_waitcnt vmcnt(2)" ::: "memory");
        else     asm volatile("s_waitcnt vmcnt(0)" ::: "memory");
        __builtin_amdgcn_s_barrier();

        int m = (DUAL && c >= CPM) ? 1 : 0;
        int j0 = (c - m * CPM) * 16;
        const float* bias = m ? b1 : b0;
        OutT* out = m ? out1 : out0;
        const bf16x8* W = (const bf16x8*)&buf[cur][0];

        f32x4 acc0 = {0.f, 0.f, 0.f, 0.f}, acc1 = {0.f, 0.f, 0.f, 0.f};
#pragma unroll
        for (int s = 0; s < 4; ++s) {
            bf16x8 wh = W[s * 64 + lane];
            bf16x8 wl = W[256 + s * 64 + lane];
            acc0 = __builtin_amdgcn_mfma_f32_16x16x32_bf16(wh, xh[0][s], acc0, 0, 0, 0);
            acc0 = __builtin_amdgcn_mfma_f32_16x16x32_bf16(wh, xlo[0][s], acc0, 0, 0, 0);
            acc0 = __builtin_amdgcn_mfma_f32_16x16x32_bf16(wl, xh[0][s], acc0, 0, 0, 0);
            acc1 = __builtin_amdgcn_mfma_f32_16x16x32_bf16(wh, xh[1][s], acc1, 0, 0, 0);
            acc1 = __builtin_amdgcn_mfma_f32_16x16x32_bf16(wh, xlo[1][s], acc1, 0, 0, 0);
            acc1 = __builtin_amdgcn_mfma_f32_16x16x32_bf16(wl, xh[1][s], acc1, 0, 0, 0);
        }
        int j = j0 + lk * 4;
        float o0[4], o1[4];
#pragma unroll
        for (int i = 0; i < 4; i++) {
            float bb = bias[j + i];
            if (EPI == 1) bb += style[j + i];
            float v0 = acc0[i] + bb, v1 = acc1[i] + bb;
            if (EPI == 2) { v0 = gelu_f(v0); v1 = gelu_f(v1); }
            o0[i] = v0; o1[i] = v1;
        }
        if constexpr (sizeof(OutT) == 2) {
            u16x4 s0 = {f2h(o0[0]), f2h(o0[1]), f2h(o0[2]), f2h(o0[3])};
            u16x4 s1v = {f2h(o1[0]), f2h(o1[1]), f2h(o1[2]), f2h(o1[3])};
            if (r0 < Nn) *(u16x4*)((unsigned short*)out + (size_t)r0 * OUT + j) = s0;
            if (r1 < Nn) *(u16x4*)((unsigned short*)out + (size_t)r1 * OUT + j) = s1v;
        } else {
            if (r0 < Nn) { f32x4 v = {o0[0], o0[1], o0[2], o0[3]}; *(f32x4*)((float*)out + (size_t)r0 * OUT + j) = v; }
            if (r1 < Nn) { f32x4 v = {o1[0], o1[1], o1[2], o1[3]}; *(f32x4*)((float*)out + (size_t)r1 * OUT + j) = v; }
        }
        __builtin_amdgcn_s_barrier();
    }
}

// ---------------- CSR build (by destination), self-loops appended ----------------
__global__ void count_k(const int* __restrict__ dst, int* __restrict__ counts, int E, int EP) {
    int e = blockIdx.x * blockDim.x + threadIdx.x;
    if (e >= EP) return;
    int d = (e < E) ? dst[e] : (e - E);
    atomicAdd(&counts[d], 1);
}

// hierarchical scan: tile sums -> tile offsets -> per-tile block scan
__global__ void tile_sum_k(const int* __restrict__ counts, int* __restrict__ tsum, int Nn) {
    int i = blockIdx.x * 256 + threadIdx.x;
    int v = (i < Nn) ? counts[i] : 0;
    int lane = threadIdx.x & 63, wave = threadIdx.x >> 6;
#pragma unroll
    for (int off = 1; off < 64; off <<= 1) v += __shfl_xor(v, off, 64);
    __shared__ int red[4];
    if (lane == 0) red[wave] = v;
    __syncthreads();
    if (threadIdx.x == 0) tsum[blockIdx.x] = red[0] + red[1] + red[2] + red[3];
}

__global__ void tile_scan_k(const int* __restrict__ tsum, int* __restrict__ toff,
                            int ntiles, int* __restrict__ rowptr, int Nn, int total) {
    __shared__ int s[256];
    int t = threadIdx.x;
    int v = (t < ntiles) ? tsum[t] : 0;
    s[t] = v;
    __syncthreads();
    for (int off = 1; off < 256; off <<= 1) {
        int a = (t >= off) ? s[t - off] : 0;
        __syncthreads();
        s[t] += a;
        __syncthreads();
    }
    if (t < ntiles) toff[t] = s[t] - v;  // exclusive
    if (t == 0) rowptr[Nn] = total;
}

__global__ void tile_write_k(const int* __restrict__ counts, const int* __restrict__ toff,
                             int* __restrict__ rowptr, int* __restrict__ fillc, int Nn) {
    int i = blockIdx.x * 256 + threadIdx.x;
    int t = threadIdx.x;
    int v = (i < Nn) ? counts[i] : 0;
    if (i < Nn) fillc[i] = 0;
    __shared__ int s[256];
    s[t] = v;
    __syncthreads();
    for (int off = 1; off < 256; off <<= 1) {
        int a = (t >= off) ? s[t - off] : 0;
        __syncthreads();
        s[t] += a;
        __syncthreads();
    }
    if (i < Nn) rowptr[i] = toff[blockIdx.x] + s[t] - v;
}

__global__ void fill_k(const int* __restrict__ src, const int* __restrict__ dst,
                       const int* __restrict__ rowptr, int* __restrict__ fillc,
                       int* __restrict__ col, int E, int EP) {
    int e = blockIdx.x * blockDim.x + threadIdx.x;
    if (e >= EP) return;
    int d = (e < E) ? dst[e] : (e - E);
    int s = (e < E) ? src[e] : (e - E);
    int pos = atomicAdd(&fillc[d], 1);
    col[rowptr[d] + pos] = s;
}

// ------ GATv2 gather H=2: ONE wave per node, both heads in-register --------------
// lane = h(1b)|grp(1b)|sub(4b): 2 edges in flight per head; logit reduce xor
// 1,2,4,8 (16-lane group); edge-slot combine xor 16; head-mean xor 32.
// No LDS, no __syncthreads, col[] loaded once per edge.
__global__ __launch_bounds__(256) void gat2_k(
    const unsigned short* __restrict__ xl, const unsigned short* __restrict__ xr,
    const float* __restrict__ att, const float* __restrict__ bo,
    const int* __restrict__ rowptr, const int* __restrict__ col,
    float* __restrict__ y, float* __restrict__ stats, int Nn) {
    if (blockIdx.x == 0 && threadIdx.x < 256) stats[threadIdx.x] = 0.f;
    int n = blockIdx.x * 4 + (threadIdx.x >> 6);
    int lane = threadIdx.x & 63;
    int h = lane >> 5, grp = (lane >> 4) & 1, sub = lane & 15;
    bool act = n < Nn;
    int nn = act ? n : 0;

    uint4 uxr = *(const uint4*)(xr + (size_t)nn * 256 + h * 128 + sub * 8);
    f16x2 xrv[4] = {b2h2(uxr.x), b2h2(uxr.y), b2h2(uxr.z), b2h2(uxr.w)};
    const float* ap = att + h * 128 + sub * 8;
    f16x2 a2[4];
#pragma unroll
    for (int i = 0; i < 4; i++) {
        f16x2 t; t.x = (_Float16)ap[2 * i]; t.y = (_Float16)ap[2 * i + 1];
        a2[i] = t;
    }
    f16x2 c02; c02.x = (_Float16)0.2f; c02.y = (_Float16)0.2f;

    float den = 0.f;
    float acc[8] = {0.f, 0.f, 0.f, 0.f, 0.f, 0.f, 0.f, 0.f};
    int beg = act ? rowptr[n] : 0, endp = act ? rowptr[n + 1] : 0;

    for (int k0 = beg; k0 < endp; k0 += 2) {
        int k = k0 + grp;
        bool ev = k < endp;
        int s = col[ev ? k : beg];
        uint4 u = *(const uint4*)(xl + (size_t)s * 256 + h * 128 + sub * 8);
        f16x2 v2[4] = {b2h2(u.x), b2h2(u.y), b2h2(u.z), b2h2(u.w)};
        float p = 0.f;
#pragma unroll
        for (int i = 0; i < 4; i++) {
            f16x2 t = v2[i] + xrv[i];
            f16x2 e = __builtin_elementwise_max(t, t * c02);
#if __has_builtin(__builtin_amdgcn_fdot2)
            p = __builtin_amdgcn_fdot2(e, a2[i], p, false);
#else
            p = fmaf((float)e.x, (float)a2[i].x, p);
            p = fmaf((float)e.y, (float)a2[i].y, p);
#endif
        }
        p += __shfl_xor(p, 1, 64);
        p += __shfl_xor(p, 2, 64);
        p += __shfl_xor(p, 4, 64);
        p += __shfl_xor(p, 8, 64);
        float pe = ev ? __expf(p) : 0.f;
        den += pe;
#pragma unroll
        for (int i = 0; i < 4; i++) {
            acc[2 * i]     = fmaf(pe, (float)v2[i].x, acc[2 * i]);
            acc[2 * i + 1] = fmaf(pe, (float)v2[i].y, acc[2 * i + 1]);
        }
    }
    // combine the two edge slots (within head)
    den += __shfl_xor(den, 16, 64);
#pragma unroll
    for (int j = 0; j < 8; j++) acc[j] += __shfl_xor(acc[j], 16, 64);
    float inv = 1.0f / (den + 1e-16f);
    float o[8];
#pragma unroll
    for (int j = 0; j < 8; j++) o[j] = acc[j] * inv;
    // head mean
#pragma unroll
    for (int j = 0; j < 8; j++) o[j] = (o[j] + __shfl_xor(o[j], 32, 64)) * 0.5f;
    if (act && lane < 16) {
        const float* bp = bo + sub * 8;
        f32x4 w0 = {o[0] + bp[0], o[1] + bp[1], o[2] + bp[2], o[3] + bp[3]};
        f32x4 w1 = {o[4] + bp[4], o[5] + bp[5], o[6] + bp[6], o[7] + bp[7]};
        *(f32x4*)(y + (size_t)n * 128 + sub * 8) = w0;
        *(f32x4*)(y + (size_t)n * 128 + sub * 8 + 4) = w1;
    }
}

// ------ GATv2 gather H=1: 4 edges/iter, 16 lanes x 8ch (unchanged) ---------------
__global__ __launch_bounds__(256) void gat1_k(
    const unsigned short* __restrict__ xl, const unsigned short* __restrict__ xr,
    const float* __restrict__ att, const float* __restrict__ bo,
    const int* __restrict__ rowptr, const int* __restrict__ col,
    float* __restrict__ y, float* __restrict__ stats, int Nn) {
    if (blockIdx.x == 0 && threadIdx.x < 256) stats[threadIdx.x] = 0.f;
    int w = threadIdx.x >> 6;
    int lane = threadIdx.x & 63;
    int g = lane >> 4, sub = lane & 15;
    int n = blockIdx.x * 4 + w;
    bool act = n < Nn;
    int nn = act ? n : 0;

    uint4 uxr = *(const uint4*)(xr + (size_t)nn * 128 + sub * 8);
    f16x2 xrv[4] = {b2h2(uxr.x), b2h2(uxr.y), b2h2(uxr.z), b2h2(uxr.w)};
    const float* ap = att + sub * 8;
    f16x2 a2[4];
#pragma unroll
    for (int i = 0; i < 4; i++) {
        f16x2 t; t.x = (_Float16)ap[2 * i]; t.y = (_Float16)ap[2 * i + 1];
        a2[i] = t;
    }
    f16x2 c02; c02.x = (_Float16)0.2f; c02.y = (_Float16)0.2f;

    float den = 0.f;
    float acc[8] = {0.f, 0.f, 0.f, 0.f, 0.f, 0.f, 0.f, 0.f};
    int beg = act ? rowptr[n] : 0, endp = act ? rowptr[n + 1] : 0;

    for (int k0 = beg; k0 < endp; k0 += 4) {
        int k = k0 + g;
        bool ev = k < endp;
        int s = col[ev ? k : beg];
        uint4 u = *(const uint4*)(xl + (size_t)s * 128 + sub * 8);
        f16x2 v2[4] = {b2h2(u.x), b2h2(u.y), b2h2(u.z), b2h2(u.w)};
        float p = 0.f;
#pragma unroll
        for (int i = 0; i < 4; i++) {
            f16x2 t = v2[i] + xrv[i];
            f16x2 e = __builtin_elementwise_max(t, t * c02);
#if __has_builtin(__builtin_amdgcn_fdot2)
            p = __builtin_amdgcn_fdot2(e, a2[i], p, false);
#else
            p = fmaf((float)e.x, (float)a2[i].x, p);
            p = fmaf((float)e.y, (float)a2[i].y, p);
#endif
        }
        p += __shfl_xor(p, 1, 64);
        p += __shfl_xor(p, 2, 64);
        p += __shfl_xor(p, 4, 64);
        p += __shfl_xor(p, 8, 64);
        float pe = ev ? __expf(p) : 0.f;
        den += pe;
#pragma unroll
        for (int i = 0; i < 4; i++) {
            acc[2 * i]     = fmaf(pe, (float)v2[i].x, acc[2 * i]);
            acc[2 * i + 1] = fmaf(pe, (float)v2[i].y, acc[2 * i + 1]);
        }
    }
#pragma unroll
    for (int off = 16; off <= 32; off <<= 1) {
        den += __shfl_xor(den, off, 64);
#pragma unroll
        for (int j = 0; j < 8; j++) acc[j] += __shfl_xor(acc[j], off, 64);
    }
    float inv = 1.0f / (den + 1e-16f);
    if (act && g == 0) {
        const float* bp = bo + sub * 8;
        f32x4 o0 = {acc[0] * inv + bp[0], acc[1] * inv + bp[1], acc[2] * inv + bp[2], acc[3] * inv + bp[3]};
        f32x4 o1 = {acc[4] * inv + bp[4], acc[5] * inv + bp[5], acc[6] * inv + bp[6], acc[7] * inv + bp[7]};
        *(f32x4*)(y + (size_t)n * 128 + sub * 8) = o0;
        *(f32x4*)(y + (size_t)n * 128 + sub * 8 + 4) = o1;
    }
}

// ---------------- GraphNorm stats: per-channel sum & sumsq -----------------------
__global__ void gn_stats_k(const float* __restrict__ y, float* __restrict__ stats, int Nn) {
    int c = threadIdx.x;  // 128 threads
    int per = (Nn + gridDim.x - 1) / gridDim.x;
    int n0 = blockIdx.x * per, n1 = min(n0 + per, Nn);
    float s = 0.f, s2 = 0.f;
    for (int n = n0; n < n1; n++) {
        float v = y[(size_t)n * 128 + c];
        s += v;
        s2 = fmaf(v, v, s2);
    }
    atomicAdd(&stats[c], s);
    atomicAdd(&stats[128 + c], s2);
}

// ------- GraphNorm finalize: stats -> per-channel affine (A, B) ------------------
__global__ void gn_final_k(const float* __restrict__ stats, const float* __restrict__ w,
                           const float* __restrict__ b, const float* __restrict__ ms,
                           float* __restrict__ AB, float invN) {
    int c = threadIdx.x;
    float mu = stats[c] * invN;
    float ex2 = stats[128 + c] * invN;
    float msv = ms[c];
    float var = ex2 - 2.f * msv * mu * mu + msv * msv * mu * mu;
    float r = rsqrtf(var + 1e-5f);
    float A = w[c] * r;
    AB[c] = A;
    AB[128 + c] = b[c] - A * msv * mu;
}

// ---------------- final head: out = h@W_h2 + b_h2 (OUT=3) ------------------------
__global__ void head2_k(const float* __restrict__ h, const float* __restrict__ W,
                        const float* __restrict__ b, float* __restrict__ out, int Nn) {
    __shared__ float w[192];
    __shared__ float bb[3];
    int t = threadIdx.x;
    if (t < 192) w[t] = W[t];
    if (t < 3) bb[t] = b[t];
    __syncthreads();
    int n = blockIdx.x * blockDim.x + t;
    if (n >= Nn) return;
    float a0 = bb[0], a1 = bb[1], a2 = bb[2];
    const float4* h4 = reinterpret_cast<const float4*>(h + (size_t)n * 64);
    for (int k4 = 0; k4 < 16; k4++) {
        float4 v = h4[k4];
        int k = k4 * 4;
        a0 = fmaf(v.x, w[(k + 0) * 3 + 0], a0); a1 = fmaf(v.x, w[(k + 0) * 3 + 1], a1); a2 = fmaf(v.x, w[(k + 0) * 3 + 2], a2);
        a0 = fmaf(v.y, w[(k + 1) * 3 + 0], a0); a1 = fmaf(v.y, w[(k + 1) * 3 + 1], a1); a2 = fmaf(v.y, w[(k + 1) * 3 + 2], a2);
        a0 = fmaf(v.z, w[(k + 2) * 3 + 0], a0); a1 = fmaf(v.z, w[(k + 2) * 3 + 1], a1); a2 = fmaf(v.z, w[(k + 2) * 3 + 2], a2);
        a0 = fmaf(v.w, w[(k + 3) * 3 + 0], a0); a1 = fmaf(v.w, w[(k + 3) * 3 + 1], a1); a2 = fmaf(v.w, w[(k + 3) * 3 + 2], a2);
    }
    out[n * 3 + 0] = a0;
    out[n * 3 + 1] = a1;
    out[n * 3 + 2] = a2;
}

extern "C" void kernel_launch(void* const* d_in, const int* in_sizes, int n_in,
                              void* d_out, int out_size, void* d_ws, size_t ws_size,
                              hipStream_t stream) {
    const float* zg = (const float*)d_in[0];
    const int* ei = (const int*)d_in[1];
    const float* tv = (const float*)d_in[2];
    const float* W_ne1 = (const float*)d_in[3];
    const float* b_ne1 = (const float*)d_in[4];
    const float* W_ne2 = (const float*)d_in[5];
    const float* b_ne2 = (const float*)d_in[6];
    const float* W_s1 = (const float*)d_in[7];
    const float* b_s1 = (const float*)d_in[8];
    const float* W_s2 = (const float*)d_in[9];
    const float* b_s2 = (const float*)d_in[10];
    const float *Wl[3], *bl[3], *Wr[3], *br[3], *attp[3], *bop[3], *gnw[3], *gnb[3], *gnms[3];
    for (int L = 0; L < 3; L++) {
        int base = 11 + L * 9;
        Wl[L] = (const float*)d_in[base + 0];
        bl[L] = (const float*)d_in[base + 1];
        Wr[L] = (const float*)d_in[base + 2];
        br[L] = (const float*)d_in[base + 3];
        attp[L] = (const float*)d_in[base + 4];
        bop[L] = (const float*)d_in[base + 5];
        gnw[L] = (const float*)d_in[base + 6];
        gnb[L] = (const float*)d_in[base + 7];
        gnms[L] = (const float*)d_in[base + 8];
    }
    const float* W_h1 = (const float*)d_in[38];
    const float* b_h1 = (const float*)d_in[39];
    const float* W_h2 = (const float*)d_in[40];
    const float* b_h2 = (const float*)d_in[41];

    int E = in_sizes[1] / 2;
    int N = in_sizes[2] / 3;
    int EP = E + N;
    int NT = (N + 255) / 256;
    const int* srcp = ei;
    const int* dstp = ei + E;

    char* p = (char*)d_ws;
    auto alloc = [&](size_t bytes) -> char* {
        char* r = p;
        p += (bytes + 255) & ~(size_t)255;
        return r;
    };
    float* style = (float*)alloc(512);
    float* h1 = (float*)alloc((size_t)N * 128 * 4);
    float* x = (float*)alloc((size_t)N * 128 * 4);
    unsigned short* xle = (unsigned short*)alloc((size_t)N * 256 * 2);
    unsigned short* xre = (unsigned short*)alloc((size_t)N * 256 * 2);
    float* y = (float*)alloc((size_t)N * 128 * 4);
    float* hb = (float*)alloc((size_t)N * 64 * 4);
    float* stats = (float*)alloc(1024);
    float* AB = (float*)alloc(1024);
    int* rowptr = (int*)alloc(((size_t)N + 1) * 4);
    int* counts = (int*)alloc((size_t)N * 4);
    int* fillc = (int*)alloc((size_t)N * 4);
    int* col = (int*)alloc((size_t)EP * 4);
    int* tsum = (int*)alloc((size_t)NT * 4);
    int* toff = (int*)alloc((size_t)NT * 4);
    unsigned short* wt = (unsigned short*)alloc((size_t)376832 * 2);

    // weight prep: 8 segments, staged fragment-order hi/lo layout
    PrepArgs pa;
    const float* srcs[8] = {W_ne2, Wl[0], Wr[0], Wl[1], Wr[1], Wl[2], Wr[2], W_h1};
    int outs[8] = {128, 256, 256, 256, 256, 128, 128, 64};
    int off = 0;
    pa.dst = wt;
    for (int s = 0; s < 8; s++) {
        pa.src[s] = srcs[s];
        pa.off[s] = off;
        pa.dstoff[s] = 2 * off;
        pa.shift[s] = (outs[s] == 256) ? 8 : (outs[s] == 128 ? 7 : 6);
        off += 128 * outs[s];
    }
    pa.off[8] = off;
    const unsigned short* ws_ne2 = wt + pa.dstoff[0];
    const unsigned short* ws_l[3] = {wt + pa.dstoff[1], wt + pa.dstoff[3], wt + pa.dstoff[5]};
    const unsigned short* ws_r[3] = {wt + pa.dstoff[2], wt + pa.dstoff[4], wt + pa.dstoff[6]};
    const unsigned short* ws_h1 = wt + pa.dstoff[7];
    prep_k<<<(off + 255) / 256, 256, 0, stream>>>(pa);

    float invN = 1.0f / (float)N;
    int NB = (N + 127) / 128;

    // style + node embedding (ne1 also zeroes counts)
    style_k<<<1, 128, 0, stream>>>(zg, W_s1, b_s1, W_s2, b_s2, style);
    ne1_k<<<(N * 128 + 255) / 256, 256, 0, stream>>>(tv, W_ne1, b_ne1, h1, counts, N);
    mfma_lin_k<128, 1, false, float, 0, 1><<<NB, 256, 0, stream>>>(
        h1, ws_ne2, b_ne2, nullptr, nullptr, style, nullptr, x, nullptr, N);

    // CSR by destination (rebuilt every launch); hierarchical scan
    count_k<<<(EP + 255) / 256, 256, 0, stream>>>(dstp, counts, E, EP);
    tile_sum_k<<<NT, 256, 0, stream>>>(counts, tsum, N);
    tile_scan_k<<<1, 256, 0, stream>>>(tsum, toff, NT, rowptr, N, EP);
    tile_write_k<<<NT, 256, 0, stream>>>(counts, toff, rowptr, fillc, N);
    fill_k<<<(EP + 255) / 256, 256, 0, stream>>>(srcp, dstp, rowptr, fillc, col, E, EP);

    // ---- layer 1 (H=2): input x (raw) ----
    mfma_lin_k<256, 0, true, unsigned short, 0, 2><<<dim3(NB, 2), 256, 0, stream>>>(
        x, ws_l[0], bl[0], ws_r[0], br[0], nullptr, nullptr, xle, xre, N);
    gat2_k<<<(N + 3) / 4, 256, 0, stream>>>(xle, xre, attp[0], bop[0], rowptr, col, y, stats, N);
    gn_stats_k<<<512, 128, 0, stream>>>(y, stats, N);
    gn_final_k<<<1, 128, 0, stream>>>(stats, gnw[0], gnb[0], gnms[0], AB, invN);

    // ---- layer 2 (H=2): input y + fused norm ----
    mfma_lin_k<256, 0, true, unsigned short, 2, 2><<<dim3(NB, 2), 256, 0, stream>>>(
        y, ws_l[1], bl[1], ws_r[1], br[1], nullptr, AB, xle, xre, N);
    gat2_k<<<(N + 3) / 4, 256, 0, stream>>>(xle, xre, attp[1], bop[1], rowptr, col, y, stats, N);
    gn_stats_k<<<512, 128, 0, stream>>>(y, stats, N);
    gn_final_k<<<1, 128, 0, stream>>>(stats, gnw[1], gnb[1], gnms[1], AB, invN);

    // ---- layer 3 (H=1): input y + fused norm ----
    mfma_lin_k<128, 0, true, unsigned short, 2, 2><<<dim3(NB, 2), 256, 0, stream>>>(
        y, ws_l[2], bl[2], ws_r[2], br[2], nullptr, AB, xle, xre, N);
    gat1_k<<<(N + 3) / 4, 256, 0, stream>>>(xle, xre, attp[2], bop[2], rowptr, col, y, stats, N);
    gn_stats_k<<<512, 128, 0, stream>>>(y, stats, N);
    gn_final_k<<<1, 128, 0, stream>>>(stats, gnw[2], gnb[2], gnms[2], AB, invN);

    // head: h = gelu(gn3(y)@W_h1 + b_h1) with fused norm; out = h@W_h2 + b_h2
    mfma_lin_k<64, 2, false, float, 2, 1><<<NB, 256, 0, stream>>>(
        y, ws_h1, b_h1, nullptr, nullptr, nullptr, AB, hb, nullptr, N);
    head2_k<<<(N + 255) / 256, 256, 0, stream>>>(hb, W_h2, b_h2, (float*)d_out, N);
}

// Round 15
// 570.500 us; speedup vs baseline: 1.5826x; 1.0641x over previous
//
#include <hip/hip_runtime.h>
#include <hip/hip_fp16.h>
#include <math.h>

#define DEVINL __device__ __forceinline__

using bf16x8 = __attribute__((ext_vector_type(8))) short;
using f32x4  = __attribute__((ext_vector_type(4))) float;
using u16x4  = __attribute__((ext_vector_type(4))) unsigned short;
using f16x2  = __attribute__((ext_vector_type(2))) _Float16;

DEVINL float gelu_f(float v) { return 0.5f * v * (1.0f + erff(v * 0.7071067811865475f)); }
DEVINL unsigned short f2bf(float f) {
    union { float f; unsigned u; } c; c.f = f;
    unsigned r = c.u + 0x7fffu + ((c.u >> 16) & 1u);
    return (unsigned short)(r >> 16);
}
DEVINL float bf2f(unsigned short s) {
    union { unsigned u; float f; } c; c.u = (unsigned)s << 16;
    return c.f;
}
DEVINL unsigned short f2h(float f) {
    __half h = __float2half_rn(f);
    return *(unsigned short*)&h;
}
DEVINL f16x2 b2h2(unsigned u) {
    union { unsigned u; f16x2 h; } c; c.u = u; return c.h;
}
DEVINL void gl_lds16(const void* g, void* l) {
    __builtin_amdgcn_global_load_lds(
        (const __attribute__((address_space(1))) unsigned*)g,
        (__attribute__((address_space(3))) unsigned*)l, 16, 0, 0);
}

// ---------------- style: style = gelu(z_g@W_s1+b_s1)@W_s2 + b_s2 ----------------
__global__ void style_k(const float* __restrict__ zg, const float* __restrict__ W1,
                        const float* __restrict__ b1, const float* __restrict__ W2,
                        const float* __restrict__ b2, float* __restrict__ style) {
    __shared__ float s1[128];
    int j = threadIdx.x;
    float a = b1[j];
    for (int k = 0; k < 256; k++) a = fmaf(zg[k], W1[k * 128 + j], a);
    s1[j] = gelu_f(a);
    __syncthreads();
    float o = b2[j];
    for (int k = 0; k < 128; k++) o = fmaf(s1[k], W2[k * 128 + j], o);
    style[j] = o;
}

// ------ node-embed layer 1 (+ fused counts zeroing for the CSR build) ------------
__global__ void ne1_k(const float* __restrict__ tv, const float* __restrict__ W,
                      const float* __restrict__ b, float* __restrict__ h1,
                      int* __restrict__ counts, int Nn) {
    int idx = blockIdx.x * blockDim.x + threadIdx.x;
    if (idx < Nn) counts[idx] = 0;
    if (idx >= Nn * 128) return;
    int n = idx >> 7, c = idx & 127;
    float o = fmaf(tv[n * 3 + 0], W[c],
              fmaf(tv[n * 3 + 1], W[128 + c],
              fmaf(tv[n * 3 + 2], W[256 + c], b[c])));
    h1[idx] = gelu_f(o);
}

// -------- weight prep: f32 W[128][OUT] -> staged fragment-order hi/lo chunks -----
struct PrepArgs {
    const float* src[8];
    unsigned short* dst;
    int dstoff[8];  // in shorts
    int off[9];     // source element offsets
    int shift[8];   // log2(OUT)
};
__global__ void prep_k(PrepArgs a) {
    int idx = blockIdx.x * 256 + threadIdx.x;
    if (idx >= a.off[8]) return;
    int s = 0;
    while (idx >= a.off[s + 1]) s++;
    int e = idx - a.off[s];
    int sh = a.shift[s];
    int k = e >> sh, j = e & ((1 << sh) - 1);
    float w = a.src[s][e];
    unsigned short hi = f2bf(w);
    unsigned short lo = f2bf(w - bf2f(hi));
    int c = j >> 4, lr = j & 15;
    int s2 = k >> 5, lk = (k >> 3) & 3, i = k & 7;
    int lane = lk * 16 + lr;
    size_t base = (size_t)a.dstoff[s] + (size_t)c * 4096 + s2 * 512 + lane * 8 + i;
    a.dst[base] = hi;
    a.dst[base + 2048] = lo;
}

// ---------------- split-MFMA linear: LDS double-buffered CHUNK-PAIRS -------------
// Pair = 2 adjacent 16-col chunks (16KB). Epilogue stores both 32B halves of each
// row's 64B line back-to-back -> full-line write coalescing (R13: WRITE 75MB for
// 51MB payload was the bottleneck). 24 MFMA per barrier pair.
template <int OUT, int EPI, bool DUAL, typename OutT, int PRE>
__global__ __launch_bounds__(256) void mfma_lin_k(
    const float* __restrict__ xin,
    const unsigned short* __restrict__ WT0, const float* __restrict__ b0,
    const unsigned short* __restrict__ WT1, const float* __restrict__ b1,
    const float* __restrict__ style, const float* __restrict__ AB,
    OutT* __restrict__ out0, OutT* __restrict__ out1, int Nn) {
    constexpr int CPM = OUT / 16;
    constexpr int NCH = (DUAL ? 2 : 1) * CPM;
    constexpr int NP = NCH / 2;
    __shared__ uint4 buf[2][1024];  // 2 x 16KB (pair of 8KB chunks)
    int t = threadIdx.x;
    int wave = t >> 6, lane = t & 63;
    int lr = lane & 15, lk = lane >> 4;
    int base = blockIdx.x * 128 + wave * 32;
    int r0 = base + lr, r1 = base + 16 + lr;
    int cr0 = min(r0, Nn - 1), cr1 = min(r1, Nn - 1);
    const float* px0 = xin + (size_t)cr0 * 128;
    const float* px1 = xin + (size_t)cr1 * 128;

    bf16x8 xh[2][4], xlo[2][4];
#pragma unroll
    for (int s = 0; s < 4; s++) {
        int cb = s * 32 + lk * 8;
        float A_[8], B_[8];
        if constexpr (PRE == 2) {
            *(f32x4*)&A_[0] = *(const f32x4*)(AB + cb);
            *(f32x4*)&A_[4] = *(const f32x4*)(AB + cb + 4);
            *(f32x4*)&B_[0] = *(const f32x4*)(AB + 128 + cb);
            *(f32x4*)&B_[4] = *(const f32x4*)(AB + 128 + cb + 4);
        }
#pragma unroll
        for (int rr = 0; rr < 2; rr++) {
            const float4* p4 = (const float4*)((rr ? px1 : px0) + cb);
            float4 a = p4[0], b = p4[1];
            float v[8] = {a.x, a.y, a.z, a.w, b.x, b.y, b.z, b.w};
            if constexpr (PRE == 2) {
#pragma unroll
                for (int i = 0; i < 8; i++) v[i] = gelu_f(fmaf(A_[i], v[i], B_[i]));
            }
            bf16x8 h, l;
#pragma unroll
            for (int i = 0; i < 8; i++) {
                unsigned short hb = f2bf(v[i]);
                h[i] = (short)hb;
                l[i] = (short)f2bf(v[i] - bf2f(hb));
            }
            xh[rr][s] = h;
            xlo[rr][s] = l;
        }
    }

    auto stagep = [&](int pp, int bsel) {
        char* l = (char*)&buf[bsel][0];
#pragma unroll
        for (int q = 0; q < 2; q++) {
            int c = 2 * pp + q;
            const unsigned short* Wt = (DUAL && c >= CPM) ? WT1 : WT0;
            int cc = (DUAL && c >= CPM) ? c - CPM : c;
            const char* g = (const char*)(Wt + (size_t)cc * 4096);
            gl_lds16(g + t * 16, l + q * 8192 + wave * 1024);
            gl_lds16(g + 4096 + t * 16, l + q * 8192 + 4096 + wave * 1024);
        }
    };

    stagep(0, 0);
    for (int pp = 0; pp < NP; ++pp) {
        int cur = pp & 1;
        bool pre = (pp + 1 < NP);
        if (pre) stagep(pp + 1, cur ^ 1);
        if (pre) asm volatile("s_waitcnt vmcnt(4)" ::: "memory");
        else     asm volatile("s_waitcnt vmcnt(0)" ::: "memory");
        __builtin_amdgcn_s_barrier();

        int c = 2 * pp;  // pair never straddles matrices (CPM is even for all OUT)
        int m = (DUAL && c >= CPM) ? 1 : 0;
        int j0 = (c - m * CPM) * 16;
        const float* bias = m ? b1 : b0;
        OutT* out = m ? out1 : out0;
        const bf16x8* WA = (const bf16x8*)&buf[cur][0];
        const bf16x8* WB = (const bf16x8*)&buf[cur][512];

        f32x4 aA0 = {0.f,0.f,0.f,0.f}, aA1 = {0.f,0.f,0.f,0.f};
        f32x4 aB0 = {0.f,0.f,0.f,0.f}, aB1 = {0.f,0.f,0.f,0.f};
#pragma unroll
        for (int s = 0; s < 4; ++s) {
            bf16x8 whA = WA[s * 64 + lane], wlA = WA[256 + s * 64 + lane];
            bf16x8 whB = WB[s * 64 + lane], wlB = WB[256 + s * 64 + lane];
            aA0 = __builtin_amdgcn_mfma_f32_16x16x32_bf16(whA, xh[0][s], aA0, 0, 0, 0);
            aA0 = __builtin_amdgcn_mfma_f32_16x16x32_bf16(whA, xlo[0][s], aA0, 0, 0, 0);
            aA0 = __builtin_amdgcn_mfma_f32_16x16x32_bf16(wlA, xh[0][s], aA0, 0, 0, 0);
            aA1 = __builtin_amdgcn_mfma_f32_16x16x32_bf16(whA, xh[1][s], aA1, 0, 0, 0);
            aA1 = __builtin_amdgcn_mfma_f32_16x16x32_bf16(whA, xlo[1][s], aA1, 0, 0, 0);
            aA1 = __builtin_amdgcn_mfma_f32_16x16x32_bf16(wlA, xh[1][s], aA1, 0, 0, 0);
            aB0 = __builtin_amdgcn_mfma_f32_16x16x32_bf16(whB, xh[0][s], aB0, 0, 0, 0);
            aB0 = __builtin_amdgcn_mfma_f32_16x16x32_bf16(whB, xlo[0][s], aB0, 0, 0, 0);
            aB0 = __builtin_amdgcn_mfma_f32_16x16x32_bf16(wlB, xh[0][s], aB0, 0, 0, 0);
            aB1 = __builtin_amdgcn_mfma_f32_16x16x32_bf16(whB, xh[1][s], aB1, 0, 0, 0);
            aB1 = __builtin_amdgcn_mfma_f32_16x16x32_bf16(whB, xlo[1][s], aB1, 0, 0, 0);
            aB1 = __builtin_amdgcn_mfma_f32_16x16x32_bf16(wlB, xh[1][s], aB1, 0, 0, 0);
        }
        int jA = j0 + lk * 4, jB = j0 + 16 + lk * 4;
        float oA0[4], oA1[4], oB0[4], oB1[4];
#pragma unroll
        for (int i = 0; i < 4; i++) {
            float bA = bias[jA + i], bB = bias[jB + i];
            if (EPI == 1) { bA += style[jA + i]; bB += style[jB + i]; }
            float vA0 = aA0[i] + bA, vA1 = aA1[i] + bA;
            float vB0 = aB0[i] + bB, vB1 = aB1[i] + bB;
            if (EPI == 2) { vA0 = gelu_f(vA0); vA1 = gelu_f(vA1); vB0 = gelu_f(vB0); vB1 = gelu_f(vB1); }
            oA0[i] = vA0; oA1[i] = vA1; oB0[i] = vB0; oB1[i] = vB1;
        }
        if constexpr (sizeof(OutT) == 2) {
            u16x4 sA0 = {f2h(oA0[0]), f2h(oA0[1]), f2h(oA0[2]), f2h(oA0[3])};
            u16x4 sB0 = {f2h(oB0[0]), f2h(oB0[1]), f2h(oB0[2]), f2h(oB0[3])};
            u16x4 sA1 = {f2h(oA1[0]), f2h(oA1[1]), f2h(oA1[2]), f2h(oA1[3])};
            u16x4 sB1 = {f2h(oB1[0]), f2h(oB1[1]), f2h(oB1[2]), f2h(oB1[3])};
            if (r0 < Nn) {
                *(u16x4*)((unsigned short*)out + (size_t)r0 * OUT + jA) = sA0;
                *(u16x4*)((unsigned short*)out + (size_t)r0 * OUT + jB) = sB0;
            }
            if (r1 < Nn) {
                *(u16x4*)((unsigned short*)out + (size_t)r1 * OUT + jA) = sA1;
                *(u16x4*)((unsigned short*)out + (size_t)r1 * OUT + jB) = sB1;
            }
        } else {
            if (r0 < Nn) {
                f32x4 vA = {oA0[0], oA0[1], oA0[2], oA0[3]};
                f32x4 vB = {oB0[0], oB0[1], oB0[2], oB0[3]};
                *(f32x4*)((float*)out + (size_t)r0 * OUT + jA) = vA;
                *(f32x4*)((float*)out + (size_t)r0 * OUT + jB) = vB;
            }
            if (r1 < Nn) {
                f32x4 vA = {oA1[0], oA1[1], oA1[2], oA1[3]};
                f32x4 vB = {oB1[0], oB1[1], oB1[2], oB1[3]};
                *(f32x4*)((float*)out + (size_t)r1 * OUT + jA) = vA;
                *(f32x4*)((float*)out + (size_t)r1 * OUT + jB) = vB;
            }
        }
        __builtin_amdgcn_s_barrier();
    }
}

// ---------------- CSR build (by destination), self-loops appended ----------------
__global__ void count_k(const int* __restrict__ dst, int* __restrict__ counts, int E, int EP) {
    int e = blockIdx.x * blockDim.x + threadIdx.x;
    if (e >= EP) return;
    int d = (e < E) ? dst[e] : (e - E);
    atomicAdd(&counts[d], 1);
}

// hierarchical scan: tile sums -> tile offsets -> per-tile block scan
__global__ void tile_sum_k(const int* __restrict__ counts, int* __restrict__ tsum, int Nn) {
    int i = blockIdx.x * 256 + threadIdx.x;
    int v = (i < Nn) ? counts[i] : 0;
    int lane = threadIdx.x & 63, wave = threadIdx.x >> 6;
#pragma unroll
    for (int off = 1; off < 64; off <<= 1) v += __shfl_xor(v, off, 64);
    __shared__ int red[4];
    if (lane == 0) red[wave] = v;
    __syncthreads();
    if (threadIdx.x == 0) tsum[blockIdx.x] = red[0] + red[1] + red[2] + red[3];
}

__global__ void tile_scan_k(const int* __restrict__ tsum, int* __restrict__ toff,
                            int ntiles, int* __restrict__ rowptr, int Nn, int total) {
    __shared__ int s[256];
    int t = threadIdx.x;
    int v = (t < ntiles) ? tsum[t] : 0;
    s[t] = v;
    __syncthreads();
    for (int off = 1; off < 256; off <<= 1) {
        int a = (t >= off) ? s[t - off] : 0;
        __syncthreads();
        s[t] += a;
        __syncthreads();
    }
    if (t < ntiles) toff[t] = s[t] - v;  // exclusive
    if (t == 0) rowptr[Nn] = total;
}

__global__ void tile_write_k(const int* __restrict__ counts, const int* __restrict__ toff,
                             int* __restrict__ rowptr, int* __restrict__ fillc, int Nn) {
    int i = blockIdx.x * 256 + threadIdx.x;
    int t = threadIdx.x;
    int v = (i < Nn) ? counts[i] : 0;
    if (i < Nn) fillc[i] = 0;
    __shared__ int s[256];
    s[t] = v;
    __syncthreads();
    for (int off = 1; off < 256; off <<= 1) {
        int a = (t >= off) ? s[t - off] : 0;
        __syncthreads();
        s[t] += a;
        __syncthreads();
    }
    if (i < Nn) rowptr[i] = toff[blockIdx.x] + s[t] - v;
}

__global__ void fill_k(const int* __restrict__ src, const int* __restrict__ dst,
                       const int* __restrict__ rowptr, int* __restrict__ fillc,
                       int* __restrict__ col, int E, int EP) {
    int e = blockIdx.x * blockDim.x + threadIdx.x;
    if (e >= EP) return;
    int d = (e < E) ? dst[e] : (e - E);
    int s = (e < E) ? src[e] : (e - E);
    int pos = atomicAdd(&fillc[d], 1);
    col[rowptr[d] + pos] = s;
}

// ------ GATv2 gather H=2: ONE wave per node, both heads in-register --------------
__global__ __launch_bounds__(256) void gat2_k(
    const unsigned short* __restrict__ xl, const unsigned short* __restrict__ xr,
    const float* __restrict__ att, const float* __restrict__ bo,
    const int* __restrict__ rowptr, const int* __restrict__ col,
    float* __restrict__ y, float* __restrict__ stats, int Nn) {
    if (blockIdx.x == 0 && threadIdx.x < 256) stats[threadIdx.x] = 0.f;
    int n = blockIdx.x * 4 + (threadIdx.x >> 6);
    int lane = threadIdx.x & 63;
    int h = lane >> 5, grp = (lane >> 4) & 1, sub = lane & 15;
    bool act = n < Nn;
    int nn = act ? n : 0;

    uint4 uxr = *(const uint4*)(xr + (size_t)nn * 256 + h * 128 + sub * 8);
    f16x2 xrv[4] = {b2h2(uxr.x), b2h2(uxr.y), b2h2(uxr.z), b2h2(uxr.w)};
    const float* ap = att + h * 128 + sub * 8;
    f16x2 a2[4];
#pragma unroll
    for (int i = 0; i < 4; i++) {
        f16x2 t; t.x = (_Float16)ap[2 * i]; t.y = (_Float16)ap[2 * i + 1];
        a2[i] = t;
    }
    f16x2 c02; c02.x = (_Float16)0.2f; c02.y = (_Float16)0.2f;

    float den = 0.f;
    float acc[8] = {0.f, 0.f, 0.f, 0.f, 0.f, 0.f, 0.f, 0.f};
    int beg = act ? rowptr[n] : 0, endp = act ? rowptr[n + 1] : 0;

    for (int k0 = beg; k0 < endp; k0 += 2) {
        int k = k0 + grp;
        bool ev = k < endp;
        int s = col[ev ? k : beg];
        uint4 u = *(const uint4*)(xl + (size_t)s * 256 + h * 128 + sub * 8);
        f16x2 v2[4] = {b2h2(u.x), b2h2(u.y), b2h2(u.z), b2h2(u.w)};
        float p = 0.f;
#pragma unroll
        for (int i = 0; i < 4; i++) {
            f16x2 t = v2[i] + xrv[i];
            f16x2 e = __builtin_elementwise_max(t, t * c02);
#if __has_builtin(__builtin_amdgcn_fdot2)
            p = __builtin_amdgcn_fdot2(e, a2[i], p, false);
#else
            p = fmaf((float)e.x, (float)a2[i].x, p);
            p = fmaf((float)e.y, (float)a2[i].y, p);
#endif
        }
        p += __shfl_xor(p, 1, 64);
        p += __shfl_xor(p, 2, 64);
        p += __shfl_xor(p, 4, 64);
        p += __shfl_xor(p, 8, 64);
        float pe = ev ? __expf(p) : 0.f;
        den += pe;
#pragma unroll
        for (int i = 0; i < 4; i++) {
            acc[2 * i]     = fmaf(pe, (float)v2[i].x, acc[2 * i]);
            acc[2 * i + 1] = fmaf(pe, (float)v2[i].y, acc[2 * i + 1]);
        }
    }
    den += __shfl_xor(den, 16, 64);
#pragma unroll
    for (int j = 0; j < 8; j++) acc[j] += __shfl_xor(acc[j], 16, 64);
    float inv = 1.0f / (den + 1e-16f);
    float o[8];
#pragma unroll
    for (int j = 0; j < 8; j++) o[j] = acc[j] * inv;
#pragma unroll
    for (int j = 0; j < 8; j++) o[j] = (o[j] + __shfl_xor(o[j], 32, 64)) * 0.5f;
    if (act && lane < 16) {
        const float* bp = bo + sub * 8;
        f32x4 w0 = {o[0] + bp[0], o[1] + bp[1], o[2] + bp[2], o[3] + bp[3]};
        f32x4 w1 = {o[4] + bp[4], o[5] + bp[5], o[6] + bp[6], o[7] + bp[7]};
        *(f32x4*)(y + (size_t)n * 128 + sub * 8) = w0;
        *(f32x4*)(y + (size_t)n * 128 + sub * 8 + 4) = w1;
    }
}

// ------ GATv2 gather H=1: 4 edges/iter, 16 lanes x 8ch ---------------------------
__global__ __launch_bounds__(256) void gat1_k(
    const unsigned short* __restrict__ xl, const unsigned short* __restrict__ xr,
    const float* __restrict__ att, const float* __restrict__ bo,
    const int* __restrict__ rowptr, const int* __restrict__ col,
    float* __restrict__ y, float* __restrict__ stats, int Nn) {
    if (blockIdx.x == 0 && threadIdx.x < 256) stats[threadIdx.x] = 0.f;
    int w = threadIdx.x >> 6;
    int lane = threadIdx.x & 63;
    int g = lane >> 4, sub = lane & 15;
    int n = blockIdx.x * 4 + w;
    bool act = n < Nn;
    int nn = act ? n : 0;

    uint4 uxr = *(const uint4*)(xr + (size_t)nn * 128 + sub * 8);
    f16x2 xrv[4] = {b2h2(uxr.x), b2h2(uxr.y), b2h2(uxr.z), b2h2(uxr.w)};
    const float* ap = att + sub * 8;
    f16x2 a2[4];
#pragma unroll
    for (int i = 0; i < 4; i++) {
        f16x2 t; t.x = (_Float16)ap[2 * i]; t.y = (_Float16)ap[2 * i + 1];
        a2[i] = t;
    }
    f16x2 c02; c02.x = (_Float16)0.2f; c02.y = (_Float16)0.2f;

    float den = 0.f;
    float acc[8] = {0.f, 0.f, 0.f, 0.f, 0.f, 0.f, 0.f, 0.f};
    int beg = act ? rowptr[n] : 0, endp = act ? rowptr[n + 1] : 0;

    for (int k0 = beg; k0 < endp; k0 += 4) {
        int k = k0 + g;
        bool ev = k < endp;
        int s = col[ev ? k : beg];
        uint4 u = *(const uint4*)(xl + (size_t)s * 128 + sub * 8);
        f16x2 v2[4] = {b2h2(u.x), b2h2(u.y), b2h2(u.z), b2h2(u.w)};
        float p = 0.f;
#pragma unroll
        for (int i = 0; i < 4; i++) {
            f16x2 t = v2[i] + xrv[i];
            f16x2 e = __builtin_elementwise_max(t, t * c02);
#if __has_builtin(__builtin_amdgcn_fdot2)
            p = __builtin_amdgcn_fdot2(e, a2[i], p, false);
#else
            p = fmaf((float)e.x, (float)a2[i].x, p);
            p = fmaf((float)e.y, (float)a2[i].y, p);
#endif
        }
        p += __shfl_xor(p, 1, 64);
        p += __shfl_xor(p, 2, 64);
        p += __shfl_xor(p, 4, 64);
        p += __shfl_xor(p, 8, 64);
        float pe = ev ? __expf(p) : 0.f;
        den += pe;
#pragma unroll
        for (int i = 0; i < 4; i++) {
            acc[2 * i]     = fmaf(pe, (float)v2[i].x, acc[2 * i]);
            acc[2 * i + 1] = fmaf(pe, (float)v2[i].y, acc[2 * i + 1]);
        }
    }
#pragma unroll
    for (int off = 16; off <= 32; off <<= 1) {
        den += __shfl_xor(den, off, 64);
#pragma unroll
        for (int j = 0; j < 8; j++) acc[j] += __shfl_xor(acc[j], off, 64);
    }
    float inv = 1.0f / (den + 1e-16f);
    if (act && g == 0) {
        const float* bp = bo + sub * 8;
        f32x4 o0 = {acc[0] * inv + bp[0], acc[1] * inv + bp[1], acc[2] * inv + bp[2], acc[3] * inv + bp[3]};
        f32x4 o1 = {acc[4] * inv + bp[4], acc[5] * inv + bp[5], acc[6] * inv + bp[6], acc[7] * inv + bp[7]};
        *(f32x4*)(y + (size_t)n * 128 + sub * 8) = o0;
        *(f32x4*)(y + (size_t)n * 128 + sub * 8 + 4) = o1;
    }
}

// ---------------- GraphNorm stats: per-channel sum & sumsq -----------------------
__global__ void gn_stats_k(const float* __restrict__ y, float* __restrict__ stats, int Nn) {
    int c = threadIdx.x;  // 128 threads
    int per = (Nn + gridDim.x - 1) / gridDim.x;
    int n0 = blockIdx.x * per, n1 = min(n0 + per, Nn);
    float s = 0.f, s2 = 0.f;
    for (int n = n0; n < n1; n++) {
        float v = y[(size_t)n * 128 + c];
        s += v;
        s2 = fmaf(v, v, s2);
    }
    atomicAdd(&stats[c], s);
    atomicAdd(&stats[128 + c], s2);
}

// ------- GraphNorm finalize: stats -> per-channel affine (A, B) ------------------
__global__ void gn_final_k(const float* __restrict__ stats, const float* __restrict__ w,
                           const float* __restrict__ b, const float* __restrict__ ms,
                           float* __restrict__ AB, float invN) {
    int c = threadIdx.x;
    float mu = stats[c] * invN;
    float ex2 = stats[128 + c] * invN;
    float msv = ms[c];
    float var = ex2 - 2.f * msv * mu * mu + msv * msv * mu * mu;
    float r = rsqrtf(var + 1e-5f);
    float A = w[c] * r;
    AB[c] = A;
    AB[128 + c] = b[c] - A * msv * mu;
}

// ---------------- final head: out = h@W_h2 + b_h2 (OUT=3) ------------------------
__global__ void head2_k(const float* __restrict__ h, const float* __restrict__ W,
                        const float* __restrict__ b, float* __restrict__ out, int Nn) {
    __shared__ float w[192];
    __shared__ float bb[3];
    int t = threadIdx.x;
    if (t < 192) w[t] = W[t];
    if (t < 3) bb[t] = b[t];
    __syncthreads();
    int n = blockIdx.x * blockDim.x + t;
    if (n >= Nn) return;
    float a0 = bb[0], a1 = bb[1], a2 = bb[2];
    const float4* h4 = reinterpret_cast<const float4*>(h + (size_t)n * 64);
    for (int k4 = 0; k4 < 16; k4++) {
        float4 v = h4[k4];
        int k = k4 * 4;
        a0 = fmaf(v.x, w[(k + 0) * 3 + 0], a0); a1 = fmaf(v.x, w[(k + 0) * 3 + 1], a1); a2 = fmaf(v.x, w[(k + 0) * 3 + 2], a2);
        a0 = fmaf(v.y, w[(k + 1) * 3 + 0], a0); a1 = fmaf(v.y, w[(k + 1) * 3 + 1], a1); a2 = fmaf(v.y, w[(k + 1) * 3 + 2], a2);
        a0 = fmaf(v.z, w[(k + 2) * 3 + 0], a0); a1 = fmaf(v.z, w[(k + 2) * 3 + 1], a1); a2 = fmaf(v.z, w[(k + 2) * 3 + 2], a2);
        a0 = fmaf(v.w, w[(k + 3) * 3 + 0], a0); a1 = fmaf(v.w, w[(k + 3) * 3 + 1], a1); a2 = fmaf(v.w, w[(k + 3) * 3 + 2], a2);
    }
    out[n * 3 + 0] = a0;
    out[n * 3 + 1] = a1;
    out[n * 3 + 2] = a2;
}

extern "C" void kernel_launch(void* const* d_in, const int* in_sizes, int n_in,
                              void* d_out, int out_size, void* d_ws, size_t ws_size,
                              hipStream_t stream) {
    const float* zg = (const float*)d_in[0];
    const int* ei = (const int*)d_in[1];
    const float* tv = (const float*)d_in[2];
    const float* W_ne1 = (const float*)d_in[3];
    const float* b_ne1 = (const float*)d_in[4];
    const float* W_ne2 = (const float*)d_in[5];
    const float* b_ne2 = (const float*)d_in[6];
    const float* W_s1 = (const float*)d_in[7];
    const float* b_s1 = (const float*)d_in[8];
    const float* W_s2 = (const float*)d_in[9];
    const float* b_s2 = (const float*)d_in[10];
    const float *Wl[3], *bl[3], *Wr[3], *br[3], *attp[3], *bop[3], *gnw[3], *gnb[3], *gnms[3];
    for (int L = 0; L < 3; L++) {
        int base = 11 + L * 9;
        Wl[L] = (const float*)d_in[base + 0];
        bl[L] = (const float*)d_in[base + 1];
        Wr[L] = (const float*)d_in[base + 2];
        br[L] = (const float*)d_in[base + 3];
        attp[L] = (const float*)d_in[base + 4];
        bop[L] = (const float*)d_in[base + 5];
        gnw[L] = (const float*)d_in[base + 6];
        gnb[L] = (const float*)d_in[base + 7];
        gnms[L] = (const float*)d_in[base + 8];
    }
    const float* W_h1 = (const float*)d_in[38];
    const float* b_h1 = (const float*)d_in[39];
    const float* W_h2 = (const float*)d_in[40];
    const float* b_h2 = (const float*)d_in[41];

    int E = in_sizes[1] / 2;
    int N = in_sizes[2] / 3;
    int EP = E + N;
    int NT = (N + 255) / 256;
    const int* srcp = ei;
    const int* dstp = ei + E;

    char* p = (char*)d_ws;
    auto alloc = [&](size_t bytes) -> char* {
        char* r = p;
        p += (bytes + 255) & ~(size_t)255;
        return r;
    };
    float* style = (float*)alloc(512);
    float* h1 = (float*)alloc((size_t)N * 128 * 4);
    float* x = (float*)alloc((size_t)N * 128 * 4);
    unsigned short* xle = (unsigned short*)alloc((size_t)N * 256 * 2);
    unsigned short* xre = (unsigned short*)alloc((size_t)N * 256 * 2);
    float* y = (float*)alloc((size_t)N * 128 * 4);
    float* hb = (float*)alloc((size_t)N * 64 * 4);
    float* stats = (float*)alloc(1024);
    float* AB = (float*)alloc(1024);
    int* rowptr = (int*)alloc(((size_t)N + 1) * 4);
    int* counts = (int*)alloc((size_t)N * 4);
    int* fillc = (int*)alloc((size_t)N * 4);
    int* col = (int*)alloc((size_t)EP * 4);
    int* tsum = (int*)alloc((size_t)NT * 4);
    int* toff = (int*)alloc((size_t)NT * 4);
    unsigned short* wt = (unsigned short*)alloc((size_t)376832 * 2);

    // weight prep: 8 segments, staged fragment-order hi/lo layout
    PrepArgs pa;
    const float* srcs[8] = {W_ne2, Wl[0], Wr[0], Wl[1], Wr[1], Wl[2], Wr[2], W_h1};
    int outs[8] = {128, 256, 256, 256, 256, 128, 128, 64};
    int off = 0;
    pa.dst = wt;
    for (int s = 0; s < 8; s++) {
        pa.src[s] = srcs[s];
        pa.off[s] = off;
        pa.dstoff[s] = 2 * off;
        pa.shift[s] = (outs[s] == 256) ? 8 : (outs[s] == 128 ? 7 : 6);
        off += 128 * outs[s];
    }
    pa.off[8] = off;
    const unsigned short* ws_ne2 = wt + pa.dstoff[0];
    const unsigned short* ws_l[3] = {wt + pa.dstoff[1], wt + pa.dstoff[3], wt + pa.dstoff[5]};
    const unsigned short* ws_r[3] = {wt + pa.dstoff[2], wt + pa.dstoff[4], wt + pa.dstoff[6]};
    const unsigned short* ws_h1 = wt + pa.dstoff[7];
    prep_k<<<(off + 255) / 256, 256, 0, stream>>>(pa);

    float invN = 1.0f / (float)N;
    int NB = (N + 127) / 128;

    // style + node embedding (ne1 also zeroes counts)
    style_k<<<1, 128, 0, stream>>>(zg, W_s1, b_s1, W_s2, b_s2, style);
    ne1_k<<<(N * 128 + 255) / 256, 256, 0, stream>>>(tv, W_ne1, b_ne1, h1, counts, N);
    mfma_lin_k<128, 1, false, float, 0><<<NB, 256, 0, stream>>>(
        h1, ws_ne2, b_ne2, nullptr, nullptr, style, nullptr, x, nullptr, N);

    // CSR by destination (rebuilt every launch); hierarchical scan
    count_k<<<(EP + 255) / 256, 256, 0, stream>>>(dstp, counts, E, EP);
    tile_sum_k<<<NT, 256, 0, stream>>>(counts, tsum, N);
    tile_scan_k<<<1, 256, 0, stream>>>(tsum, toff, NT, rowptr, N, EP);
    tile_write_k<<<NT, 256, 0, stream>>>(counts, toff, rowptr, fillc, N);
    fill_k<<<(EP + 255) / 256, 256, 0, stream>>>(srcp, dstp, rowptr, fillc, col, E, EP);

    // ---- layer 1 (H=2): input x (raw) ----
    mfma_lin_k<256, 0, true, unsigned short, 0><<<NB, 256, 0, stream>>>(
        x, ws_l[0], bl[0], ws_r[0], br[0], nullptr, nullptr, xle, xre, N);
    gat2_k<<<(N + 3) / 4, 256, 0, stream>>>(xle, xre, attp[0], bop[0], rowptr, col, y, stats, N);
    gn_stats_k<<<512, 128, 0, stream>>>(y, stats, N);
    gn_final_k<<<1, 128, 0, stream>>>(stats, gnw[0], gnb[0], gnms[0], AB, invN);

    // ---- layer 2 (H=2): input y + fused norm ----
    mfma_lin_k<256, 0, true, unsigned short, 2><<<NB, 256, 0, stream>>>(
        y, ws_l[1], bl[1], ws_r[1], br[1], nullptr, AB, xle, xre, N);
    gat2_k<<<(N + 3) / 4, 256, 0, stream>>>(xle, xre, attp[1], bop[1], rowptr, col, y, stats, N);
    gn_stats_k<<<512, 128, 0, stream>>>(y, stats, N);
    gn_final_k<<<1, 128, 0, stream>>>(stats, gnw[1], gnb[1], gnms[1], AB, invN);

    // ---- layer 3 (H=1): input y + fused norm ----
    mfma_lin_k<128, 0, true, unsigned short, 2><<<NB, 256, 0, stream>>>(
        y, ws_l[2], bl[2], ws_r[2], br[2], nullptr, AB, xle, xre, N);
    gat1_k<<<(N + 3) / 4, 256, 0, stream>>>(xle, xre, attp[2], bop[2], rowptr, col, y, stats, N);
    gn_stats_k<<<512, 128, 0, stream>>>(y, stats, N);
    gn_final_k<<<1, 128, 0, stream>>>(stats, gnw[2], gnb[2], gnms[2], AB, invN);

    // head: h = gelu(gn3(y)@W_h1 + b_h1) with fused norm; out = h@W_h2 + b_h2
    mfma_lin_k<64, 2, false, float, 2><<<NB, 256, 0, stream>>>(
        y, ws_h1, b_h1, nullptr, nullptr, nullptr, AB, hb, nullptr, N);
    head2_k<<<(N + 255) / 256, 256, 0, stream>>>(hb, W_h2, b_h2, (float*)d_out, N);
}

// Round 16
// 556.600 us; speedup vs baseline: 1.6221x; 1.0250x over previous
//
#include <hip/hip_runtime.h>
#include <hip/hip_fp16.h>
#include <math.h>

#define DEVINL __device__ __forceinline__

using bf16x8 = __attribute__((ext_vector_type(8))) short;
using f32x4  = __attribute__((ext_vector_type(4))) float;
using u16x4  = __attribute__((ext_vector_type(4))) unsigned short;
using f16x2  = __attribute__((ext_vector_type(2))) _Float16;

DEVINL float gelu_f(float v) { return 0.5f * v * (1.0f + erff(v * 0.7071067811865475f)); }
DEVINL unsigned short f2bf(float f) {
    union { float f; unsigned u; } c; c.f = f;
    unsigned r = c.u + 0x7fffu + ((c.u >> 16) & 1u);
    return (unsigned short)(r >> 16);
}
DEVINL float bf2f(unsigned short s) {
    union { unsigned u; float f; } c; c.u = (unsigned)s << 16;
    return c.f;
}
DEVINL unsigned short f2h(float f) {
    __half h = __float2half_rn(f);
    return *(unsigned short*)&h;
}
DEVINL f16x2 b2h2(unsigned u) {
    union { unsigned u; f16x2 h; } c; c.u = u; return c.h;
}
DEVINL void gl_lds16(const void* g, void* l) {
    __builtin_amdgcn_global_load_lds(
        (const __attribute__((address_space(1))) unsigned*)g,
        (__attribute__((address_space(3))) unsigned*)l, 16, 0, 0);
}

// ---------------- style: style = gelu(z_g@W_s1+b_s1)@W_s2 + b_s2 ----------------
__global__ void style_k(const float* __restrict__ zg, const float* __restrict__ W1,
                        const float* __restrict__ b1, const float* __restrict__ W2,
                        const float* __restrict__ b2, float* __restrict__ style) {
    __shared__ float s1[128];
    int j = threadIdx.x;
    float a = b1[j];
    for (int k = 0; k < 256; k++) a = fmaf(zg[k], W1[k * 128 + j], a);
    s1[j] = gelu_f(a);
    __syncthreads();
    float o = b2[j];
    for (int k = 0; k < 128; k++) o = fmaf(s1[k], W2[k * 128 + j], o);
    style[j] = o;
}

// ------ node-embed layer 1 (+ fused counts zeroing for the CSR build) ------------
__global__ void ne1_k(const float* __restrict__ tv, const float* __restrict__ W,
                      const float* __restrict__ b, float* __restrict__ h1,
                      int* __restrict__ counts, int Nn) {
    int idx = blockIdx.x * blockDim.x + threadIdx.x;
    if (idx < Nn) counts[idx] = 0;
    if (idx >= Nn * 128) return;
    int n = idx >> 7, c = idx & 127;
    float o = fmaf(tv[n * 3 + 0], W[c],
              fmaf(tv[n * 3 + 1], W[128 + c],
              fmaf(tv[n * 3 + 2], W[256 + c], b[c])));
    h1[idx] = gelu_f(o);
}

// -------- weight prep: f32 W[128][OUT] -> staged fragment-order hi/lo chunks -----
struct PrepArgs {
    const float* src[8];
    unsigned short* dst;
    int dstoff[8];  // in shorts
    int off[9];     // source element offsets
    int shift[8];   // log2(OUT)
};
__global__ void prep_k(PrepArgs a) {
    int idx = blockIdx.x * 256 + threadIdx.x;
    if (idx >= a.off[8]) return;
    int s = 0;
    while (idx >= a.off[s + 1]) s++;
    int e = idx - a.off[s];
    int sh = a.shift[s];
    int k = e >> sh, j = e & ((1 << sh) - 1);
    float w = a.src[s][e];
    unsigned short hi = f2bf(w);
    unsigned short lo = f2bf(w - bf2f(hi));
    int c = j >> 4, lr = j & 15;
    int s2 = k >> 5, lk = (k >> 3) & 3, i = k & 7;
    int lane = lk * 16 + lr;
    size_t base = (size_t)a.dstoff[s] + (size_t)c * 4096 + s2 * 512 + lane * 8 + i;
    a.dst[base] = hi;
    a.dst[base + 2048] = lo;
}

// ---------------- split-MFMA linear: chunk-pairs, 64 rows/block ------------------
// 4 waves x 16 rows; pair = 2 adjacent 16-col chunks (16KB staged, vmcnt(4)).
// Full-line write coalescing (R15: WRITE 75->56MB). Grid 2x R15 for occupancy.
template <int OUT, int EPI, bool DUAL, typename OutT, int PRE>
__global__ __launch_bounds__(256) void mfma_lin_k(
    const float* __restrict__ xin,
    const unsigned short* __restrict__ WT0, const float* __restrict__ b0,
    const unsigned short* __restrict__ WT1, const float* __restrict__ b1,
    const float* __restrict__ style, const float* __restrict__ AB,
    OutT* __restrict__ out0, OutT* __restrict__ out1, int Nn) {
    constexpr int CPM = OUT / 16;
    constexpr int NCH = (DUAL ? 2 : 1) * CPM;
    constexpr int NP = NCH / 2;
    __shared__ uint4 buf[2][1024];  // 2 x 16KB (pair of 8KB chunks)
    int t = threadIdx.x;
    int wave = t >> 6, lane = t & 63;
    int lr = lane & 15, lk = lane >> 4;
    int r0 = blockIdx.x * 64 + wave * 16 + lr;
    int cr0 = min(r0, Nn - 1);
    const float* px0 = xin + (size_t)cr0 * 128;

    bf16x8 xh[4], xlo[4];
#pragma unroll
    for (int s = 0; s < 4; s++) {
        int cb = s * 32 + lk * 8;
        float A_[8], B_[8];
        if constexpr (PRE == 2) {
            *(f32x4*)&A_[0] = *(const f32x4*)(AB + cb);
            *(f32x4*)&A_[4] = *(const f32x4*)(AB + cb + 4);
            *(f32x4*)&B_[0] = *(const f32x4*)(AB + 128 + cb);
            *(f32x4*)&B_[4] = *(const f32x4*)(AB + 128 + cb + 4);
        }
        const float4* p4 = (const float4*)(px0 + cb);
        float4 a = p4[0], b = p4[1];
        float v[8] = {a.x, a.y, a.z, a.w, b.x, b.y, b.z, b.w};
        if constexpr (PRE == 2) {
#pragma unroll
            for (int i = 0; i < 8; i++) v[i] = gelu_f(fmaf(A_[i], v[i], B_[i]));
        }
        bf16x8 h, l;
#pragma unroll
        for (int i = 0; i < 8; i++) {
            unsigned short hb = f2bf(v[i]);
            h[i] = (short)hb;
            l[i] = (short)f2bf(v[i] - bf2f(hb));
        }
        xh[s] = h;
        xlo[s] = l;
    }

    auto stagep = [&](int pp, int bsel) {
        char* l = (char*)&buf[bsel][0];
#pragma unroll
        for (int q = 0; q < 2; q++) {
            int c = 2 * pp + q;
            const unsigned short* Wt = (DUAL && c >= CPM) ? WT1 : WT0;
            int cc = (DUAL && c >= CPM) ? c - CPM : c;
            const char* g = (const char*)(Wt + (size_t)cc * 4096);
            gl_lds16(g + t * 16, l + q * 8192 + wave * 1024);
            gl_lds16(g + 4096 + t * 16, l + q * 8192 + 4096 + wave * 1024);
        }
    };

    stagep(0, 0);
    for (int pp = 0; pp < NP; ++pp) {
        int cur = pp & 1;
        bool pre = (pp + 1 < NP);
        if (pre) stagep(pp + 1, cur ^ 1);
        if (pre) asm volatile("s_waitcnt vmcnt(4)" ::: "memory");
        else     asm volatile("s_waitcnt vmcnt(0)" ::: "memory");
        __builtin_amdgcn_s_barrier();

        int c = 2 * pp;  // pair never straddles matrices (CPM even)
        int m = (DUAL && c >= CPM) ? 1 : 0;
        int j0 = (c - m * CPM) * 16;
        const float* bias = m ? b1 : b0;
        OutT* out = m ? out1 : out0;
        const bf16x8* WA = (const bf16x8*)&buf[cur][0];
        const bf16x8* WB = (const bf16x8*)&buf[cur][512];

        f32x4 aA0 = {0.f,0.f,0.f,0.f}, aB0 = {0.f,0.f,0.f,0.f};
#pragma unroll
        for (int s = 0; s < 4; ++s) {
            bf16x8 whA = WA[s * 64 + lane], wlA = WA[256 + s * 64 + lane];
            bf16x8 whB = WB[s * 64 + lane], wlB = WB[256 + s * 64 + lane];
            aA0 = __builtin_amdgcn_mfma_f32_16x16x32_bf16(whA, xh[s], aA0, 0, 0, 0);
            aA0 = __builtin_amdgcn_mfma_f32_16x16x32_bf16(whA, xlo[s], aA0, 0, 0, 0);
            aA0 = __builtin_amdgcn_mfma_f32_16x16x32_bf16(wlA, xh[s], aA0, 0, 0, 0);
            aB0 = __builtin_amdgcn_mfma_f32_16x16x32_bf16(whB, xh[s], aB0, 0, 0, 0);
            aB0 = __builtin_amdgcn_mfma_f32_16x16x32_bf16(whB, xlo[s], aB0, 0, 0, 0);
            aB0 = __builtin_amdgcn_mfma_f32_16x16x32_bf16(wlB, xh[s], aB0, 0, 0, 0);
        }
        int jA = j0 + lk * 4, jB = j0 + 16 + lk * 4;
        float oA0[4], oB0[4];
#pragma unroll
        for (int i = 0; i < 4; i++) {
            float bA = bias[jA + i], bB = bias[jB + i];
            if (EPI == 1) { bA += style[jA + i]; bB += style[jB + i]; }
            float vA0 = aA0[i] + bA, vB0 = aB0[i] + bB;
            if (EPI == 2) { vA0 = gelu_f(vA0); vB0 = gelu_f(vB0); }
            oA0[i] = vA0; oB0[i] = vB0;
        }
        if constexpr (sizeof(OutT) == 2) {
            u16x4 sA0 = {f2h(oA0[0]), f2h(oA0[1]), f2h(oA0[2]), f2h(oA0[3])};
            u16x4 sB0 = {f2h(oB0[0]), f2h(oB0[1]), f2h(oB0[2]), f2h(oB0[3])};
            if (r0 < Nn) {
                *(u16x4*)((unsigned short*)out + (size_t)r0 * OUT + jA) = sA0;
                *(u16x4*)((unsigned short*)out + (size_t)r0 * OUT + jB) = sB0;
            }
        } else {
            if (r0 < Nn) {
                f32x4 vA = {oA0[0], oA0[1], oA0[2], oA0[3]};
                f32x4 vB = {oB0[0], oB0[1], oB0[2], oB0[3]};
                *(f32x4*)((float*)out + (size_t)r0 * OUT + jA) = vA;
                *(f32x4*)((float*)out + (size_t)r0 * OUT + jB) = vB;
            }
        }
        __builtin_amdgcn_s_barrier();
    }
}

// ---------------- CSR build (by destination), self-loops appended ----------------
__global__ void count_k(const int* __restrict__ dst, int* __restrict__ counts, int E, int EP) {
    int e = blockIdx.x * blockDim.x + threadIdx.x;
    if (e >= EP) return;
    int d = (e < E) ? dst[e] : (e - E);
    atomicAdd(&counts[d], 1);
}

// hierarchical scan: tile sums -> tile offsets -> per-tile block scan
__global__ void tile_sum_k(const int* __restrict__ counts, int* __restrict__ tsum, int Nn) {
    int i = blockIdx.x * 256 + threadIdx.x;
    int v = (i < Nn) ? counts[i] : 0;
    int lane = threadIdx.x & 63, wave = threadIdx.x >> 6;
#pragma unroll
    for (int off = 1; off < 64; off <<= 1) v += __shfl_xor(v, off, 64);
    __shared__ int red[4];
    if (lane == 0) red[wave] = v;
    __syncthreads();
    if (threadIdx.x == 0) tsum[blockIdx.x] = red[0] + red[1] + red[2] + red[3];
}

__global__ void tile_scan_k(const int* __restrict__ tsum, int* __restrict__ toff,
                            int ntiles, int* __restrict__ rowptr, int Nn, int total) {
    __shared__ int s[256];
    int t = threadIdx.x;
    int v = (t < ntiles) ? tsum[t] : 0;
    s[t] = v;
    __syncthreads();
    for (int off = 1; off < 256; off <<= 1) {
        int a = (t >= off) ? s[t - off] : 0;
        __syncthreads();
        s[t] += a;
        __syncthreads();
    }
    if (t < ntiles) toff[t] = s[t] - v;  // exclusive
    if (t == 0) rowptr[Nn] = total;
}

__global__ void tile_write_k(const int* __restrict__ counts, const int* __restrict__ toff,
                             int* __restrict__ rowptr, int* __restrict__ fillc, int Nn) {
    int i = blockIdx.x * 256 + threadIdx.x;
    int t = threadIdx.x;
    int v = (i < Nn) ? counts[i] : 0;
    if (i < Nn) fillc[i] = 0;
    __shared__ int s[256];
    s[t] = v;
    __syncthreads();
    for (int off = 1; off < 256; off <<= 1) {
        int a = (t >= off) ? s[t - off] : 0;
        __syncthreads();
        s[t] += a;
        __syncthreads();
    }
    if (i < Nn) rowptr[i] = toff[blockIdx.x] + s[t] - v;
}

__global__ void fill_k(const int* __restrict__ src, const int* __restrict__ dst,
                       const int* __restrict__ rowptr, int* __restrict__ fillc,
                       int* __restrict__ col, int E, int EP) {
    int e = blockIdx.x * blockDim.x + threadIdx.x;
    if (e >= EP) return;
    int d = (e < E) ? dst[e] : (e - E);
    int s = (e < E) ? src[e] : (e - E);
    int pos = atomicAdd(&fillc[d], 1);
    col[rowptr[d] + pos] = s;
}

// ------ GATv2 gather H=2: ONE wave per node, both heads in-register --------------
__global__ __launch_bounds__(256) void gat2_k(
    const unsigned short* __restrict__ xl, const unsigned short* __restrict__ xr,
    const float* __restrict__ att, const float* __restrict__ bo,
    const int* __restrict__ rowptr, const int* __restrict__ col,
    float* __restrict__ y, float* __restrict__ stats, int Nn) {
    if (blockIdx.x == 0 && threadIdx.x < 256) stats[threadIdx.x] = 0.f;
    int n = blockIdx.x * 4 + (threadIdx.x >> 6);
    int lane = threadIdx.x & 63;
    int h = lane >> 5, grp = (lane >> 4) & 1, sub = lane & 15;
    bool act = n < Nn;
    int nn = act ? n : 0;

    uint4 uxr = *(const uint4*)(xr + (size_t)nn * 256 + h * 128 + sub * 8);
    f16x2 xrv[4] = {b2h2(uxr.x), b2h2(uxr.y), b2h2(uxr.z), b2h2(uxr.w)};
    const float* ap = att + h * 128 + sub * 8;
    f16x2 a2[4];
#pragma unroll
    for (int i = 0; i < 4; i++) {
        f16x2 t; t.x = (_Float16)ap[2 * i]; t.y = (_Float16)ap[2 * i + 1];
        a2[i] = t;
    }
    f16x2 c02; c02.x = (_Float16)0.2f; c02.y = (_Float16)0.2f;

    float den = 0.f;
    float acc[8] = {0.f, 0.f, 0.f, 0.f, 0.f, 0.f, 0.f, 0.f};
    int beg = act ? rowptr[n] : 0, endp = act ? rowptr[n + 1] : 0;

    for (int k0 = beg; k0 < endp; k0 += 2) {
        int k = k0 + grp;
        bool ev = k < endp;
        int s = col[ev ? k : beg];
        uint4 u = *(const uint4*)(xl + (size_t)s * 256 + h * 128 + sub * 8);
        f16x2 v2[4] = {b2h2(u.x), b2h2(u.y), b2h2(u.z), b2h2(u.w)};
        float p = 0.f;
#pragma unroll
        for (int i = 0; i < 4; i++) {
            f16x2 t = v2[i] + xrv[i];
            f16x2 e = __builtin_elementwise_max(t, t * c02);
#if __has_builtin(__builtin_amdgcn_fdot2)
            p = __builtin_amdgcn_fdot2(e, a2[i], p, false);
#else
            p = fmaf((float)e.x, (float)a2[i].x, p);
            p = fmaf((float)e.y, (float)a2[i].y, p);
#endif
        }
        p += __shfl_xor(p, 1, 64);
        p += __shfl_xor(p, 2, 64);
        p += __shfl_xor(p, 4, 64);
        p += __shfl_xor(p, 8, 64);
        float pe = ev ? __expf(p) : 0.f;
        den += pe;
#pragma unroll
        for (int i = 0; i < 4; i++) {
            acc[2 * i]     = fmaf(pe, (float)v2[i].x, acc[2 * i]);
            acc[2 * i + 1] = fmaf(pe, (float)v2[i].y, acc[2 * i + 1]);
        }
    }
    den += __shfl_xor(den, 16, 64);
#pragma unroll
    for (int j = 0; j < 8; j++) acc[j] += __shfl_xor(acc[j], 16, 64);
    float inv = 1.0f / (den + 1e-16f);
    float o[8];
#pragma unroll
    for (int j = 0; j < 8; j++) o[j] = acc[j] * inv;
#pragma unroll
    for (int j = 0; j < 8; j++) o[j] = (o[j] + __shfl_xor(o[j], 32, 64)) * 0.5f;
    if (act && lane < 16) {
        const float* bp = bo + sub * 8;
        f32x4 w0 = {o[0] + bp[0], o[1] + bp[1], o[2] + bp[2], o[3] + bp[3]};
        f32x4 w1 = {o[4] + bp[4], o[5] + bp[5], o[6] + bp[6], o[7] + bp[7]};
        *(f32x4*)(y + (size_t)n * 128 + sub * 8) = w0;
        *(f32x4*)(y + (size_t)n * 128 + sub * 8 + 4) = w1;
    }
}

// ------ GATv2 gather H=1: 4 edges/iter, 16 lanes x 8ch ---------------------------
__global__ __launch_bounds__(256) void gat1_k(
    const unsigned short* __restrict__ xl, const unsigned short* __restrict__ xr,
    const float* __restrict__ att, const float* __restrict__ bo,
    const int* __restrict__ rowptr, const int* __restrict__ col,
    float* __restrict__ y, float* __restrict__ stats, int Nn) {
    if (blockIdx.x == 0 && threadIdx.x < 256) stats[threadIdx.x] = 0.f;
    int w = threadIdx.x >> 6;
    int lane = threadIdx.x & 63;
    int g = lane >> 4, sub = lane & 15;
    int n = blockIdx.x * 4 + w;
    bool act = n < Nn;
    int nn = act ? n : 0;

    uint4 uxr = *(const uint4*)(xr + (size_t)nn * 128 + sub * 8);
    f16x2 xrv[4] = {b2h2(uxr.x), b2h2(uxr.y), b2h2(uxr.z), b2h2(uxr.w)};
    const float* ap = att + sub * 8;
    f16x2 a2[4];
#pragma unroll
    for (int i = 0; i < 4; i++) {
        f16x2 t; t.x = (_Float16)ap[2 * i]; t.y = (_Float16)ap[2 * i + 1];
        a2[i] = t;
    }
    f16x2 c02; c02.x = (_Float16)0.2f; c02.y = (_Float16)0.2f;

    float den = 0.f;
    float acc[8] = {0.f, 0.f, 0.f, 0.f, 0.f, 0.f, 0.f, 0.f};
    int beg = act ? rowptr[n] : 0, endp = act ? rowptr[n + 1] : 0;

    for (int k0 = beg; k0 < endp; k0 += 4) {
        int k = k0 + g;
        bool ev = k < endp;
        int s = col[ev ? k : beg];
        uint4 u = *(const uint4*)(xl + (size_t)s * 128 + sub * 8);
        f16x2 v2[4] = {b2h2(u.x), b2h2(u.y), b2h2(u.z), b2h2(u.w)};
        float p = 0.f;
#pragma unroll
        for (int i = 0; i < 4; i++) {
            f16x2 t = v2[i] + xrv[i];
            f16x2 e = __builtin_elementwise_max(t, t * c02);
#if __has_builtin(__builtin_amdgcn_fdot2)
            p = __builtin_amdgcn_fdot2(e, a2[i], p, false);
#else
            p = fmaf((float)e.x, (float)a2[i].x, p);
            p = fmaf((float)e.y, (float)a2[i].y, p);
#endif
        }
        p += __shfl_xor(p, 1, 64);
        p += __shfl_xor(p, 2, 64);
        p += __shfl_xor(p, 4, 64);
        p += __shfl_xor(p, 8, 64);
        float pe = ev ? __expf(p) : 0.f;
        den += pe;
#pragma unroll
        for (int i = 0; i < 4; i++) {
            acc[2 * i]     = fmaf(pe, (float)v2[i].x, acc[2 * i]);
            acc[2 * i + 1] = fmaf(pe, (float)v2[i].y, acc[2 * i + 1]);
        }
    }
#pragma unroll
    for (int off = 16; off <= 32; off <<= 1) {
        den += __shfl_xor(den, off, 64);
#pragma unroll
        for (int j = 0; j < 8; j++) acc[j] += __shfl_xor(acc[j], off, 64);
    }
    float inv = 1.0f / (den + 1e-16f);
    if (act && g == 0) {
        const float* bp = bo + sub * 8;
        f32x4 o0 = {acc[0] * inv + bp[0], acc[1] * inv + bp[1], acc[2] * inv + bp[2], acc[3] * inv + bp[3]};
        f32x4 o1 = {acc[4] * inv + bp[4], acc[5] * inv + bp[5], acc[6] * inv + bp[6], acc[7] * inv + bp[7]};
        *(f32x4*)(y + (size_t)n * 128 + sub * 8) = o0;
        *(f32x4*)(y + (size_t)n * 128 + sub * 8 + 4) = o1;
    }
}

// ------- GraphNorm stats: 256 thr, LDS pre-reduce, 1024 blocks -------------------
__global__ __launch_bounds__(256) void gn_stats_k(const float* __restrict__ y,
                                                  float* __restrict__ stats, int Nn) {
    int t = threadIdx.x;
    int c = t & 127, half = t >> 7;
    int per = (Nn + gridDim.x - 1) / gridDim.x;
    int n0 = blockIdx.x * per, n1 = min(n0 + per, Nn);
    float s = 0.f, s2 = 0.f;
    for (int n = n0 + half; n < n1; n += 2) {
        float v = y[(size_t)n * 128 + c];
        s += v;
        s2 = fmaf(v, v, s2);
    }
    __shared__ float shs[256], shq[256];
    shs[t] = s; shq[t] = s2;
    __syncthreads();
    if (t < 128) {
        atomicAdd(&stats[t], shs[t] + shs[t + 128]);
        atomicAdd(&stats[128 + t], shq[t] + shq[t + 128]);
    }
}

// ------- GraphNorm finalize: stats -> per-channel affine (A, B) ------------------
__global__ void gn_final_k(const float* __restrict__ stats, const float* __restrict__ w,
                           const float* __restrict__ b, const float* __restrict__ ms,
                           float* __restrict__ AB, float invN) {
    int c = threadIdx.x;
    float mu = stats[c] * invN;
    float ex2 = stats[128 + c] * invN;
    float msv = ms[c];
    float var = ex2 - 2.f * msv * mu * mu + msv * msv * mu * mu;
    float r = rsqrtf(var + 1e-5f);
    float A = w[c] * r;
    AB[c] = A;
    AB[128 + c] = b[c] - A * msv * mu;
}

// ---------------- final head: out = h@W_h2 + b_h2 (OUT=3) ------------------------
__global__ void head2_k(const float* __restrict__ h, const float* __restrict__ W,
                        const float* __restrict__ b, float* __restrict__ out, int Nn) {
    __shared__ float w[192];
    __shared__ float bb[3];
    int t = threadIdx.x;
    if (t < 192) w[t] = W[t];
    if (t < 3) bb[t] = b[t];
    __syncthreads();
    int n = blockIdx.x * blockDim.x + t;
    if (n >= Nn) return;
    float a0 = bb[0], a1 = bb[1], a2 = bb[2];
    const float4* h4 = reinterpret_cast<const float4*>(h + (size_t)n * 64);
    for (int k4 = 0; k4 < 16; k4++) {
        float4 v = h4[k4];
        int k = k4 * 4;
        a0 = fmaf(v.x, w[(k + 0) * 3 + 0], a0); a1 = fmaf(v.x, w[(k + 0) * 3 + 1], a1); a2 = fmaf(v.x, w[(k + 0) * 3 + 2], a2);
        a0 = fmaf(v.y, w[(k + 1) * 3 + 0], a0); a1 = fmaf(v.y, w[(k + 1) * 3 + 1], a1); a2 = fmaf(v.y, w[(k + 1) * 3 + 2], a2);
        a0 = fmaf(v.z, w[(k + 2) * 3 + 0], a0); a1 = fmaf(v.z, w[(k + 2) * 3 + 1], a1); a2 = fmaf(v.z, w[(k + 2) * 3 + 2], a2);
        a0 = fmaf(v.w, w[(k + 3) * 3 + 0], a0); a1 = fmaf(v.w, w[(k + 3) * 3 + 1], a1); a2 = fmaf(v.w, w[(k + 3) * 3 + 2], a2);
    }
    out[n * 3 + 0] = a0;
    out[n * 3 + 1] = a1;
    out[n * 3 + 2] = a2;
}

extern "C" void kernel_launch(void* const* d_in, const int* in_sizes, int n_in,
                              void* d_out, int out_size, void* d_ws, size_t ws_size,
                              hipStream_t stream) {
    const float* zg = (const float*)d_in[0];
    const int* ei = (const int*)d_in[1];
    const float* tv = (const float*)d_in[2];
    const float* W_ne1 = (const float*)d_in[3];
    const float* b_ne1 = (const float*)d_in[4];
    const float* W_ne2 = (const float*)d_in[5];
    const float* b_ne2 = (const float*)d_in[6];
    const float* W_s1 = (const float*)d_in[7];
    const float* b_s1 = (const float*)d_in[8];
    const float* W_s2 = (const float*)d_in[9];
    const float* b_s2 = (const float*)d_in[10];
    const float *Wl[3], *bl[3], *Wr[3], *br[3], *attp[3], *bop[3], *gnw[3], *gnb[3], *gnms[3];
    for (int L = 0; L < 3; L++) {
        int base = 11 + L * 9;
        Wl[L] = (const float*)d_in[base + 0];
        bl[L] = (const float*)d_in[base + 1];
        Wr[L] = (const float*)d_in[base + 2];
        br[L] = (const float*)d_in[base + 3];
        attp[L] = (const float*)d_in[base + 4];
        bop[L] = (const float*)d_in[base + 5];
        gnw[L] = (const float*)d_in[base + 6];
        gnb[L] = (const float*)d_in[base + 7];
        gnms[L] = (const float*)d_in[base + 8];
    }
    const float* W_h1 = (const float*)d_in[38];
    const float* b_h1 = (const float*)d_in[39];
    const float* W_h2 = (const float*)d_in[40];
    const float* b_h2 = (const float*)d_in[41];

    int E = in_sizes[1] / 2;
    int N = in_sizes[2] / 3;
    int EP = E + N;
    int NT = (N + 255) / 256;
    const int* srcp = ei;
    const int* dstp = ei + E;

    char* p = (char*)d_ws;
    auto alloc = [&](size_t bytes) -> char* {
        char* r = p;
        p += (bytes + 255) & ~(size_t)255;
        return r;
    };
    float* style = (float*)alloc(512);
    float* h1 = (float*)alloc((size_t)N * 128 * 4);
    float* x = (float*)alloc((size_t)N * 128 * 4);
    unsigned short* xle = (unsigned short*)alloc((size_t)N * 256 * 2);
    unsigned short* xre = (unsigned short*)alloc((size_t)N * 256 * 2);
    float* y = (float*)alloc((size_t)N * 128 * 4);
    float* hb = (float*)alloc((size_t)N * 64 * 4);
    float* stats = (float*)alloc(1024);
    float* AB = (float*)alloc(1024);
    int* rowptr = (int*)alloc(((size_t)N + 1) * 4);
    int* counts = (int*)alloc((size_t)N * 4);
    int* fillc = (int*)alloc((size_t)N * 4);
    int* col = (int*)alloc((size_t)EP * 4);
    int* tsum = (int*)alloc((size_t)NT * 4);
    int* toff = (int*)alloc((size_t)NT * 4);
    unsigned short* wt = (unsigned short*)alloc((size_t)376832 * 2);

    // weight prep: 8 segments, staged fragment-order hi/lo layout
    PrepArgs pa;
    const float* srcs[8] = {W_ne2, Wl[0], Wr[0], Wl[1], Wr[1], Wl[2], Wr[2], W_h1};
    int outs[8] = {128, 256, 256, 256, 256, 128, 128, 64};
    int off = 0;
    pa.dst = wt;
    for (int s = 0; s < 8; s++) {
        pa.src[s] = srcs[s];
        pa.off[s] = off;
        pa.dstoff[s] = 2 * off;
        pa.shift[s] = (outs[s] == 256) ? 8 : (outs[s] == 128 ? 7 : 6);
        off += 128 * outs[s];
    }
    pa.off[8] = off;
    const unsigned short* ws_ne2 = wt + pa.dstoff[0];
    const unsigned short* ws_l[3] = {wt + pa.dstoff[1], wt + pa.dstoff[3], wt + pa.dstoff[5]};
    const unsigned short* ws_r[3] = {wt + pa.dstoff[2], wt + pa.dstoff[4], wt + pa.dstoff[6]};
    const unsigned short* ws_h1 = wt + pa.dstoff[7];
    prep_k<<<(off + 255) / 256, 256, 0, stream>>>(pa);

    float invN = 1.0f / (float)N;
    int NB = (N + 63) / 64;

    // style + node embedding (ne1 also zeroes counts)
    style_k<<<1, 128, 0, stream>>>(zg, W_s1, b_s1, W_s2, b_s2, style);
    ne1_k<<<(N * 128 + 255) / 256, 256, 0, stream>>>(tv, W_ne1, b_ne1, h1, counts, N);
    mfma_lin_k<128, 1, false, float, 0><<<NB, 256, 0, stream>>>(
        h1, ws_ne2, b_ne2, nullptr, nullptr, style, nullptr, x, nullptr, N);

    // CSR by destination (rebuilt every launch); hierarchical scan
    count_k<<<(EP + 255) / 256, 256, 0, stream>>>(dstp, counts, E, EP);
    tile_sum_k<<<NT, 256, 0, stream>>>(counts, tsum, N);
    tile_scan_k<<<1, 256, 0, stream>>>(tsum, toff, NT, rowptr, N, EP);
    tile_write_k<<<NT, 256, 0, stream>>>(counts, toff, rowptr, fillc, N);
    fill_k<<<(EP + 255) / 256, 256, 0, stream>>>(srcp, dstp, rowptr, fillc, col, E, EP);

    // ---- layer 1 (H=2): input x (raw) ----
    mfma_lin_k<256, 0, true, unsigned short, 0><<<NB, 256, 0, stream>>>(
        x, ws_l[0], bl[0], ws_r[0], br[0], nullptr, nullptr, xle, xre, N);
    gat2_k<<<(N + 3) / 4, 256, 0, stream>>>(xle, xre, attp[0], bop[0], rowptr, col, y, stats, N);
    gn_stats_k<<<1024, 256, 0, stream>>>(y, stats, N);
    gn_final_k<<<1, 128, 0, stream>>>(stats, gnw[0], gnb[0], gnms[0], AB, invN);

    // ---- layer 2 (H=2): input y + fused norm ----
    mfma_lin_k<256, 0, true, unsigned short, 2><<<NB, 256, 0, stream>>>(
        y, ws_l[1], bl[1], ws_r[1], br[1], nullptr, AB, xle, xre, N);
    gat2_k<<<(N + 3) / 4, 256, 0, stream>>>(xle, xre, attp[1], bop[1], rowptr, col, y, stats, N);
    gn_stats_k<<<1024, 256, 0, stream>>>(y, stats, N);
    gn_final_k<<<1, 128, 0, stream>>>(stats, gnw[1], gnb[1], gnms[1], AB, invN);

    // ---- layer 3 (H=1): input y + fused norm ----
    mfma_lin_k<128, 0, true, unsigned short, 2><<<NB, 256, 0, stream>>>(
        y, ws_l[2], bl[2], ws_r[2], br[2], nullptr, AB, xle, xre, N);
    gat1_k<<<(N + 3) / 4, 256, 0, stream>>>(xle, xre, attp[2], bop[2], rowptr, col, y, stats, N);
    gn_stats_k<<<1024, 256, 0, stream>>>(y, stats, N);
    gn_final_k<<<1, 128, 0, stream>>>(stats, gnw[2], gnb[2], gnms[2], AB, invN);

    // head: h = gelu(gn3(y)@W_h1 + b_h1) with fused norm; out = h@W_h2 + b_h2
    mfma_lin_k<64, 2, false, float, 2><<<NB, 256, 0, stream>>>(
        y, ws_h1, b_h1, nullptr, nullptr, nullptr, AB, hb, nullptr, N);
    head2_k<<<(N + 255) / 256, 256, 0, stream>>>(hb, W_h2, b_h2, (float*)d_out, N);
}